// Round 8
// baseline (337.188 us; speedup 1.0000x reference)
//
#include <hip/hip_runtime.h>
#include <math.h>

#define NN   4096
#define DIM  256
#define NE   131072
#define NH   4
#define DH   64
#define F1D  128
#define NG   16
#define AD   32

typedef unsigned short u16;
typedef unsigned int   u32;
typedef __attribute__((ext_vector_type(8))) short short8b;
typedef __attribute__((ext_vector_type(4))) float f32x4;

enum { EPI_BIAS = 0, EPI_BNELU = 1, EPI_BIAS_ELU = 2, EPI_BIAS_RES = 3 };

__device__ inline u16 f2bf(float x) {
    u32 u = __float_as_uint(x);
    u += 0x7fffu + ((u >> 16) & 1u);
    return (u16)(u >> 16);
}
__device__ inline float bf2f(u16 h) {
    return __uint_as_float(((u32)h) << 16);
}
__device__ inline u32 packbf(float a, float b) {
    return (u32)f2bf(a) | ((u32)f2bf(b) << 16);
}

// ---------------- CSR build ----------------
__global__ void csr_count(const int* __restrict__ dst, int* __restrict__ cnt) {
    int e = blockIdx.x * 256 + threadIdx.x;
    atomicAdd(&cnt[dst[e]], 1);
}

__global__ void csr_scan(const int* __restrict__ cnt, int* __restrict__ off) {
    int lane = threadIdx.x;
    int base = lane * (NN / 64);
    int s = 0;
    for (int i = 0; i < NN / 64; ++i) s += cnt[base + i];
    int acc = s;
    #pragma unroll
    for (int o = 1; o < 64; o <<= 1) {
        int t = __shfl_up(acc, o);
        if (lane >= o) acc += t;
    }
    int run = acc - s;
    for (int i = 0; i < NN / 64; ++i) { off[base + i] = run; run += cnt[base + i]; }
    if (lane == 63) off[NN] = run;
}

__global__ void csr_fill(const int* __restrict__ dst, const int* __restrict__ src,
                         const float* __restrict__ eattr, const int* __restrict__ off,
                         int* __restrict__ cur, int* __restrict__ esrc,
                         float* __restrict__ ewt) {
    int e = blockIdx.x * 256 + threadIdx.x;
    int d = dst[e];
    int pos = off[d] + atomicAdd(&cur[d], 1);
    esrc[pos] = src[e];
    ewt[pos]  = eattr[e];
}

// ---------------- neighbor aggregation: 1 wave per node -------------------
template<bool LAST>
__global__ __launch_bounds__(256) void agg_kernel(
    const float* __restrict__ x, const int* __restrict__ esrc,
    const float* __restrict__ ewt, const int* __restrict__ off,
    float* __restrict__ agg)
{
    const int node = blockIdx.x * 4 + (threadIdx.x >> 6);
    const int lane = threadIdx.x & 63;
    const int d4 = lane * 4;
    int j = off[node];
    const int j1 = off[node + 1];
    float4 acc = make_float4(0.f, 0.f, 0.f, 0.f);
    for (; j + 4 <= j1; j += 4) {
        const int s0 = esrc[j], s1 = esrc[j + 1], s2 = esrc[j + 2], s3 = esrc[j + 3];
        const float4 x0 = *(const float4*)&x[(size_t)s0 * DIM + d4];
        const float4 x1 = *(const float4*)&x[(size_t)s1 * DIM + d4];
        const float4 x2 = *(const float4*)&x[(size_t)s2 * DIM + d4];
        const float4 x3 = *(const float4*)&x[(size_t)s3 * DIM + d4];
        const float w0 = LAST ? ewt[j]     : 1.f;
        const float w1 = LAST ? ewt[j + 1] : 1.f;
        const float w2 = LAST ? ewt[j + 2] : 1.f;
        const float w3 = LAST ? ewt[j + 3] : 1.f;
        acc.x = fmaf(x0.x, w0, acc.x); acc.y = fmaf(x0.y, w0, acc.y);
        acc.z = fmaf(x0.z, w0, acc.z); acc.w = fmaf(x0.w, w0, acc.w);
        acc.x = fmaf(x1.x, w1, acc.x); acc.y = fmaf(x1.y, w1, acc.y);
        acc.z = fmaf(x1.z, w1, acc.z); acc.w = fmaf(x1.w, w1, acc.w);
        acc.x = fmaf(x2.x, w2, acc.x); acc.y = fmaf(x2.y, w2, acc.y);
        acc.z = fmaf(x2.z, w2, acc.z); acc.w = fmaf(x2.w, w2, acc.w);
        acc.x = fmaf(x3.x, w3, acc.x); acc.y = fmaf(x3.y, w3, acc.y);
        acc.z = fmaf(x3.z, w3, acc.z); acc.w = fmaf(x3.w, w3, acc.w);
    }
    for (; j < j1; ++j) {
        const int s = esrc[j];
        const float w = LAST ? ewt[j] : 1.f;
        const float4 xv = *(const float4*)&x[(size_t)s * DIM + d4];
        acc.x = fmaf(xv.x, w, acc.x); acc.y = fmaf(xv.y, w, acc.y);
        acc.z = fmaf(xv.z, w, acc.z); acc.w = fmaf(xv.w, w, acc.w);
    }
    *(float4*)&agg[(size_t)node * DIM + d4] = acc;
}

// ---------------- fp32 tiled GEMM, 64x64 tile, 512 threads ----------------
// 8 waves/block (2 waves/SIMD at 1 block/CU — round-7 fix: 256-thread blocks
// at grid 256 left 1 wave/SIMD, ~27% issue efficiency). Loader split:
// threads 0..255 stage A, 256..511 stage B. Microtile 4 rows x 2 cols.
// Per-output k-accumulation order identical to the 256-thread version.
template<int EPI, bool DUAL>
__global__ __launch_bounds__(512) void gemm_kernel(
    const float* __restrict__ A0, const float* __restrict__ B0,
    const float* __restrict__ A1, const float* __restrict__ B1,
    const float* __restrict__ bias,
    const float* __restrict__ gamma, const float* __restrict__ beta,
    const float* __restrict__ bnmean, const float* __restrict__ bnvar,
    const float* __restrict__ resid,
    float* __restrict__ out, int K, int M)
{
    __shared__ float As[16][68];
    __shared__ float Bs[16][64];

    const int tid  = threadIdx.x;
    const int row0 = blockIdx.y * 64;
    const int col0 = blockIdx.x * 64;

    const int tx = tid & 31;          // cols tx*2 .. tx*2+1
    const int ty = tid >> 5;          // rows ty*4 .. ty*4+3
    const bool isA = tid < 256;
    const int lrow = (tid & 255) >> 2;     // A-load row
    const int lk4  = (tid & 3) * 4;        // A-load k offset
    const int bk   = (tid & 255) >> 4;     // B-load k row
    const int bc4  = (tid & 15) * 4;       // B-load col offset

    float acc[4][2] = {};
    const int kTot = DUAL ? 2 * K : K;

    float4 v;
    if (isA) v = *(const float4*)&A0[(size_t)(row0 + lrow) * K + lk4];
    else     v = *(const float4*)&B0[(size_t)bk * M + col0 + bc4];

    for (int k0 = 0; k0 < kTot; k0 += 16) {
        __syncthreads();
        if (isA) {
            As[lk4 + 0][lrow] = v.x;
            As[lk4 + 1][lrow] = v.y;
            As[lk4 + 2][lrow] = v.z;
            As[lk4 + 3][lrow] = v.w;
        } else {
            *(float4*)&Bs[bk][bc4] = v;
        }
        if (k0 + 16 < kTot) {
            const int kn = k0 + 16;
            const bool ph1 = DUAL && (kn >= K);
            const float* A = ph1 ? A1 : A0;
            const float* B = ph1 ? B1 : B0;
            const int kb = ph1 ? (kn - K) : kn;
            if (isA) v = *(const float4*)&A[(size_t)(row0 + lrow) * K + kb + lk4];
            else     v = *(const float4*)&B[(size_t)(kb + bk) * M + col0 + bc4];
        }
        __syncthreads();
        #pragma unroll
        for (int kk = 0; kk < 16; ++kk) {
            const float4 a = *(const float4*)&As[kk][ty * 4];
            const float2 b = *(const float2*)&Bs[kk][tx * 2];
            acc[0][0] = fmaf(a.x, b.x, acc[0][0]);
            acc[0][1] = fmaf(a.x, b.y, acc[0][1]);
            acc[1][0] = fmaf(a.y, b.x, acc[1][0]);
            acc[1][1] = fmaf(a.y, b.y, acc[1][1]);
            acc[2][0] = fmaf(a.z, b.x, acc[2][0]);
            acc[2][1] = fmaf(a.z, b.y, acc[2][1]);
            acc[3][0] = fmaf(a.w, b.x, acc[3][0]);
            acc[3][1] = fmaf(a.w, b.y, acc[3][1]);
        }
    }
    #pragma unroll
    for (int i = 0; i < 4; ++i) {
        const int r = row0 + ty * 4 + i;
        float2 o2;
        #pragma unroll
        for (int j = 0; j < 2; ++j) {
            const int c = col0 + tx * 2 + j;
            float t = acc[i][j] + bias[c];
            if (EPI == EPI_BNELU) {
                t = gamma[c] * (t - bnmean[c]) * rsqrtf(bnvar[c] + 1e-5f) + beta[c];
                t = t > 0.f ? t : expm1f(t);
            } else if (EPI == EPI_BIAS_ELU) {
                t = t > 0.f ? t : expm1f(t);
            } else if (EPI == EPI_BIAS_RES) {
                t += resid[(size_t)r * M + c];
            }
            if (j == 0) o2.x = t; else o2.y = t;
        }
        *(float2*)&out[(size_t)r * M + col0 + tx * 2] = o2;
    }
}

// ---------------- fused QKV GEMM (single launch, bf16 hi/lo epilogue) -----
__global__ __launch_bounds__(256) void gemm_qkv(
    const float* __restrict__ A0, const float* __restrict__ B0,
    const float* __restrict__ bias,
    u16* __restrict__ qh_o, u16* __restrict__ ql_o,
    u16* __restrict__ kh_o, u16* __restrict__ kl_o,
    u16* __restrict__ vt_o)
{
    __shared__ float As[16][68];
    __shared__ float Bs[16][64];
    const int K = DIM, M = DIM;

    const int tid  = threadIdx.x;
    const int row0 = blockIdx.y * 64;
    const int c0raw = blockIdx.x * 64;
    const int mat  = c0raw >> 8;
    const int col0 = c0raw & 255;
    const float* Bp = B0 + (size_t)mat * K * M;
    const float* biasp = bias + mat * M;

    const int ty = tid >> 4;
    const int tx = tid & 15;
    const int lrow = tid >> 2;
    const int lk4  = (tid & 3) * 4;
    const int bk   = tid >> 4;
    const int bc4  = (tid & 15) * 4;

    float acc[4][4] = {};
    float4 av, bv;
    av = *(const float4*)&A0[(size_t)(row0 + lrow) * K + lk4];
    bv = *(const float4*)&Bp[(size_t)bk * M + col0 + bc4];
    for (int k0 = 0; k0 < K; k0 += 16) {
        __syncthreads();
        As[lk4 + 0][lrow] = av.x;
        As[lk4 + 1][lrow] = av.y;
        As[lk4 + 2][lrow] = av.z;
        As[lk4 + 3][lrow] = av.w;
        *(float4*)&Bs[bk][bc4] = bv;
        if (k0 + 16 < K) {
            const int kb = k0 + 16;
            av = *(const float4*)&A0[(size_t)(row0 + lrow) * K + kb + lk4];
            bv = *(const float4*)&Bp[(size_t)(kb + bk) * M + col0 + bc4];
        }
        __syncthreads();
        #pragma unroll
        for (int kk = 0; kk < 16; ++kk) {
            float4 a = *(const float4*)&As[kk][ty * 4];
            float4 b = *(const float4*)&Bs[kk][tx * 4];
            acc[0][0] = fmaf(a.x, b.x, acc[0][0]);
            acc[0][1] = fmaf(a.x, b.y, acc[0][1]);
            acc[0][2] = fmaf(a.x, b.z, acc[0][2]);
            acc[0][3] = fmaf(a.x, b.w, acc[0][3]);
            acc[1][0] = fmaf(a.y, b.x, acc[1][0]);
            acc[1][1] = fmaf(a.y, b.y, acc[1][1]);
            acc[1][2] = fmaf(a.y, b.z, acc[1][2]);
            acc[1][3] = fmaf(a.y, b.w, acc[1][3]);
            acc[2][0] = fmaf(a.z, b.x, acc[2][0]);
            acc[2][1] = fmaf(a.z, b.y, acc[2][1]);
            acc[2][2] = fmaf(a.z, b.z, acc[2][2]);
            acc[2][3] = fmaf(a.z, b.w, acc[2][3]);
            acc[3][0] = fmaf(a.w, b.x, acc[3][0]);
            acc[3][1] = fmaf(a.w, b.y, acc[3][1]);
            acc[3][2] = fmaf(a.w, b.z, acc[3][2]);
            acc[3][3] = fmaf(a.w, b.w, acc[3][3]);
        }
    }
    if (mat < 2) {
        const float s = (mat == 0) ? 0.125f : 1.0f;
        u16* hi = (mat == 0) ? qh_o : kh_o;
        u16* lo = (mat == 0) ? ql_o : kl_o;
        #pragma unroll
        for (int i = 0; i < 4; ++i) {
            const int r = row0 + ty * 4 + i;
            const int c = col0 + tx * 4;
            u32 wh[2], wl[2];
            #pragma unroll
            for (int g = 0; g < 2; ++g) {
                float v0 = (acc[i][g * 2]     + biasp[c + g * 2])     * s;
                float v1 = (acc[i][g * 2 + 1] + biasp[c + g * 2 + 1]) * s;
                u16 h0 = f2bf(v0), h1 = f2bf(v1);
                float l0 = v0 - bf2f(h0), l1 = v1 - bf2f(h1);
                wh[g] = (u32)h0 | ((u32)h1 << 16);
                wl[g] = packbf(l0, l1);
            }
            *(uint2*)&hi[(size_t)r * DIM + c] = make_uint2(wh[0], wh[1]);
            *(uint2*)&lo[(size_t)r * DIM + c] = make_uint2(wl[0], wl[1]);
        }
    } else {
        #pragma unroll
        for (int j = 0; j < 4; ++j) {
            const int c = col0 + tx * 4 + j;
            const int r = row0 + ty * 4;
            float v0 = acc[0][j] + biasp[c];
            float v1 = acc[1][j] + biasp[c];
            float v2 = acc[2][j] + biasp[c];
            float v3 = acc[3][j] + biasp[c];
            *(uint2*)&vt_o[(size_t)c * NN + r] =
                make_uint2(packbf(v0, v1), packbf(v2, v3));
        }
    }
}

// ---------------- MFMA flash attention -----------------------------------
// 64x64 tiles; QK^T fp32-emulated via bf16 hi/lo (4 mfma passes); PV bf16.
// P stored [q][k] (stride 72 u16) so PV B-fragments are single ds_read_b128.
// LDS 38144 B; launch_bounds min=3 (VGPR 84, no spill — round-6 lesson:
// min=4 squeezed VGPR to 64 and spilled 400+MB to scratch).
#define QB 64
#define KB 64
#define NSPLIT 4
#define NKT (NN / KB)
#define KP 72

__global__ __launch_bounds__(256, 3) void attn_kernel(
    const u16* __restrict__ qhi, const u16* __restrict__ qlo,
    const u16* __restrict__ khi, const u16* __restrict__ klo,
    const u16* __restrict__ vT,
    float* __restrict__ op0, float* __restrict__ op1,
    float* __restrict__ op2, float* __restrict__ op3,
    float* __restrict__ mpart, float* __restrict__ lpart)
{
    __shared__ u16 lds[19072];            // 38144 B
    u16* Kh = lds;                        // [64][72]
    u16* Kl = lds + 4608;
    u16* Vt = lds + 9216;                 // [key][d] per-head
    u16* Pb = lds + 13824;                // [q][72]  P bf16
    u16* Qh = lds;                        // overlay: init phase only
    u16* Ql = lds + 4608;                 // overlay: init phase only
    float* fls = (float*)(lds + 18432);   // 320 floats
    float* mh0 = fls;
    float* mh1 = fls + 64;
    float* lh0 = fls + 128;
    float* lh1 = fls + 192;
    float* frow = fls + 256;

    const int tid = threadIdx.x;
    const int h   = blockIdx.y;
    const int q0  = blockIdx.x * QB;
    const int sp  = blockIdx.z;
    const int kt0 = (sp * NKT) / NSPLIT;
    const int kt1 = ((sp + 1) * NKT) / NSPLIT;

    const int w   = tid >> 6;
    const int l   = tid & 63;
    const int l15 = l & 15, h4 = l >> 4;
    const int qh  = w & 1, kh = w >> 1;

    const int lrow = tid & 63, lseg = tid >> 6;
    const int gq = h * DH + lseg * 16;

    {   // stage Q (once, into overlay region)
        const u16* s0 = qhi + (size_t)(q0 + lrow) * DIM + gq;
        const u16* s1 = qlo + (size_t)(q0 + lrow) * DIM + gq;
        uint4 a = ((const uint4*)s0)[0], b = ((const uint4*)s0)[1];
        uint4 c = ((const uint4*)s1)[0], d = ((const uint4*)s1)[1];
        *(uint4*)&Qh[lrow * KP + lseg * 16]     = a;
        *(uint4*)&Qh[lrow * KP + lseg * 16 + 8] = b;
        *(uint4*)&Ql[lrow * KP + lseg * 16]     = c;
        *(uint4*)&Ql[lrow * KP + lseg * 16 + 8] = d;
    }
    uint4 ska, skb, sla, slb, sva, svb;
    {
        const int key0 = kt0 * KB;
        const u16* s0 = khi + (size_t)(key0 + lrow) * DIM + gq;
        const u16* s1 = klo + (size_t)(key0 + lrow) * DIM + gq;
        const u16* s2 = vT + (size_t)(h * DH + lrow) * NN + key0 + lseg * 16;
        ska = ((const uint4*)s0)[0]; skb = ((const uint4*)s0)[1];
        sla = ((const uint4*)s1)[0]; slb = ((const uint4*)s1)[1];
        sva = ((const uint4*)s2)[0]; svb = ((const uint4*)s2)[1];
    }
    __syncthreads();                              // Q staged

    short8b qf[2][2][2];
    #pragma unroll
    for (int qb = 0; qb < 2; ++qb)
        #pragma unroll
        for (int kc = 0; kc < 2; ++kc) {
            const int r = qh * 32 + qb * 16 + l15;
            const int dc = kc * 32 + h4 * 8;
            qf[qb][kc][0] = *(const short8b*)&Qh[r * KP + dc];
            qf[qb][kc][1] = *(const short8b*)&Ql[r * KP + dc];
        }
    __syncthreads();                              // hoist done; overlay safe

    const f32x4 z4 = {0.f, 0.f, 0.f, 0.f};
    f32x4 oacc[2][2] = {{z4, z4}, {z4, z4}};
    float m_run[2][4], l_run[2][4];
    #pragma unroll
    for (int qb = 0; qb < 2; ++qb)
        #pragma unroll
        for (int i = 0; i < 4; ++i) { m_run[qb][i] = -3.0e38f; l_run[qb][i] = 0.f; }

    for (int kt = kt0; kt < kt1; ++kt) {
        *(uint4*)&Kh[lrow * KP + lseg * 16]     = ska;
        *(uint4*)&Kh[lrow * KP + lseg * 16 + 8] = skb;
        *(uint4*)&Kl[lrow * KP + lseg * 16]     = sla;
        *(uint4*)&Kl[lrow * KP + lseg * 16 + 8] = slb;
        *(uint4*)&Vt[lrow * KP + lseg * 16]     = sva;
        *(uint4*)&Vt[lrow * KP + lseg * 16 + 8] = svb;
        __syncthreads();                          // tile staged

        // ---- S = Q K^T (4-pass hi/lo) ----
        f32x4 sc[2][2] = {{z4, z4}, {z4, z4}};
        __builtin_amdgcn_s_setprio(1);
        #pragma unroll
        for (int kc = 0; kc < 2; ++kc) {
            short8b kfh[2], kfl[2];
            #pragma unroll
            for (int kcb = 0; kcb < 2; ++kcb) {
                const int r = kh * 32 + kcb * 16 + l15;
                const int dc = kc * 32 + h4 * 8;
                kfh[kcb] = *(const short8b*)&Kh[r * KP + dc];
                kfl[kcb] = *(const short8b*)&Kl[r * KP + dc];
            }
            #pragma unroll
            for (int qb = 0; qb < 2; ++qb)
                #pragma unroll
                for (int kcb = 0; kcb < 2; ++kcb) {
                    sc[qb][kcb] = __builtin_amdgcn_mfma_f32_16x16x32_bf16(
                        qf[qb][kc][0], kfh[kcb], sc[qb][kcb], 0, 0, 0);
                    sc[qb][kcb] = __builtin_amdgcn_mfma_f32_16x16x32_bf16(
                        qf[qb][kc][0], kfl[kcb], sc[qb][kcb], 0, 0, 0);
                    sc[qb][kcb] = __builtin_amdgcn_mfma_f32_16x16x32_bf16(
                        qf[qb][kc][1], kfh[kcb], sc[qb][kcb], 0, 0, 0);
                    sc[qb][kcb] = __builtin_amdgcn_mfma_f32_16x16x32_bf16(
                        qf[qb][kc][1], kfl[kcb], sc[qb][kcb], 0, 0, 0);
                }
        }
        __builtin_amdgcn_s_setprio(0);
        // prefetch next tile while softmax runs
        if (kt + 1 < kt1) {
            const int key0 = (kt + 1) * KB;
            const u16* s0 = khi + (size_t)(key0 + lrow) * DIM + gq;
            const u16* s1 = klo + (size_t)(key0 + lrow) * DIM + gq;
            const u16* s2 = vT + (size_t)(h * DH + lrow) * NN + key0 + lseg * 16;
            ska = ((const uint4*)s0)[0]; skb = ((const uint4*)s0)[1];
            sla = ((const uint4*)s1)[0]; slb = ((const uint4*)s1)[1];
            sva = ((const uint4*)s2)[0]; svb = ((const uint4*)s2)[1];
        }
        // ---- softmax part 1: wave-half row max ----
        float pm[2][4];
        #pragma unroll
        for (int qb = 0; qb < 2; ++qb)
            #pragma unroll
            for (int i = 0; i < 4; ++i)
                pm[qb][i] = fmaxf(sc[qb][0][i], sc[qb][1][i]);
        #pragma unroll
        for (int off = 1; off < 16; off <<= 1)
            #pragma unroll
            for (int qb = 0; qb < 2; ++qb)
                #pragma unroll
                for (int i = 0; i < 4; ++i)
                    pm[qb][i] = fmaxf(pm[qb][i], __shfl_xor(pm[qb][i], off));
        if (l15 == 0) {
            float* mh = kh ? mh1 : mh0;
            #pragma unroll
            for (int qb = 0; qb < 2; ++qb)
                #pragma unroll
                for (int i = 0; i < 4; ++i)
                    mh[qh * 32 + qb * 16 + h4 * 4 + i] = pm[qb][i];
        }
        __syncthreads();                          // mhalf visible

        // ---- softmax part 2: exp, sums, P, frow ----
        float f[2][4], lsum[2][4], p[2][2][4];
        #pragma unroll
        for (int qb = 0; qb < 2; ++qb)
            #pragma unroll
            for (int i = 0; i < 4; ++i) {
                const int r = qh * 32 + qb * 16 + h4 * 4 + i;
                const float mnew = fmaxf(m_run[qb][i], fmaxf(mh0[r], mh1[r]));
                f[qb][i] = __expf(m_run[qb][i] - mnew);
                m_run[qb][i] = mnew;
                p[qb][0][i] = __expf(sc[qb][0][i] - mnew);
                p[qb][1][i] = __expf(sc[qb][1][i] - mnew);
                float ls = p[qb][0][i] + p[qb][1][i];
                #pragma unroll
                for (int off = 1; off < 16; off <<= 1) ls += __shfl_xor(ls, off);
                lsum[qb][i] = ls;
            }
        if (l15 == 0) {
            float* lh = kh ? lh1 : lh0;
            #pragma unroll
            for (int qb = 0; qb < 2; ++qb)
                #pragma unroll
                for (int i = 0; i < 4; ++i)
                    lh[qh * 32 + qb * 16 + h4 * 4 + i] = lsum[qb][i];
            if (kh == 0)
                #pragma unroll
                for (int qb = 0; qb < 2; ++qb)
                    #pragma unroll
                    for (int i = 0; i < 4; ++i)
                        frow[qh * 32 + qb * 16 + h4 * 4 + i] = f[qb][i];
        }
        // P store: [q][k] layout, 16 scalar u16 stores
        #pragma unroll
        for (int qb = 0; qb < 2; ++qb)
            #pragma unroll
            for (int kcb = 0; kcb < 2; ++kcb) {
                const int kk = kh * 32 + kcb * 16 + l15;
                #pragma unroll
                for (int i = 0; i < 4; ++i)
                    Pb[(qh * 32 + qb * 16 + h4 * 4 + i) * KP + kk] =
                        f2bf(p[qb][kcb][i]);
            }
        __syncthreads();                          // P, frow, lhalf visible

        {   // running denominator
            const float* lhx = kh ? lh0 : lh1;
            #pragma unroll
            for (int qb = 0; qb < 2; ++qb)
                #pragma unroll
                for (int i = 0; i < 4; ++i) {
                    const int r = qh * 32 + qb * 16 + h4 * 4 + i;
                    l_run[qb][i] = l_run[qb][i] * f[qb][i] + lsum[qb][i] + lhx[r];
                }
        }

        // ---- PV: o^T += V^T * P^T (P fragments = single b128 reads) ----
        float fq[2];
        #pragma unroll
        for (int qb = 0; qb < 2; ++qb) fq[qb] = frow[qh * 32 + qb * 16 + l15];
        #pragma unroll
        for (int db = 0; db < 2; ++db)
            #pragma unroll
            for (int qb = 0; qb < 2; ++qb)
                oacc[db][qb] *= fq[qb];
        __builtin_amdgcn_s_setprio(1);
        #pragma unroll
        for (int kc = 0; kc < 2; ++kc) {
            short8b vf[2], pf[2];
            #pragma unroll
            for (int db = 0; db < 2; ++db)
                vf[db] = *(const short8b*)&Vt[(kh * 32 + db * 16 + l15) * KP + kc * 32 + h4 * 8];
            #pragma unroll
            for (int qb = 0; qb < 2; ++qb)
                pf[qb] = *(const short8b*)&Pb[(qh * 32 + qb * 16 + l15) * KP + kc * 32 + h4 * 8];
            #pragma unroll
            for (int db = 0; db < 2; ++db)
                #pragma unroll
                for (int qb = 0; qb < 2; ++qb)
                    oacc[db][qb] = __builtin_amdgcn_mfma_f32_16x16x32_bf16(
                        vf[db], pf[qb], oacc[db][qb], 0, 0, 0);
        }
        __builtin_amdgcn_s_setprio(0);
        __syncthreads();                          // PV done, buffers free
    }

    float* ob = (sp == 0) ? op0 : ((sp == 1) ? op1 : ((sp == 2) ? op2 : op3));
    #pragma unroll
    for (int db = 0; db < 2; ++db)
        #pragma unroll
        for (int qb = 0; qb < 2; ++qb) {
            const int qq = q0 + qh * 32 + qb * 16 + l15;
            const int d0 = h * DH + kh * 32 + db * 16 + h4 * 4;
            *(f32x4*)&ob[(size_t)qq * DIM + d0] = oacc[db][qb];
        }
    if (kh == 0 && l15 == 0) {
        #pragma unroll
        for (int qb = 0; qb < 2; ++qb)
            #pragma unroll
            for (int i = 0; i < 4; ++i) {
                const int r = qh * 32 + qb * 16 + h4 * 4 + i;
                mpart[((size_t)sp * NN + q0 + r) * NH + h] = m_run[qb][i];
                lpart[((size_t)sp * NN + q0 + r) * NH + h] = l_run[qb][i];
            }
    }
}

// merge the 4 partials (in-place into o0 is safe: thread-private float4s)
__global__ __launch_bounds__(256) void attn_combine(
    const float* o0, const float* __restrict__ o1,
    const float* __restrict__ o2, const float* __restrict__ o3,
    const float* __restrict__ mp, const float* __restrict__ lp,
    float* out)
{
    const int gid = blockIdx.x * 256 + threadIdx.x;
    const int row = gid >> 6;
    const int c4  = (gid & 63) * 4;
    const int h   = c4 >> 6;
    float m[4], wgt[4];
    #pragma unroll
    for (int z = 0; z < 4; ++z) m[z] = mp[((size_t)z * NN + row) * NH + h];
    const float M = fmaxf(fmaxf(m[0], m[1]), fmaxf(m[2], m[3]));
    float den = 0.f;
    #pragma unroll
    for (int z = 0; z < 4; ++z) {
        wgt[z] = __expf(m[z] - M);
        den += lp[((size_t)z * NN + row) * NH + h] * wgt[z];
    }
    const float inv = 1.f / den;
    const float4 a = *(const float4*)&o0[(size_t)row * DIM + c4];
    const float4 b = *(const float4*)&o1[(size_t)row * DIM + c4];
    const float4 c = *(const float4*)&o2[(size_t)row * DIM + c4];
    const float4 d = *(const float4*)&o3[(size_t)row * DIM + c4];
    float4 r;
    r.x = (a.x * wgt[0] + b.x * wgt[1] + c.x * wgt[2] + d.x * wgt[3]) * inv;
    r.y = (a.y * wgt[0] + b.y * wgt[1] + c.y * wgt[2] + d.y * wgt[3]) * inv;
    r.z = (a.z * wgt[0] + b.z * wgt[1] + c.z * wgt[2] + d.z * wgt[3]) * inv;
    r.w = (a.w * wgt[0] + b.w * wgt[1] + c.w * wgt[2] + d.w * wgt[3]) * inv;
    *(float4*)&out[(size_t)row * DIM + c4] = r;
}

// ---------------- per-node group adapter ----------------
__global__ __launch_bounds__(64) void adapter_kernel(
    const float* __restrict__ feats, const int* __restrict__ grp,
    const float* __restrict__ AW1, const float* __restrict__ Ab1,
    const float* __restrict__ AW2, const float* __restrict__ Ab2,
    float* __restrict__ out)
{
    const int n = blockIdx.x;
    const int lane = threadIdx.x;
    __shared__ float f[F1D];
    f[lane]      = feats[(size_t)n * F1D + lane];
    f[lane + 64] = feats[(size_t)n * F1D + 64 + lane];
    __syncthreads();
    const int g = grp[n];
    const float* W1 = AW1 + (size_t)g * F1D * AD;
    const int a = lane & 31;
    const int half = lane >> 5;
    float hsum = 0.f;
    for (int d = 0; d < 64; ++d)
        hsum = fmaf(f[half * 64 + d], W1[(half * 64 + d) * AD + a], hsum);
    hsum += __shfl_xor(hsum, 32);
    hsum = fmaxf(hsum + Ab1[g * AD + a], 0.f);
    float p = hsum * AW2[g * AD + a];
    #pragma unroll
    for (int mm = 1; mm < 32; mm <<= 1) p += __shfl_xor(p, mm);
    if (lane == 0) out[n] = p + Ab2[g];
}

// ---------------- host-side orchestration ----------------
extern "C" void kernel_launch(void* const* d_in, const int* in_sizes, int n_in,
                              void* d_out, int out_size, void* d_ws, size_t ws_size,
                              hipStream_t stream)
{
    const float* x_in   = (const float*)d_in[0];
    const float* eattr  = (const float*)d_in[1];
    const float* Wself  = (const float*)d_in[2];
    const float* Wnbr   = (const float*)d_in[3];
    const float* convb  = (const float*)d_in[4];
    const float* gamma  = (const float*)d_in[5];
    const float* beta   = (const float*)d_in[6];
    const float* bnmean = (const float*)d_in[7];
    const float* bnvar  = (const float*)d_in[8];
    const float* Wqkv   = (const float*)d_in[9];
    const float* bqkv   = (const float*)d_in[10];
    const float* Wo     = (const float*)d_in[11];
    const float* bo     = (const float*)d_in[12];
    const float* fc1W   = (const float*)d_in[13];
    const float* fc1b   = (const float*)d_in[14];
    const float* AW1    = (const float*)d_in[15];
    const float* Ab1    = (const float*)d_in[16];
    const float* AW2    = (const float*)d_in[17];
    const float* Ab2    = (const float*)d_in[18];
    const int*   eidx   = (const int*)d_in[19];
    const int*   grp    = (const int*)d_in[20];
    const int* srcArr = eidx;
    const int* dstArr = eidx + NE;

    float* fws = (float*)d_ws;
    const size_t NM = (size_t)NN * DIM;
    float* bufA  = fws;                  // conv x / residual
    float* bufB  = fws + NM;             // agg / attn op0 / combined o
    float* bufC  = fws + 2 * NM;         // x L1 / op1
    float* bufD  = fws + 3 * NM;         // op2
    float* bufE  = fws + 4 * NM;         // op3 / Wo out
    float* feats = fws + 5 * NM;         // NN x F1D
    float* mpart = fws + 5 * NM + NM / 2;         // [4][NN][NH]
    float* lpart = mpart + 4 * NN * NH;
    u16* qhi = (u16*)(lpart + 4 * NN * NH);       // NN*DIM u16 each
    u16* qlo = qhi + NM;
    u16* khi = qlo + NM;
    u16* klo = khi + NM;
    u16* vt  = klo + NM;                          // [DIM][NN]
    int*   esrc = (int*)(vt + NM);                // NE
    float* ewt  = (float*)(esrc + NE);            // NE
    int* off    = (int*)(ewt + NE);               // NN+1
    int* cur    = off + NN + 1;                   // NN
    float* outp = (float*)d_out;

    // CSR build
    hipMemsetAsync(cur, 0, NN * sizeof(int), stream);
    csr_count<<<NE / 256, 256, 0, stream>>>(dstArr, cur);
    csr_scan<<<1, 64, 0, stream>>>(cur, off);
    hipMemsetAsync(cur, 0, NN * sizeof(int), stream);
    csr_fill<<<NE / 256, 256, 0, stream>>>(dstArr, srcArr, eattr, off, cur, esrc, ewt);

    const dim3 gg(DIM / 64, NN / 64);
    const int rgrid = NN * DIM / 4 / 256;

    // conv layer 0: x_in -> bufA
    agg_kernel<false><<<NN / 4, 256, 0, stream>>>(x_in, esrc, ewt, off, bufB);
    gemm_kernel<EPI_BNELU, true><<<gg, 512, 0, stream>>>(
        x_in, Wself, bufB, Wnbr, convb, gamma, beta, bnmean, bnvar,
        nullptr, bufA, DIM, DIM);
    // conv layer 1: bufA -> bufC
    agg_kernel<false><<<NN / 4, 256, 0, stream>>>(bufA, esrc, ewt, off, bufB);
    gemm_kernel<EPI_BNELU, true><<<gg, 512, 0, stream>>>(
        bufA, Wself + DIM * DIM, bufB, Wnbr + DIM * DIM, convb + DIM,
        gamma + DIM, beta + DIM, bnmean + DIM, bnvar + DIM,
        nullptr, bufC, DIM, DIM);
    // conv layer 2 (edge-weighted): bufC -> bufA
    agg_kernel<true><<<NN / 4, 256, 0, stream>>>(bufC, esrc, ewt, off, bufB);
    gemm_kernel<EPI_BIAS, true><<<gg, 512, 0, stream>>>(
        bufC, Wself + 2 * DIM * DIM, bufB, Wnbr + 2 * DIM * DIM, convb + 2 * DIM,
        nullptr, nullptr, nullptr, nullptr, nullptr, bufA, DIM, DIM);

    // fused QKV projection -> bf16 hi/lo Q,K + V^T
    gemm_qkv<<<dim3(3 * DIM / 64, NN / 64), 256, 0, stream>>>(
        bufA, Wqkv, bqkv, qhi, qlo, khi, klo, vt);

    // MFMA flash attention (4-way key split) -> partials, combine -> bufB
    attn_kernel<<<dim3(NN / QB, NH, NSPLIT), 256, 0, stream>>>(
        qhi, qlo, khi, klo, vt, bufB, bufC, bufD, bufE, mpart, lpart);
    attn_combine<<<rgrid, 256, 0, stream>>>(
        bufB, bufC, bufD, bufE, mpart, lpart, bufB);

    // output projection + residual: bufE = bufA + bufB @ Wo + bo
    gemm_kernel<EPI_BIAS_RES, false><<<gg, 512, 0, stream>>>(
        bufB, Wo, nullptr, nullptr, bo,
        nullptr, nullptr, nullptr, nullptr, bufA, bufE, DIM, DIM);

    // fc1 + ELU: feats = elu(bufE @ fc1W + fc1b)
    gemm_kernel<EPI_BIAS_ELU, false><<<dim3(F1D / 64, NN / 64), 512, 0, stream>>>(
        bufE, fc1W, nullptr, nullptr, fc1b,
        nullptr, nullptr, nullptr, nullptr, nullptr, feats, DIM, F1D);

    // adapter routing -> out
    adapter_kernel<<<NN, 64, 0, stream>>>(feats, grp, AW1, Ab1, AW2, Ab2, outp);
}

// Round 9
// 309.930 us; speedup vs baseline: 1.0879x; 1.0879x over previous
//
#include <hip/hip_runtime.h>
#include <math.h>

#define NN   4096
#define DIM  256
#define NE   131072
#define NH   4
#define DH   64
#define F1D  128
#define NG   16
#define AD   32

typedef unsigned short u16;
typedef unsigned int   u32;
typedef __attribute__((ext_vector_type(8))) short short8b;
typedef __attribute__((ext_vector_type(4))) float f32x4;

enum { EPI_BIAS = 0, EPI_BNELU = 1, EPI_BIAS_ELU = 2, EPI_BIAS_RES = 3 };
enum { MEPI_WO = 0, MEPI_FC1 = 1 };

__device__ inline u16 f2bf(float x) {
    u32 u = __float_as_uint(x);
    u += 0x7fffu + ((u >> 16) & 1u);
    return (u16)(u >> 16);
}
__device__ inline float bf2f(u16 h) {
    return __uint_as_float(((u32)h) << 16);
}
__device__ inline u32 packbf(float a, float b) {
    return (u32)f2bf(a) | ((u32)f2bf(b) << 16);
}

// ---------------- CSR build ----------------
__global__ void csr_count(const int* __restrict__ dst, int* __restrict__ cnt) {
    int e = blockIdx.x * 256 + threadIdx.x;
    atomicAdd(&cnt[dst[e]], 1);
}

__global__ void csr_scan(const int* __restrict__ cnt, int* __restrict__ off) {
    int lane = threadIdx.x;
    int base = lane * (NN / 64);
    int s = 0;
    for (int i = 0; i < NN / 64; ++i) s += cnt[base + i];
    int acc = s;
    #pragma unroll
    for (int o = 1; o < 64; o <<= 1) {
        int t = __shfl_up(acc, o);
        if (lane >= o) acc += t;
    }
    int run = acc - s;
    for (int i = 0; i < NN / 64; ++i) { off[base + i] = run; run += cnt[base + i]; }
    if (lane == 63) off[NN] = run;
}

__global__ void csr_fill(const int* __restrict__ dst, const int* __restrict__ src,
                         const float* __restrict__ eattr, const int* __restrict__ off,
                         int* __restrict__ cur, int* __restrict__ esrc,
                         float* __restrict__ ewt) {
    int e = blockIdx.x * 256 + threadIdx.x;
    int d = dst[e];
    int pos = off[d] + atomicAdd(&cur[d], 1);
    esrc[pos] = src[e];
    ewt[pos]  = eattr[e];
}

// ---------------- weight transpose + hi/lo bf16 convert -------------------
// W[K][M] fp32 -> Wt_h/Wt_l[M][K] bf16.
__global__ __launch_bounds__(256) void wconvert(
    const float* __restrict__ W, u16* __restrict__ Wth, u16* __restrict__ Wtl,
    int K, int M)
{
    const int gid = blockIdx.x * 256 + threadIdx.x;
    const int kq = K / 4;
    const int m  = gid / kq;
    const int k4 = (gid % kq) * 4;
    u16 h[4]; float l[4];
    #pragma unroll
    for (int j = 0; j < 4; ++j) {
        const float v = W[(size_t)(k4 + j) * M + m];
        h[j] = f2bf(v);
        l[j] = v - bf2f(h[j]);
    }
    *(uint2*)&Wth[(size_t)m * K + k4] =
        make_uint2((u32)h[0] | ((u32)h[1] << 16), (u32)h[2] | ((u32)h[3] << 16));
    *(uint2*)&Wtl[(size_t)m * K + k4] =
        make_uint2(packbf(l[0], l[1]), packbf(l[2], l[3]));
}

// ---------------- neighbor aggregation: 1 wave per node -------------------
template<bool LAST>
__global__ __launch_bounds__(256) void agg_kernel(
    const float* __restrict__ x, const int* __restrict__ esrc,
    const float* __restrict__ ewt, const int* __restrict__ off,
    float* __restrict__ agg)
{
    const int node = blockIdx.x * 4 + (threadIdx.x >> 6);
    const int lane = threadIdx.x & 63;
    const int d4 = lane * 4;
    int j = off[node];
    const int j1 = off[node + 1];
    float4 acc = make_float4(0.f, 0.f, 0.f, 0.f);
    for (; j + 4 <= j1; j += 4) {
        const int s0 = esrc[j], s1 = esrc[j + 1], s2 = esrc[j + 2], s3 = esrc[j + 3];
        const float4 x0 = *(const float4*)&x[(size_t)s0 * DIM + d4];
        const float4 x1 = *(const float4*)&x[(size_t)s1 * DIM + d4];
        const float4 x2 = *(const float4*)&x[(size_t)s2 * DIM + d4];
        const float4 x3 = *(const float4*)&x[(size_t)s3 * DIM + d4];
        const float w0 = LAST ? ewt[j]     : 1.f;
        const float w1 = LAST ? ewt[j + 1] : 1.f;
        const float w2 = LAST ? ewt[j + 2] : 1.f;
        const float w3 = LAST ? ewt[j + 3] : 1.f;
        acc.x = fmaf(x0.x, w0, acc.x); acc.y = fmaf(x0.y, w0, acc.y);
        acc.z = fmaf(x0.z, w0, acc.z); acc.w = fmaf(x0.w, w0, acc.w);
        acc.x = fmaf(x1.x, w1, acc.x); acc.y = fmaf(x1.y, w1, acc.y);
        acc.z = fmaf(x1.z, w1, acc.z); acc.w = fmaf(x1.w, w1, acc.w);
        acc.x = fmaf(x2.x, w2, acc.x); acc.y = fmaf(x2.y, w2, acc.y);
        acc.z = fmaf(x2.z, w2, acc.z); acc.w = fmaf(x2.w, w2, acc.w);
        acc.x = fmaf(x3.x, w3, acc.x); acc.y = fmaf(x3.y, w3, acc.y);
        acc.z = fmaf(x3.z, w3, acc.z); acc.w = fmaf(x3.w, w3, acc.w);
    }
    for (; j < j1; ++j) {
        const int s = esrc[j];
        const float w = LAST ? ewt[j] : 1.f;
        const float4 xv = *(const float4*)&x[(size_t)s * DIM + d4];
        acc.x = fmaf(xv.x, w, acc.x); acc.y = fmaf(xv.y, w, acc.y);
        acc.z = fmaf(xv.z, w, acc.z); acc.w = fmaf(xv.w, w, acc.w);
    }
    *(float4*)&agg[(size_t)node * DIM + d4] = acc;
}

// ---------------- fp32 tiled GEMM, 64x64 tile, BK=16, register prefetch ---
// (round-7 proven version; used for the 3 conv layers that feed the
// attention scores and therefore must stay fp32-accurate)
template<int EPI, bool DUAL>
__global__ __launch_bounds__(256) void gemm_kernel(
    const float* __restrict__ A0, const float* __restrict__ B0,
    const float* __restrict__ A1, const float* __restrict__ B1,
    const float* __restrict__ bias,
    const float* __restrict__ gamma, const float* __restrict__ beta,
    const float* __restrict__ bnmean, const float* __restrict__ bnvar,
    const float* __restrict__ resid,
    float* __restrict__ out, int K, int M)
{
    __shared__ float As[16][68];
    __shared__ float Bs[16][64];

    const int tid  = threadIdx.x;
    const int row0 = blockIdx.y * 64;
    const int col0 = blockIdx.x * 64;

    const int ty = tid >> 4;
    const int tx = tid & 15;
    const int lrow = tid >> 2;
    const int lk4  = (tid & 3) * 4;
    const int bk   = tid >> 4;
    const int bc4  = (tid & 15) * 4;

    float acc[4][4] = {};
    const int kTot = DUAL ? 2 * K : K;

    float4 av, bv;
    av = *(const float4*)&A0[(size_t)(row0 + lrow) * K + lk4];
    bv = *(const float4*)&B0[(size_t)bk * M + col0 + bc4];
    for (int k0 = 0; k0 < kTot; k0 += 16) {
        __syncthreads();
        As[lk4 + 0][lrow] = av.x;
        As[lk4 + 1][lrow] = av.y;
        As[lk4 + 2][lrow] = av.z;
        As[lk4 + 3][lrow] = av.w;
        *(float4*)&Bs[bk][bc4] = bv;
        if (k0 + 16 < kTot) {
            const int kn = k0 + 16;
            const bool ph1 = DUAL && (kn >= K);
            const float* A = ph1 ? A1 : A0;
            const float* B = ph1 ? B1 : B0;
            const int kb = ph1 ? (kn - K) : kn;
            av = *(const float4*)&A[(size_t)(row0 + lrow) * K + kb + lk4];
            bv = *(const float4*)&B[(size_t)(kb + bk) * M + col0 + bc4];
        }
        __syncthreads();
        #pragma unroll
        for (int kk = 0; kk < 16; ++kk) {
            float4 a = *(const float4*)&As[kk][ty * 4];
            float4 b = *(const float4*)&Bs[kk][tx * 4];
            acc[0][0] = fmaf(a.x, b.x, acc[0][0]);
            acc[0][1] = fmaf(a.x, b.y, acc[0][1]);
            acc[0][2] = fmaf(a.x, b.z, acc[0][2]);
            acc[0][3] = fmaf(a.x, b.w, acc[0][3]);
            acc[1][0] = fmaf(a.y, b.x, acc[1][0]);
            acc[1][1] = fmaf(a.y, b.y, acc[1][1]);
            acc[1][2] = fmaf(a.y, b.z, acc[1][2]);
            acc[1][3] = fmaf(a.y, b.w, acc[1][3]);
            acc[2][0] = fmaf(a.z, b.x, acc[2][0]);
            acc[2][1] = fmaf(a.z, b.y, acc[2][1]);
            acc[2][2] = fmaf(a.z, b.z, acc[2][2]);
            acc[2][3] = fmaf(a.z, b.w, acc[2][3]);
            acc[3][0] = fmaf(a.w, b.x, acc[3][0]);
            acc[3][1] = fmaf(a.w, b.y, acc[3][1]);
            acc[3][2] = fmaf(a.w, b.z, acc[3][2]);
            acc[3][3] = fmaf(a.w, b.w, acc[3][3]);
        }
    }
    #pragma unroll
    for (int i = 0; i < 4; ++i) {
        const int r = row0 + ty * 4 + i;
        #pragma unroll
        for (int j = 0; j < 4; ++j) {
            const int c = col0 + tx * 4 + j;
            float v = acc[i][j] + bias[c];
            if (EPI == EPI_BNELU) {
                v = gamma[c] * (v - bnmean[c]) * rsqrtf(bnvar[c] + 1e-5f) + beta[c];
                v = v > 0.f ? v : expm1f(v);
            } else if (EPI == EPI_BIAS_ELU) {
                v = v > 0.f ? v : expm1f(v);
            } else if (EPI == EPI_BIAS_RES) {
                v += resid[(size_t)r * M + c];
            }
            out[(size_t)r * M + c] = v;
        }
    }
}

// ---------------- fused QKV GEMM (single launch, bf16 hi/lo epilogue) -----
__global__ __launch_bounds__(256) void gemm_qkv(
    const float* __restrict__ A0, const float* __restrict__ B0,
    const float* __restrict__ bias,
    u16* __restrict__ qh_o, u16* __restrict__ ql_o,
    u16* __restrict__ kh_o, u16* __restrict__ kl_o,
    u16* __restrict__ vt_o)
{
    __shared__ float As[16][68];
    __shared__ float Bs[16][64];
    const int K = DIM, M = DIM;

    const int tid  = threadIdx.x;
    const int row0 = blockIdx.y * 64;
    const int c0raw = blockIdx.x * 64;
    const int mat  = c0raw >> 8;
    const int col0 = c0raw & 255;
    const float* Bp = B0 + (size_t)mat * K * M;
    const float* biasp = bias + mat * M;

    const int ty = tid >> 4;
    const int tx = tid & 15;
    const int lrow = tid >> 2;
    const int lk4  = (tid & 3) * 4;
    const int bk   = tid >> 4;
    const int bc4  = (tid & 15) * 4;

    float acc[4][4] = {};
    float4 av, bv;
    av = *(const float4*)&A0[(size_t)(row0 + lrow) * K + lk4];
    bv = *(const float4*)&Bp[(size_t)bk * M + col0 + bc4];
    for (int k0 = 0; k0 < K; k0 += 16) {
        __syncthreads();
        As[lk4 + 0][lrow] = av.x;
        As[lk4 + 1][lrow] = av.y;
        As[lk4 + 2][lrow] = av.z;
        As[lk4 + 3][lrow] = av.w;
        *(float4*)&Bs[bk][bc4] = bv;
        if (k0 + 16 < K) {
            const int kb = k0 + 16;
            av = *(const float4*)&A0[(size_t)(row0 + lrow) * K + kb + lk4];
            bv = *(const float4*)&Bp[(size_t)(kb + bk) * M + col0 + bc4];
        }
        __syncthreads();
        #pragma unroll
        for (int kk = 0; kk < 16; ++kk) {
            float4 a = *(const float4*)&As[kk][ty * 4];
            float4 b = *(const float4*)&Bs[kk][tx * 4];
            acc[0][0] = fmaf(a.x, b.x, acc[0][0]);
            acc[0][1] = fmaf(a.x, b.y, acc[0][1]);
            acc[0][2] = fmaf(a.x, b.z, acc[0][2]);
            acc[0][3] = fmaf(a.x, b.w, acc[0][3]);
            acc[1][0] = fmaf(a.y, b.x, acc[1][0]);
            acc[1][1] = fmaf(a.y, b.y, acc[1][1]);
            acc[1][2] = fmaf(a.y, b.z, acc[1][2]);
            acc[1][3] = fmaf(a.y, b.w, acc[1][3]);
            acc[2][0] = fmaf(a.z, b.x, acc[2][0]);
            acc[2][1] = fmaf(a.z, b.y, acc[2][1]);
            acc[2][2] = fmaf(a.z, b.z, acc[2][2]);
            acc[2][3] = fmaf(a.z, b.w, acc[2][3]);
            acc[3][0] = fmaf(a.w, b.x, acc[3][0]);
            acc[3][1] = fmaf(a.w, b.y, acc[3][1]);
            acc[3][2] = fmaf(a.w, b.z, acc[3][2]);
            acc[3][3] = fmaf(a.w, b.w, acc[3][3]);
        }
    }
    if (mat < 2) {
        const float s = (mat == 0) ? 0.125f : 1.0f;
        u16* hi = (mat == 0) ? qh_o : kh_o;
        u16* lo = (mat == 0) ? ql_o : kl_o;
        #pragma unroll
        for (int i = 0; i < 4; ++i) {
            const int r = row0 + ty * 4 + i;
            const int c = col0 + tx * 4;
            u32 wh[2], wl[2];
            #pragma unroll
            for (int g = 0; g < 2; ++g) {
                float v0 = (acc[i][g * 2]     + biasp[c + g * 2])     * s;
                float v1 = (acc[i][g * 2 + 1] + biasp[c + g * 2 + 1]) * s;
                u16 h0 = f2bf(v0), h1 = f2bf(v1);
                float l0 = v0 - bf2f(h0), l1 = v1 - bf2f(h1);
                wh[g] = (u32)h0 | ((u32)h1 << 16);
                wl[g] = packbf(l0, l1);
            }
            *(uint2*)&hi[(size_t)r * DIM + c] = make_uint2(wh[0], wh[1]);
            *(uint2*)&lo[(size_t)r * DIM + c] = make_uint2(wl[0], wl[1]);
        }
    } else {
        #pragma unroll
        for (int j = 0; j < 4; ++j) {
            const int c = col0 + tx * 4 + j;
            const int r = row0 + ty * 4;
            float v0 = acc[0][j] + biasp[c];
            float v1 = acc[1][j] + biasp[c];
            float v2 = acc[2][j] + biasp[c];
            float v3 = acc[3][j] + biasp[c];
            *(uint2*)&vt_o[(size_t)c * NN + r] =
                make_uint2(packbf(v0, v1), packbf(v2, v3));
        }
    }
}

// ---------------- MFMA hi/lo GEMM (post-softmax dense layers) -------------
// C[N][M] = A[N][K] @ B[K][M], A given hi/lo bf16 row-major, B given as
// transposed hi/lo bf16 Bt[M][K]. 4-pass emulation (~1e-5 relative — safe
// for post-softmax layers). 64x64 tile, K-step 64, 4 waves (quadrants).
template<int MEPI>
__global__ __launch_bounds__(256) void mfma_gemm(
    const u16* __restrict__ Ah, const u16* __restrict__ Al,
    const u16* __restrict__ Bth, const u16* __restrict__ Btl,
    const float* __restrict__ bias, const float* __restrict__ resid,
    float* __restrict__ outf, u16* __restrict__ outh, u16* __restrict__ outl,
    int K, int M)
{
    __shared__ u16 lds[4 * 4608];        // Ah,Al,Bh,Bl tiles [64][72]
    u16* As_h = lds;
    u16* As_l = lds + 4608;
    u16* Bs_h = lds + 9216;
    u16* Bs_l = lds + 13824;
    #define TKP 72

    const int tid  = threadIdx.x;
    const int row0 = blockIdx.y * 64;
    const int col0 = blockIdx.x * 64;

    const int w   = tid >> 6;
    const int l15 = tid & 15, h4 = (tid & 63) >> 4;
    const int rh  = w & 1, ch = w >> 1;

    const int lrow = tid & 63, lseg = tid >> 6;
    const int lc = lseg * 16;

    uint4 sah0, sah1, sal0, sal1, sbh0, sbh1, sbl0, sbl1;
    {
        const u16* pa0 = Ah  + (size_t)(row0 + lrow) * K + lc;
        const u16* pa1 = Al  + (size_t)(row0 + lrow) * K + lc;
        const u16* pb0 = Bth + (size_t)(col0 + lrow) * K + lc;
        const u16* pb1 = Btl + (size_t)(col0 + lrow) * K + lc;
        sah0 = ((const uint4*)pa0)[0]; sah1 = ((const uint4*)pa0)[1];
        sal0 = ((const uint4*)pa1)[0]; sal1 = ((const uint4*)pa1)[1];
        sbh0 = ((const uint4*)pb0)[0]; sbh1 = ((const uint4*)pb0)[1];
        sbl0 = ((const uint4*)pb1)[0]; sbl1 = ((const uint4*)pb1)[1];
    }

    const f32x4 z4 = {0.f, 0.f, 0.f, 0.f};
    f32x4 acc[2][2] = {{z4, z4}, {z4, z4}};
    const int NKT = K / 64;

    for (int kt = 0; kt < NKT; ++kt) {
        *(uint4*)&As_h[lrow * TKP + lc]     = sah0;
        *(uint4*)&As_h[lrow * TKP + lc + 8] = sah1;
        *(uint4*)&As_l[lrow * TKP + lc]     = sal0;
        *(uint4*)&As_l[lrow * TKP + lc + 8] = sal1;
        *(uint4*)&Bs_h[lrow * TKP + lc]     = sbh0;
        *(uint4*)&Bs_h[lrow * TKP + lc + 8] = sbh1;
        *(uint4*)&Bs_l[lrow * TKP + lc]     = sbl0;
        *(uint4*)&Bs_l[lrow * TKP + lc + 8] = sbl1;
        __syncthreads();

        __builtin_amdgcn_s_setprio(1);
        #pragma unroll
        for (int kc = 0; kc < 2; ++kc) {
            const int dc = kc * 32 + h4 * 8;
            short8b afh[2], afl[2], bfh[2], bfl[2];
            #pragma unroll
            for (int ab = 0; ab < 2; ++ab) {
                const int r = rh * 32 + ab * 16 + l15;
                afh[ab] = *(const short8b*)&As_h[r * TKP + dc];
                afl[ab] = *(const short8b*)&As_l[r * TKP + dc];
            }
            #pragma unroll
            for (int bb = 0; bb < 2; ++bb) {
                const int r = ch * 32 + bb * 16 + l15;
                bfh[bb] = *(const short8b*)&Bs_h[r * TKP + dc];
                bfl[bb] = *(const short8b*)&Bs_l[r * TKP + dc];
            }
            #pragma unroll
            for (int ab = 0; ab < 2; ++ab)
                #pragma unroll
                for (int bb = 0; bb < 2; ++bb) {
                    acc[ab][bb] = __builtin_amdgcn_mfma_f32_16x16x32_bf16(
                        afh[ab], bfh[bb], acc[ab][bb], 0, 0, 0);
                    acc[ab][bb] = __builtin_amdgcn_mfma_f32_16x16x32_bf16(
                        afh[ab], bfl[bb], acc[ab][bb], 0, 0, 0);
                    acc[ab][bb] = __builtin_amdgcn_mfma_f32_16x16x32_bf16(
                        afl[ab], bfh[bb], acc[ab][bb], 0, 0, 0);
                    acc[ab][bb] = __builtin_amdgcn_mfma_f32_16x16x32_bf16(
                        afl[ab], bfl[bb], acc[ab][bb], 0, 0, 0);
                }
        }
        __builtin_amdgcn_s_setprio(0);
        if (kt + 1 < NKT) {
            const int kb = (kt + 1) * 64 + lc;
            const u16* pa0 = Ah  + (size_t)(row0 + lrow) * K + kb;
            const u16* pa1 = Al  + (size_t)(row0 + lrow) * K + kb;
            const u16* pb0 = Bth + (size_t)(col0 + lrow) * K + kb;
            const u16* pb1 = Btl + (size_t)(col0 + lrow) * K + kb;
            sah0 = ((const uint4*)pa0)[0]; sah1 = ((const uint4*)pa0)[1];
            sal0 = ((const uint4*)pa1)[0]; sal1 = ((const uint4*)pa1)[1];
            sbh0 = ((const uint4*)pb0)[0]; sbh1 = ((const uint4*)pb0)[1];
            sbl0 = ((const uint4*)pb1)[0]; sbl1 = ((const uint4*)pb1)[1];
        }
        __syncthreads();
    }

    // epilogue: fragment (ab,bb): col = col0+ch*32+bb*16+l15 (fixed per lane),
    // rows = row0+rh*32+ab*16+h4*4+i
    #pragma unroll
    for (int ab = 0; ab < 2; ++ab)
        #pragma unroll
        for (int bb = 0; bb < 2; ++bb) {
            const int c  = col0 + ch * 32 + bb * 16 + l15;
            const int r0 = row0 + rh * 32 + ab * 16 + h4 * 4;
            #pragma unroll
            for (int i = 0; i < 4; ++i) {
                const int r = r0 + i;
                float t = acc[ab][bb][i] + bias[c];
                if (MEPI == MEPI_WO) {
                    t += resid[(size_t)r * M + c];
                    const u16 h = f2bf(t);
                    outh[(size_t)r * M + c] = h;
                    outl[(size_t)r * M + c] = f2bf(t - bf2f(h));
                } else {    // FC1: bias + ELU -> fp32 feats
                    t = t > 0.f ? t : expm1f(t);
                    outf[(size_t)r * M + c] = t;
                }
            }
        }
    #undef TKP
}

// ---------------- MFMA flash attention -----------------------------------
// 64x64 tiles; QK^T fp32-emulated via bf16 hi/lo (4 mfma passes); PV bf16.
// Round-9 restructure: QK^T wave w owns q-rows w*16..w*16+15 x all 64 k
// -> softmax is fully wave-local (no cross-wave m/l exchange, 3 barriers
// per tile instead of 4). PV keeps the quadrant split.
#define QB 64
#define KB 64
#define NSPLIT 4
#define NKT (NN / KB)
#define KP 72

__global__ __launch_bounds__(256, 3) void attn_kernel(
    const u16* __restrict__ qhi, const u16* __restrict__ qlo,
    const u16* __restrict__ khi, const u16* __restrict__ klo,
    const u16* __restrict__ vT,
    float* __restrict__ op0, float* __restrict__ op1,
    float* __restrict__ op2, float* __restrict__ op3,
    float* __restrict__ mpart, float* __restrict__ lpart)
{
    __shared__ u16 lds[18560];            // 37120 B
    u16* Kh = lds;                        // [64][72]
    u16* Kl = lds + 4608;
    u16* Vt = lds + 9216;                 // [key][d] per-head
    u16* Pb = lds + 13824;                // [q][72]  P bf16
    u16* Qh = lds;                        // overlay: init phase only
    u16* Ql = lds + 4608;                 // overlay: init phase only
    float* frow = (float*)(lds + 18432);  // [64] rescale factors

    const int tid = threadIdx.x;
    const int h   = blockIdx.y;
    const int q0  = blockIdx.x * QB;
    const int sp  = blockIdx.z;
    const int kt0 = (sp * NKT) / NSPLIT;
    const int kt1 = ((sp + 1) * NKT) / NSPLIT;

    const int w   = tid >> 6;
    const int l   = tid & 63;
    const int l15 = l & 15, h4 = l >> 4;
    const int qh  = w & 1, kh = w >> 1;   // PV quadrant mapping

    const int lrow = tid & 63, lseg = tid >> 6;
    const int gq = h * DH + lseg * 16;

    {   // stage Q (once, into overlay region)
        const u16* s0 = qhi + (size_t)(q0 + lrow) * DIM + gq;
        const u16* s1 = qlo + (size_t)(q0 + lrow) * DIM + gq;
        uint4 a = ((const uint4*)s0)[0], b = ((const uint4*)s0)[1];
        uint4 c = ((const uint4*)s1)[0], d = ((const uint4*)s1)[1];
        *(uint4*)&Qh[lrow * KP + lseg * 16]     = a;
        *(uint4*)&Qh[lrow * KP + lseg * 16 + 8] = b;
        *(uint4*)&Ql[lrow * KP + lseg * 16]     = c;
        *(uint4*)&Ql[lrow * KP + lseg * 16 + 8] = d;
    }
    uint4 ska, skb, sla, slb, sva, svb;
    {
        const int key0 = kt0 * KB;
        const u16* s0 = khi + (size_t)(key0 + lrow) * DIM + gq;
        const u16* s1 = klo + (size_t)(key0 + lrow) * DIM + gq;
        const u16* s2 = vT + (size_t)(h * DH + lrow) * NN + key0 + lseg * 16;
        ska = ((const uint4*)s0)[0]; skb = ((const uint4*)s0)[1];
        sla = ((const uint4*)s1)[0]; slb = ((const uint4*)s1)[1];
        sva = ((const uint4*)s2)[0]; svb = ((const uint4*)s2)[1];
    }
    __syncthreads();                              // Q staged

    // hoist Q fragments: wave w owns q rows w*16..+15
    short8b qf[2][2];                             // [kc][hi/lo]
    #pragma unroll
    for (int kc = 0; kc < 2; ++kc) {
        const int r = w * 16 + l15;
        const int dc = kc * 32 + h4 * 8;
        qf[kc][0] = *(const short8b*)&Qh[r * KP + dc];
        qf[kc][1] = *(const short8b*)&Ql[r * KP + dc];
    }
    __syncthreads();                              // hoist done; overlay safe

    const f32x4 z4 = {0.f, 0.f, 0.f, 0.f};
    f32x4 oacc[2][2] = {{z4, z4}, {z4, z4}};
    float m_run[4], l_run[4];
    #pragma unroll
    for (int i = 0; i < 4; ++i) { m_run[i] = -3.0e38f; l_run[i] = 0.f; }

    for (int kt = kt0; kt < kt1; ++kt) {
        *(uint4*)&Kh[lrow * KP + lseg * 16]     = ska;
        *(uint4*)&Kh[lrow * KP + lseg * 16 + 8] = skb;
        *(uint4*)&Kl[lrow * KP + lseg * 16]     = sla;
        *(uint4*)&Kl[lrow * KP + lseg * 16 + 8] = slb;
        *(uint4*)&Vt[lrow * KP + lseg * 16]     = sva;
        *(uint4*)&Vt[lrow * KP + lseg * 16 + 8] = svb;
        __syncthreads();                          // B1: tile staged

        // ---- S = Q K^T (4-pass hi/lo): 16 q-rows x 64 k per wave ----
        f32x4 sc[4] = {z4, z4, z4, z4};
        __builtin_amdgcn_s_setprio(1);
        #pragma unroll
        for (int kc = 0; kc < 2; ++kc) {
            const int dc = kc * 32 + h4 * 8;
            short8b kfh[4], kfl[4];
            #pragma unroll
            for (int kcb = 0; kcb < 4; ++kcb) {
                const int r = kcb * 16 + l15;
                kfh[kcb] = *(const short8b*)&Kh[r * KP + dc];
                kfl[kcb] = *(const short8b*)&Kl[r * KP + dc];
            }
            #pragma unroll
            for (int kcb = 0; kcb < 4; ++kcb) {
                sc[kcb] = __builtin_amdgcn_mfma_f32_16x16x32_bf16(
                    qf[kc][0], kfh[kcb], sc[kcb], 0, 0, 0);
                sc[kcb] = __builtin_amdgcn_mfma_f32_16x16x32_bf16(
                    qf[kc][0], kfl[kcb], sc[kcb], 0, 0, 0);
                sc[kcb] = __builtin_amdgcn_mfma_f32_16x16x32_bf16(
                    qf[kc][1], kfh[kcb], sc[kcb], 0, 0, 0);
                sc[kcb] = __builtin_amdgcn_mfma_f32_16x16x32_bf16(
                    qf[kc][1], kfl[kcb], sc[kcb], 0, 0, 0);
            }
        }
        __builtin_amdgcn_s_setprio(0);
        // prefetch next tile while softmax runs
        if (kt + 1 < kt1) {
            const int key0 = (kt + 1) * KB;
            const u16* s0 = khi + (size_t)(key0 + lrow) * DIM + gq;
            const u16* s1 = klo + (size_t)(key0 + lrow) * DIM + gq;
            const u16* s2 = vT + (size_t)(h * DH + lrow) * NN + key0 + lseg * 16;
            ska = ((const uint4*)s0)[0]; skb = ((const uint4*)s0)[1];
            sla = ((const uint4*)s1)[0]; slb = ((const uint4*)s1)[1];
            sva = ((const uint4*)s2)[0]; svb = ((const uint4*)s2)[1];
        }
        // ---- wave-local softmax (rows w*16 + h4*4 + i) ----
        float p[4][4], fr[4];
        #pragma unroll
        for (int i = 0; i < 4; ++i) {
            float pm = fmaxf(fmaxf(sc[0][i], sc[1][i]), fmaxf(sc[2][i], sc[3][i]));
            #pragma unroll
            for (int off = 1; off < 16; off <<= 1)
                pm = fmaxf(pm, __shfl_xor(pm, off));
            const float mnew = fmaxf(m_run[i], pm);
            fr[i] = __expf(m_run[i] - mnew);
            m_run[i] = mnew;
            p[0][i] = __expf(sc[0][i] - mnew);
            p[1][i] = __expf(sc[1][i] - mnew);
            p[2][i] = __expf(sc[2][i] - mnew);
            p[3][i] = __expf(sc[3][i] - mnew);
            float ls = (p[0][i] + p[1][i]) + (p[2][i] + p[3][i]);
            #pragma unroll
            for (int off = 1; off < 16; off <<= 1) ls += __shfl_xor(ls, off);
            l_run[i] = l_run[i] * fr[i] + ls;
        }
        // P store: rows w*16+h4*4+i, cols kcb*16+l15
        #pragma unroll
        for (int kcb = 0; kcb < 4; ++kcb) {
            const int kk = kcb * 16 + l15;
            #pragma unroll
            for (int i = 0; i < 4; ++i)
                Pb[(w * 16 + h4 * 4 + i) * KP + kk] = f2bf(p[kcb][i]);
        }
        if (l15 == 0) {
            #pragma unroll
            for (int i = 0; i < 4; ++i)
                frow[w * 16 + h4 * 4 + i] = fr[i];
        }
        __syncthreads();                          // B2: P + frow visible

        // ---- PV: o^T += V^T * P^T (quadrant split, P = b128 reads) ----
        float fq[2];
        #pragma unroll
        for (int qb = 0; qb < 2; ++qb) fq[qb] = frow[qh * 32 + qb * 16 + l15];
        #pragma unroll
        for (int db = 0; db < 2; ++db)
            #pragma unroll
            for (int qb = 0; qb < 2; ++qb)
                oacc[db][qb] *= fq[qb];
        __builtin_amdgcn_s_setprio(1);
        #pragma unroll
        for (int kc = 0; kc < 2; ++kc) {
            short8b vf[2], pf[2];
            #pragma unroll
            for (int db = 0; db < 2; ++db)
                vf[db] = *(const short8b*)&Vt[(kh * 32 + db * 16 + l15) * KP + kc * 32 + h4 * 8];
            #pragma unroll
            for (int qb = 0; qb < 2; ++qb)
                pf[qb] = *(const short8b*)&Pb[(qh * 32 + qb * 16 + l15) * KP + kc * 32 + h4 * 8];
            #pragma unroll
            for (int db = 0; db < 2; ++db)
                #pragma unroll
                for (int qb = 0; qb < 2; ++qb)
                    oacc[db][qb] = __builtin_amdgcn_mfma_f32_16x16x32_bf16(
                        vf[db], pf[qb], oacc[db][qb], 0, 0, 0);
        }
        __builtin_amdgcn_s_setprio(0);
        __syncthreads();                          // B3: PV done, buffers free
    }

    float* ob = (sp == 0) ? op0 : ((sp == 1) ? op1 : ((sp == 2) ? op2 : op3));
    #pragma unroll
    for (int db = 0; db < 2; ++db)
        #pragma unroll
        for (int qb = 0; qb < 2; ++qb) {
            const int qq = q0 + qh * 32 + qb * 16 + l15;
            const int d0 = h * DH + kh * 32 + db * 16 + h4 * 4;
            *(f32x4*)&ob[(size_t)qq * DIM + d0] = oacc[db][qb];
        }
    if (l15 == 0) {
        #pragma unroll
        for (int i = 0; i < 4; ++i) {
            const int r = w * 16 + h4 * 4 + i;
            mpart[((size_t)sp * NN + q0 + r) * NH + h] = m_run[i];
            lpart[((size_t)sp * NN + q0 + r) * NH + h] = l_run[i];
        }
    }
}

// merge the 4 partials -> hi/lo bf16 (feeds the MFMA Wo GEMM)
__global__ __launch_bounds__(256) void attn_combine(
    const float* __restrict__ o0, const float* __restrict__ o1,
    const float* __restrict__ o2, const float* __restrict__ o3,
    const float* __restrict__ mp, const float* __restrict__ lp,
    u16* __restrict__ ohi, u16* __restrict__ olo)
{
    const int gid = blockIdx.x * 256 + threadIdx.x;
    const int row = gid >> 6;
    const int c4  = (gid & 63) * 4;
    const int h   = c4 >> 6;
    float m[4], wgt[4];
    #pragma unroll
    for (int z = 0; z < 4; ++z) m[z] = mp[((size_t)z * NN + row) * NH + h];
    const float M = fmaxf(fmaxf(m[0], m[1]), fmaxf(m[2], m[3]));
    float den = 0.f;
    #pragma unroll
    for (int z = 0; z < 4; ++z) {
        wgt[z] = __expf(m[z] - M);
        den += lp[((size_t)z * NN + row) * NH + h] * wgt[z];
    }
    const float inv = 1.f / den;
    const float4 a = *(const float4*)&o0[(size_t)row * DIM + c4];
    const float4 b = *(const float4*)&o1[(size_t)row * DIM + c4];
    const float4 c = *(const float4*)&o2[(size_t)row * DIM + c4];
    const float4 d = *(const float4*)&o3[(size_t)row * DIM + c4];
    float r[4];
    r[0] = (a.x * wgt[0] + b.x * wgt[1] + c.x * wgt[2] + d.x * wgt[3]) * inv;
    r[1] = (a.y * wgt[0] + b.y * wgt[1] + c.y * wgt[2] + d.y * wgt[3]) * inv;
    r[2] = (a.z * wgt[0] + b.z * wgt[1] + c.z * wgt[2] + d.z * wgt[3]) * inv;
    r[3] = (a.w * wgt[0] + b.w * wgt[1] + c.w * wgt[2] + d.w * wgt[3]) * inv;
    u16 hh[4]; float ll[4];
    #pragma unroll
    for (int j = 0; j < 4; ++j) { hh[j] = f2bf(r[j]); ll[j] = r[j] - bf2f(hh[j]); }
    *(uint2*)&ohi[(size_t)row * DIM + c4] =
        make_uint2((u32)hh[0] | ((u32)hh[1] << 16), (u32)hh[2] | ((u32)hh[3] << 16));
    *(uint2*)&olo[(size_t)row * DIM + c4] =
        make_uint2(packbf(ll[0], ll[1]), packbf(ll[2], ll[3]));
}

// ---------------- per-node group adapter ----------------
__global__ __launch_bounds__(64) void adapter_kernel(
    const float* __restrict__ feats, const int* __restrict__ grp,
    const float* __restrict__ AW1, const float* __restrict__ Ab1,
    const float* __restrict__ AW2, const float* __restrict__ Ab2,
    float* __restrict__ out)
{
    const int n = blockIdx.x;
    const int lane = threadIdx.x;
    __shared__ float f[F1D];
    f[lane]      = feats[(size_t)n * F1D + lane];
    f[lane + 64] = feats[(size_t)n * F1D + 64 + lane];
    __syncthreads();
    const int g = grp[n];
    const float* W1 = AW1 + (size_t)g * F1D * AD;
    const int a = lane & 31;
    const int half = lane >> 5;
    float hsum = 0.f;
    for (int d = 0; d < 64; ++d)
        hsum = fmaf(f[half * 64 + d], W1[(half * 64 + d) * AD + a], hsum);
    hsum += __shfl_xor(hsum, 32);
    hsum = fmaxf(hsum + Ab1[g * AD + a], 0.f);
    float p = hsum * AW2[g * AD + a];
    #pragma unroll
    for (int mm = 1; mm < 32; mm <<= 1) p += __shfl_xor(p, mm);
    if (lane == 0) out[n] = p + Ab2[g];
}

// ---------------- host-side orchestration ----------------
extern "C" void kernel_launch(void* const* d_in, const int* in_sizes, int n_in,
                              void* d_out, int out_size, void* d_ws, size_t ws_size,
                              hipStream_t stream)
{
    const float* x_in   = (const float*)d_in[0];
    const float* eattr  = (const float*)d_in[1];
    const float* Wself  = (const float*)d_in[2];
    const float* Wnbr   = (const float*)d_in[3];
    const float* convb  = (const float*)d_in[4];
    const float* gamma  = (const float*)d_in[5];
    const float* beta   = (const float*)d_in[6];
    const float* bnmean = (const float*)d_in[7];
    const float* bnvar  = (const float*)d_in[8];
    const float* Wqkv   = (const float*)d_in[9];
    const float* bqkv   = (const float*)d_in[10];
    const float* Wo     = (const float*)d_in[11];
    const float* bo     = (const float*)d_in[12];
    const float* fc1W   = (const float*)d_in[13];
    const float* fc1b   = (const float*)d_in[14];
    const float* AW1    = (const float*)d_in[15];
    const float* Ab1    = (const float*)d_in[16];
    const float* AW2    = (const float*)d_in[17];
    const float* Ab2    = (const float*)d_in[18];
    const int*   eidx   = (const int*)d_in[19];
    const int*   grp    = (const int*)d_in[20];
    const int* srcArr = eidx;
    const int* dstArr = eidx + NE;

    float* fws = (float*)d_ws;
    const size_t NM = (size_t)NN * DIM;
    float* bufA  = fws;                  // conv x / residual
    float* bufB  = fws + NM;             // agg / attn op0
    float* bufC  = fws + 2 * NM;         // x L1 / op1
    float* bufD  = fws + 3 * NM;         // op2
    float* bufE  = fws + 4 * NM;         // op3
    float* feats = fws + 5 * NM;         // NN x F1D
    float* mpart = fws + 5 * NM + NM / 2;         // [4][NN][NH]
    float* lpart = mpart + 4 * NN * NH;
    u16* qhi = (u16*)(lpart + 4 * NN * NH);       // NN*DIM u16 each
    u16* qlo = qhi + NM;
    u16* khi = qlo + NM;
    u16* klo = khi + NM;
    u16* vt  = klo + NM;                          // [DIM][NN]
    int*   esrc = (int*)(vt + NM);                // NE
    float* ewt  = (float*)(esrc + NE);            // NE
    int* off    = (int*)(ewt + NE);               // NN+1
    int* cur    = off + NN + 1;                   // NN
    u16* wo_th  = (u16*)(cur + NN);               // [256][256]
    u16* wo_tl  = wo_th + DIM * DIM;
    u16* fc1_th = wo_tl + DIM * DIM;              // [128][256]
    u16* fc1_tl = fc1_th + F1D * DIM;
    float* outp = (float*)d_out;

    // buffer reuse after attention:
    u16* ohi = qhi;   u16* olo = qlo;    // combine output (Wo's A)
    u16* xh2 = khi;   u16* xl2 = klo;    // Wo output (fc1's A)

    // weight conversion (independent of everything else)
    wconvert<<<DIM * DIM / 4 / 256, 256, 0, stream>>>(Wo, wo_th, wo_tl, DIM, DIM);
    wconvert<<<DIM * F1D / 4 / 256, 256, 0, stream>>>(fc1W, fc1_th, fc1_tl, DIM, F1D);

    // CSR build
    hipMemsetAsync(cur, 0, NN * sizeof(int), stream);
    csr_count<<<NE / 256, 256, 0, stream>>>(dstArr, cur);
    csr_scan<<<1, 64, 0, stream>>>(cur, off);
    hipMemsetAsync(cur, 0, NN * sizeof(int), stream);
    csr_fill<<<NE / 256, 256, 0, stream>>>(dstArr, srcArr, eattr, off, cur, esrc, ewt);

    const dim3 gg(DIM / 64, NN / 64);
    const int rgrid = NN * DIM / 4 / 256;

    // conv layer 0: x_in -> bufA
    agg_kernel<false><<<NN / 4, 256, 0, stream>>>(x_in, esrc, ewt, off, bufB);
    gemm_kernel<EPI_BNELU, true><<<gg, 256, 0, stream>>>(
        x_in, Wself, bufB, Wnbr, convb, gamma, beta, bnmean, bnvar,
        nullptr, bufA, DIM, DIM);
    // conv layer 1: bufA -> bufC
    agg_kernel<false><<<NN / 4, 256, 0, stream>>>(bufA, esrc, ewt, off, bufB);
    gemm_kernel<EPI_BNELU, true><<<gg, 256, 0, stream>>>(
        bufA, Wself + DIM * DIM, bufB, Wnbr + DIM * DIM, convb + DIM,
        gamma + DIM, beta + DIM, bnmean + DIM, bnvar + DIM,
        nullptr, bufC, DIM, DIM);
    // conv layer 2 (edge-weighted): bufC -> bufA
    agg_kernel<true><<<NN / 4, 256, 0, stream>>>(bufC, esrc, ewt, off, bufB);
    gemm_kernel<EPI_BIAS, true><<<gg, 256, 0, stream>>>(
        bufC, Wself + 2 * DIM * DIM, bufB, Wnbr + 2 * DIM * DIM, convb + 2 * DIM,
        nullptr, nullptr, nullptr, nullptr, nullptr, bufA, DIM, DIM);

    // fused QKV projection -> bf16 hi/lo Q,K + V^T (fp32 compute: feeds scores)
    gemm_qkv<<<dim3(3 * DIM / 64, NN / 64), 256, 0, stream>>>(
        bufA, Wqkv, bqkv, qhi, qlo, khi, klo, vt);

    // MFMA flash attention (4-way key split) -> partials, combine -> hi/lo
    attn_kernel<<<dim3(NN / QB, NH, NSPLIT), 256, 0, stream>>>(
        qhi, qlo, khi, klo, vt, bufB, bufC, bufD, bufE, mpart, lpart);
    attn_combine<<<rgrid, 256, 0, stream>>>(
        bufB, bufC, bufD, bufE, mpart, lpart, ohi, olo);

    // output projection + residual (MFMA hi/lo): xh2/xl2 = hi/lo(bufA + o@Wo + bo)
    mfma_gemm<MEPI_WO><<<dim3(DIM / 64, NN / 64), 256, 0, stream>>>(
        ohi, olo, wo_th, wo_tl, bo, bufA, nullptr, xh2, xl2, DIM, DIM);

    // fc1 + ELU (MFMA hi/lo): feats = elu(x' @ fc1W + fc1b)
    mfma_gemm<MEPI_FC1><<<dim3(F1D / 64, NN / 64), 256, 0, stream>>>(
        xh2, xl2, fc1_th, fc1_tl, fc1b, nullptr, feats, nullptr, nullptr, DIM, F1D);

    // adapter routing -> out
    adapter_kernel<<<NN, 64, 0, stream>>>(feats, grp, AW1, Ab1, AW2, Ab2, outp);
}

// Round 10
// 284.512 us; speedup vs baseline: 1.1851x; 1.0893x over previous
//
#include <hip/hip_runtime.h>
#include <math.h>

#define NN   4096
#define DIM  256
#define NE   131072
#define NH   4
#define DH   64
#define F1D  128
#define NG   16
#define AD   32

typedef unsigned short u16;
typedef unsigned int   u32;
typedef _Float16 f16;
typedef __attribute__((ext_vector_type(8))) _Float16 half8;
typedef __attribute__((ext_vector_type(4))) float f32x4;

enum { EPI_BIAS = 0, EPI_BNELU = 1 };
enum { MEPI_WO = 0, MEPI_FC1 = 1 };

#define MFMA16(a, b, c) __builtin_amdgcn_mfma_f32_16x16x32_f16(a, b, c, 0, 0, 0)

__device__ inline u16 f2h(float x) { union { f16 f; u16 u; } c; c.f = (f16)x; return c.u; }
__device__ inline float h2f(u16 h) { union { f16 f; u16 u; } c; c.u = h; return (float)c.f; }
// fp16 hi/lo split: x = hi + lo + eps, |eps| <= 2^-24 |x|  (fp32-grade)
__device__ inline void split16(float x, u16& h, u16& l) {
    union { f16 f; u16 u; } ch, cl;
    ch.f = (f16)x;
    cl.f = (f16)(x - (float)ch.f);
    h = ch.u; l = cl.u;
}

// ---------------- CSR build ----------------
__global__ void csr_count(const int* __restrict__ dst, int* __restrict__ cnt) {
    int e = blockIdx.x * 256 + threadIdx.x;
    atomicAdd(&cnt[dst[e]], 1);
}

__global__ void csr_scan(const int* __restrict__ cnt, int* __restrict__ off) {
    int lane = threadIdx.x;
    int base = lane * (NN / 64);
    int s = 0;
    for (int i = 0; i < NN / 64; ++i) s += cnt[base + i];
    int acc = s;
    #pragma unroll
    for (int o = 1; o < 64; o <<= 1) {
        int t = __shfl_up(acc, o);
        if (lane >= o) acc += t;
    }
    int run = acc - s;
    for (int i = 0; i < NN / 64; ++i) { off[base + i] = run; run += cnt[base + i]; }
    if (lane == 63) off[NN] = run;
}

__global__ void csr_fill(const int* __restrict__ dst, const int* __restrict__ src,
                         const float* __restrict__ eattr, const int* __restrict__ off,
                         int* __restrict__ cur, int* __restrict__ esrc,
                         float* __restrict__ ewt) {
    int e = blockIdx.x * 256 + threadIdx.x;
    int d = dst[e];
    int pos = off[d] + atomicAdd(&cur[d], 1);
    esrc[pos] = src[e];
    ewt[pos]  = eattr[e];
}

// ---------------- one-time converts ----------------
// x[N][256] fp32 -> fp16 hi/lo planes
__global__ __launch_bounds__(256) void xconvert(
    const float* __restrict__ x, u16* __restrict__ xh, u16* __restrict__ xl)
{
    const int gid = blockIdx.x * 256 + threadIdx.x;
    const float4 v = *(const float4*)&x[(size_t)gid * 4];
    u16 h[4], l[4];
    split16(v.x, h[0], l[0]); split16(v.y, h[1], l[1]);
    split16(v.z, h[2], l[2]); split16(v.w, h[3], l[3]);
    *(uint2*)&xh[(size_t)gid * 4] =
        make_uint2((u32)h[0] | ((u32)h[1] << 16), (u32)h[2] | ((u32)h[3] << 16));
    *(uint2*)&xl[(size_t)gid * 4] =
        make_uint2((u32)l[0] | ((u32)l[1] << 16), (u32)l[2] | ((u32)l[3] << 16));
}

// 3 conv layers: [Wself_L | Wnbr_L] transposed -> out[L][m=256][k=512] planes
__global__ __launch_bounds__(256) void wconv_dual3(
    const float* __restrict__ Ws, const float* __restrict__ Wn,
    u16* __restrict__ oh, u16* __restrict__ ol)
{
    const int gid = blockIdx.x * 256 + threadIdx.x;
    const int L = gid / 32768;
    const int rem = gid % 32768;
    const int m = rem / 128;
    const int k4 = (rem % 128) * 4;
    const float* S = Ws + (size_t)L * 65536;
    const float* Nb = Wn + (size_t)L * 65536;
    u16 h[4], l[4];
    #pragma unroll
    for (int j = 0; j < 4; ++j) {
        const int k = k4 + j;
        const float v = (k < 256) ? S[(size_t)k * 256 + m] : Nb[(size_t)(k - 256) * 256 + m];
        split16(v, h[j], l[j]);
    }
    const size_t o = (size_t)L * 131072 + (size_t)m * 512 + k4;
    *(uint2*)&oh[o] = make_uint2((u32)h[0] | ((u32)h[1] << 16), (u32)h[2] | ((u32)h[3] << 16));
    *(uint2*)&ol[o] = make_uint2((u32)l[0] | ((u32)l[1] << 16), (u32)l[2] | ((u32)l[3] << 16));
}

// Wqkv (3 mats) + Wo transposed -> out[4][m=256][k=256] planes
__global__ __launch_bounds__(256) void wconvert4(
    const float* __restrict__ Wqkv, const float* __restrict__ Wo,
    u16* __restrict__ oh, u16* __restrict__ ol)
{
    const int gid = blockIdx.x * 256 + threadIdx.x;
    const int mat = gid / 16384;
    const int rem = gid % 16384;
    const int m = rem / 64;
    const int k4 = (rem % 64) * 4;
    const float* W = (mat < 3) ? Wqkv + (size_t)mat * 65536 : Wo;
    u16 h[4], l[4];
    #pragma unroll
    for (int j = 0; j < 4; ++j)
        split16(W[(size_t)(k4 + j) * 256 + m], h[j], l[j]);
    const size_t o = (size_t)mat * 65536 + (size_t)m * 256 + k4;
    *(uint2*)&oh[o] = make_uint2((u32)h[0] | ((u32)h[1] << 16), (u32)h[2] | ((u32)h[3] << 16));
    *(uint2*)&ol[o] = make_uint2((u32)l[0] | ((u32)l[1] << 16), (u32)l[2] | ((u32)l[3] << 16));
}

// fc1W[256][128] -> out[m=128][k=256] planes
__global__ __launch_bounds__(256) void wconvert_fc1(
    const float* __restrict__ W, u16* __restrict__ oh, u16* __restrict__ ol)
{
    const int gid = blockIdx.x * 256 + threadIdx.x;
    const int m = gid / 64;
    const int k4 = (gid % 64) * 4;
    u16 h[4], l[4];
    #pragma unroll
    for (int j = 0; j < 4; ++j)
        split16(W[(size_t)(k4 + j) * F1D + m], h[j], l[j]);
    const size_t o = (size_t)m * 256 + k4;
    *(uint2*)&oh[o] = make_uint2((u32)h[0] | ((u32)h[1] << 16), (u32)h[2] | ((u32)h[3] << 16));
    *(uint2*)&ol[o] = make_uint2((u32)l[0] | ((u32)l[1] << 16), (u32)l[2] | ((u32)l[3] << 16));
}

// ---------------- neighbor aggregation: 1 wave per node, fp16-plane out ---
template<bool LAST>
__global__ __launch_bounds__(256) void agg_kernel(
    const float* __restrict__ x, const int* __restrict__ esrc,
    const float* __restrict__ ewt, const int* __restrict__ off,
    u16* __restrict__ aggh, u16* __restrict__ aggl)
{
    const int node = blockIdx.x * 4 + (threadIdx.x >> 6);
    const int lane = threadIdx.x & 63;
    const int d4 = lane * 4;
    int j = off[node];
    const int j1 = off[node + 1];
    float4 acc = make_float4(0.f, 0.f, 0.f, 0.f);
    for (; j + 4 <= j1; j += 4) {
        const int s0 = esrc[j], s1 = esrc[j + 1], s2 = esrc[j + 2], s3 = esrc[j + 3];
        const float4 x0 = *(const float4*)&x[(size_t)s0 * DIM + d4];
        const float4 x1 = *(const float4*)&x[(size_t)s1 * DIM + d4];
        const float4 x2 = *(const float4*)&x[(size_t)s2 * DIM + d4];
        const float4 x3 = *(const float4*)&x[(size_t)s3 * DIM + d4];
        const float w0 = LAST ? ewt[j]     : 1.f;
        const float w1 = LAST ? ewt[j + 1] : 1.f;
        const float w2 = LAST ? ewt[j + 2] : 1.f;
        const float w3 = LAST ? ewt[j + 3] : 1.f;
        acc.x = fmaf(x0.x, w0, acc.x); acc.y = fmaf(x0.y, w0, acc.y);
        acc.z = fmaf(x0.z, w0, acc.z); acc.w = fmaf(x0.w, w0, acc.w);
        acc.x = fmaf(x1.x, w1, acc.x); acc.y = fmaf(x1.y, w1, acc.y);
        acc.z = fmaf(x1.z, w1, acc.z); acc.w = fmaf(x1.w, w1, acc.w);
        acc.x = fmaf(x2.x, w2, acc.x); acc.y = fmaf(x2.y, w2, acc.y);
        acc.z = fmaf(x2.z, w2, acc.z); acc.w = fmaf(x2.w, w2, acc.w);
        acc.x = fmaf(x3.x, w3, acc.x); acc.y = fmaf(x3.y, w3, acc.y);
        acc.z = fmaf(x3.z, w3, acc.z); acc.w = fmaf(x3.w, w3, acc.w);
    }
    for (; j < j1; ++j) {
        const int s = esrc[j];
        const float w = LAST ? ewt[j] : 1.f;
        const float4 xv = *(const float4*)&x[(size_t)s * DIM + d4];
        acc.x = fmaf(xv.x, w, acc.x); acc.y = fmaf(xv.y, w, acc.y);
        acc.z = fmaf(xv.z, w, acc.z); acc.w = fmaf(xv.w, w, acc.w);
    }
    u16 h[4], l[4];
    split16(acc.x, h[0], l[0]); split16(acc.y, h[1], l[1]);
    split16(acc.z, h[2], l[2]); split16(acc.w, h[3], l[3]);
    *(uint2*)&aggh[(size_t)node * DIM + d4] =
        make_uint2((u32)h[0] | ((u32)h[1] << 16), (u32)h[2] | ((u32)h[3] << 16));
    *(uint2*)&aggl[(size_t)node * DIM + d4] =
        make_uint2((u32)l[0] | ((u32)l[1] << 16), (u32)l[2] | ((u32)l[3] << 16));
}

// ---------------- conv MFMA GEMM: y = x@Wself + agg@Wnbr + b (+BN+ELU) ----
// fp16 hi/lo 3-pass (error ~2^-26 relative). Kcat = 512 (x | agg).
// 64x64 tile, 4 waves (quadrants), K-step 64. Outputs fp32 + fp16 planes.
template<int EPI>
__global__ __launch_bounds__(256) void conv_mfma(
    const u16* __restrict__ xh, const u16* __restrict__ xl,
    const u16* __restrict__ gh, const u16* __restrict__ gl,
    const u16* __restrict__ bth, const u16* __restrict__ btl,
    const float* __restrict__ bias,
    const float* __restrict__ gamma, const float* __restrict__ beta,
    const float* __restrict__ bnmean, const float* __restrict__ bnvar,
    float* __restrict__ outf, u16* __restrict__ oh, u16* __restrict__ ol)
{
    __shared__ u16 lds[4 * 4608];
    u16* As_h = lds;
    u16* As_l = lds + 4608;
    u16* Bs_h = lds + 9216;
    u16* Bs_l = lds + 13824;
    #define TKP 72

    const int tid  = threadIdx.x;
    const int row0 = blockIdx.y * 64;
    const int col0 = blockIdx.x * 64;

    const int w   = tid >> 6;
    const int l15 = tid & 15, h4 = (tid & 63) >> 4;
    const int rh  = w & 1, ch = w >> 1;
    const int lrow = tid & 63, lseg = tid >> 6;
    const int lc = lseg * 16;

    uint4 sah0, sah1, sal0, sal1, sbh0, sbh1, sbl0, sbl1;
    {
        const u16* pah = xh + (size_t)(row0 + lrow) * DIM + lc;
        const u16* pal = xl + (size_t)(row0 + lrow) * DIM + lc;
        const u16* pbh = bth + (size_t)(col0 + lrow) * 512 + lc;
        const u16* pbl = btl + (size_t)(col0 + lrow) * 512 + lc;
        sah0 = ((const uint4*)pah)[0]; sah1 = ((const uint4*)pah)[1];
        sal0 = ((const uint4*)pal)[0]; sal1 = ((const uint4*)pal)[1];
        sbh0 = ((const uint4*)pbh)[0]; sbh1 = ((const uint4*)pbh)[1];
        sbl0 = ((const uint4*)pbl)[0]; sbl1 = ((const uint4*)pbl)[1];
    }

    const f32x4 z4 = {0.f, 0.f, 0.f, 0.f};
    f32x4 acc[2][2] = {{z4, z4}, {z4, z4}};

    for (int kt = 0; kt < 8; ++kt) {
        *(uint4*)&As_h[lrow * TKP + lc]     = sah0;
        *(uint4*)&As_h[lrow * TKP + lc + 8] = sah1;
        *(uint4*)&As_l[lrow * TKP + lc]     = sal0;
        *(uint4*)&As_l[lrow * TKP + lc + 8] = sal1;
        *(uint4*)&Bs_h[lrow * TKP + lc]     = sbh0;
        *(uint4*)&Bs_h[lrow * TKP + lc + 8] = sbh1;
        *(uint4*)&Bs_l[lrow * TKP + lc]     = sbl0;
        *(uint4*)&Bs_l[lrow * TKP + lc + 8] = sbl1;
        __syncthreads();

        __builtin_amdgcn_s_setprio(1);
        #pragma unroll
        for (int kc = 0; kc < 2; ++kc) {
            const int dc = kc * 32 + h4 * 8;
            half8 afh[2], afl[2], bfh[2], bfl[2];
            #pragma unroll
            for (int ab = 0; ab < 2; ++ab) {
                const int r = rh * 32 + ab * 16 + l15;
                afh[ab] = *(const half8*)&As_h[r * TKP + dc];
                afl[ab] = *(const half8*)&As_l[r * TKP + dc];
            }
            #pragma unroll
            for (int bb = 0; bb < 2; ++bb) {
                const int r = ch * 32 + bb * 16 + l15;
                bfh[bb] = *(const half8*)&Bs_h[r * TKP + dc];
                bfl[bb] = *(const half8*)&Bs_l[r * TKP + dc];
            }
            #pragma unroll
            for (int ab = 0; ab < 2; ++ab)
                #pragma unroll
                for (int bb = 0; bb < 2; ++bb) {
                    acc[ab][bb] = MFMA16(afh[ab], bfh[bb], acc[ab][bb]);
                    acc[ab][bb] = MFMA16(afh[ab], bfl[bb], acc[ab][bb]);
                    acc[ab][bb] = MFMA16(afl[ab], bfh[bb], acc[ab][bb]);
                }
        }
        __builtin_amdgcn_s_setprio(0);
        if (kt + 1 < 8) {
            const int kn = kt + 1;
            const u16 *pah, *pal;
            if (kn < 4) {
                pah = xh + (size_t)(row0 + lrow) * DIM + kn * 64 + lc;
                pal = xl + (size_t)(row0 + lrow) * DIM + kn * 64 + lc;
            } else {
                pah = gh + (size_t)(row0 + lrow) * DIM + (kn - 4) * 64 + lc;
                pal = gl + (size_t)(row0 + lrow) * DIM + (kn - 4) * 64 + lc;
            }
            const u16* pbh = bth + (size_t)(col0 + lrow) * 512 + kn * 64 + lc;
            const u16* pbl = btl + (size_t)(col0 + lrow) * 512 + kn * 64 + lc;
            sah0 = ((const uint4*)pah)[0]; sah1 = ((const uint4*)pah)[1];
            sal0 = ((const uint4*)pal)[0]; sal1 = ((const uint4*)pal)[1];
            sbh0 = ((const uint4*)pbh)[0]; sbh1 = ((const uint4*)pbh)[1];
            sbl0 = ((const uint4*)pbl)[0]; sbl1 = ((const uint4*)pbl)[1];
        }
        __syncthreads();
    }

    #pragma unroll
    for (int ab = 0; ab < 2; ++ab)
        #pragma unroll
        for (int bb = 0; bb < 2; ++bb) {
            const int c  = col0 + ch * 32 + bb * 16 + l15;
            const int r0 = row0 + rh * 32 + ab * 16 + h4 * 4;
            #pragma unroll
            for (int i = 0; i < 4; ++i) {
                const int r = r0 + i;
                float t = acc[ab][bb][i] + bias[c];
                if (EPI == EPI_BNELU) {
                    t = gamma[c] * (t - bnmean[c]) * rsqrtf(bnvar[c] + 1e-5f) + beta[c];
                    t = t > 0.f ? t : expm1f(t);
                }
                outf[(size_t)r * DIM + c] = t;
                u16 hh, ll;
                split16(t, hh, ll);
                oh[(size_t)r * DIM + c] = hh;
                ol[(size_t)r * DIM + c] = ll;
            }
        }
    #undef TKP
}

// ---------------- QKV MFMA GEMM (fp16 3-pass) -----------------------------
// grid (12, 64): mat = bx>>2. Outputs: Q/K fp16 hi/lo planes (Q * 1/8),
// V transposed single fp16 plane [256][NN].
__global__ __launch_bounds__(256) void qkv_mfma(
    const u16* __restrict__ xh, const u16* __restrict__ xl,
    const u16* __restrict__ wth, const u16* __restrict__ wtl,
    const float* __restrict__ bias,
    u16* __restrict__ qh_o, u16* __restrict__ ql_o,
    u16* __restrict__ kh_o, u16* __restrict__ kl_o,
    u16* __restrict__ vt_o)
{
    __shared__ u16 lds[4 * 4608];
    u16* As_h = lds;
    u16* As_l = lds + 4608;
    u16* Bs_h = lds + 9216;
    u16* Bs_l = lds + 13824;
    #define TKP 72

    const int tid  = threadIdx.x;
    const int row0 = blockIdx.y * 64;
    const int mat  = blockIdx.x >> 2;
    const int col0 = (blockIdx.x & 3) * 64;
    const float* biasp = bias + mat * DIM;

    const int w   = tid >> 6;
    const int l15 = tid & 15, h4 = (tid & 63) >> 4;
    const int rh  = w & 1, ch = w >> 1;
    const int lrow = tid & 63, lseg = tid >> 6;
    const int lc = lseg * 16;

    const size_t brow = (size_t)(mat * 256 + col0 + lrow) * 256;
    uint4 sah0, sah1, sal0, sal1, sbh0, sbh1, sbl0, sbl1;
    {
        const u16* pah = xh + (size_t)(row0 + lrow) * DIM + lc;
        const u16* pal = xl + (size_t)(row0 + lrow) * DIM + lc;
        sah0 = ((const uint4*)pah)[0]; sah1 = ((const uint4*)pah)[1];
        sal0 = ((const uint4*)pal)[0]; sal1 = ((const uint4*)pal)[1];
        sbh0 = ((const uint4*)(wth + brow + lc))[0]; sbh1 = ((const uint4*)(wth + brow + lc))[1];
        sbl0 = ((const uint4*)(wtl + brow + lc))[0]; sbl1 = ((const uint4*)(wtl + brow + lc))[1];
    }

    const f32x4 z4 = {0.f, 0.f, 0.f, 0.f};
    f32x4 acc[2][2] = {{z4, z4}, {z4, z4}};

    for (int kt = 0; kt < 4; ++kt) {
        *(uint4*)&As_h[lrow * TKP + lc]     = sah0;
        *(uint4*)&As_h[lrow * TKP + lc + 8] = sah1;
        *(uint4*)&As_l[lrow * TKP + lc]     = sal0;
        *(uint4*)&As_l[lrow * TKP + lc + 8] = sal1;
        *(uint4*)&Bs_h[lrow * TKP + lc]     = sbh0;
        *(uint4*)&Bs_h[lrow * TKP + lc + 8] = sbh1;
        *(uint4*)&Bs_l[lrow * TKP + lc]     = sbl0;
        *(uint4*)&Bs_l[lrow * TKP + lc + 8] = sbl1;
        __syncthreads();

        __builtin_amdgcn_s_setprio(1);
        #pragma unroll
        for (int kc = 0; kc < 2; ++kc) {
            const int dc = kc * 32 + h4 * 8;
            half8 afh[2], afl[2], bfh[2], bfl[2];
            #pragma unroll
            for (int ab = 0; ab < 2; ++ab) {
                const int r = rh * 32 + ab * 16 + l15;
                afh[ab] = *(const half8*)&As_h[r * TKP + dc];
                afl[ab] = *(const half8*)&As_l[r * TKP + dc];
            }
            #pragma unroll
            for (int bb = 0; bb < 2; ++bb) {
                const int r = ch * 32 + bb * 16 + l15;
                bfh[bb] = *(const half8*)&Bs_h[r * TKP + dc];
                bfl[bb] = *(const half8*)&Bs_l[r * TKP + dc];
            }
            #pragma unroll
            for (int ab = 0; ab < 2; ++ab)
                #pragma unroll
                for (int bb = 0; bb < 2; ++bb) {
                    acc[ab][bb] = MFMA16(afh[ab], bfh[bb], acc[ab][bb]);
                    acc[ab][bb] = MFMA16(afh[ab], bfl[bb], acc[ab][bb]);
                    acc[ab][bb] = MFMA16(afl[ab], bfh[bb], acc[ab][bb]);
                }
        }
        __builtin_amdgcn_s_setprio(0);
        if (kt + 1 < 4) {
            const int kb = (kt + 1) * 64 + lc;
            const u16* pah = xh + (size_t)(row0 + lrow) * DIM + kb;
            const u16* pal = xl + (size_t)(row0 + lrow) * DIM + kb;
            sah0 = ((const uint4*)pah)[0]; sah1 = ((const uint4*)pah)[1];
            sal0 = ((const uint4*)pal)[0]; sal1 = ((const uint4*)pal)[1];
            sbh0 = ((const uint4*)(wth + brow + kb))[0]; sbh1 = ((const uint4*)(wth + brow + kb))[1];
            sbl0 = ((const uint4*)(wtl + brow + kb))[0]; sbl1 = ((const uint4*)(wtl + brow + kb))[1];
        }
        __syncthreads();
    }

    const float s = (mat == 0) ? 0.125f : 1.0f;
    u16* oph = (mat == 0) ? qh_o : kh_o;
    u16* opl = (mat == 0) ? ql_o : kl_o;
    #pragma unroll
    for (int ab = 0; ab < 2; ++ab)
        #pragma unroll
        for (int bb = 0; bb < 2; ++bb) {
            const int c  = col0 + ch * 32 + bb * 16 + l15;
            const int r0 = row0 + rh * 32 + ab * 16 + h4 * 4;
            if (mat < 2) {
                #pragma unroll
                for (int i = 0; i < 4; ++i) {
                    const int r = r0 + i;
                    const float t = (acc[ab][bb][i] + biasp[c]) * s;
                    u16 hh, ll;
                    split16(t, hh, ll);
                    oph[(size_t)r * DIM + c] = hh;
                    opl[(size_t)r * DIM + c] = ll;
                }
            } else {
                u16 v[4];
                #pragma unroll
                for (int i = 0; i < 4; ++i)
                    v[i] = f2h(acc[ab][bb][i] + biasp[c]);
                *(uint2*)&vt_o[(size_t)c * NN + r0] =
                    make_uint2((u32)v[0] | ((u32)v[1] << 16), (u32)v[2] | ((u32)v[3] << 16));
            }
        }
    #undef TKP
}

// ---------------- MFMA fp16 GEMM (Wo / fc1) -------------------------------
template<int MEPI>
__global__ __launch_bounds__(256) void mfma_gemm(
    const u16* __restrict__ Ah, const u16* __restrict__ Al,
    const u16* __restrict__ Bth, const u16* __restrict__ Btl,
    const float* __restrict__ bias, const float* __restrict__ resid,
    float* __restrict__ outf, u16* __restrict__ outh, u16* __restrict__ outl,
    int K, int M)
{
    __shared__ u16 lds[4 * 4608];
    u16* As_h = lds;
    u16* As_l = lds + 4608;
    u16* Bs_h = lds + 9216;
    u16* Bs_l = lds + 13824;
    #define TKP 72

    const int tid  = threadIdx.x;
    const int row0 = blockIdx.y * 64;
    const int col0 = blockIdx.x * 64;

    const int w   = tid >> 6;
    const int l15 = tid & 15, h4 = (tid & 63) >> 4;
    const int rh  = w & 1, ch = w >> 1;
    const int lrow = tid & 63, lseg = tid >> 6;
    const int lc = lseg * 16;

    uint4 sah0, sah1, sal0, sal1, sbh0, sbh1, sbl0, sbl1;
    {
        const u16* pa0 = Ah  + (size_t)(row0 + lrow) * K + lc;
        const u16* pa1 = Al  + (size_t)(row0 + lrow) * K + lc;
        const u16* pb0 = Bth + (size_t)(col0 + lrow) * K + lc;
        const u16* pb1 = Btl + (size_t)(col0 + lrow) * K + lc;
        sah0 = ((const uint4*)pa0)[0]; sah1 = ((const uint4*)pa0)[1];
        sal0 = ((const uint4*)pa1)[0]; sal1 = ((const uint4*)pa1)[1];
        sbh0 = ((const uint4*)pb0)[0]; sbh1 = ((const uint4*)pb0)[1];
        sbl0 = ((const uint4*)pb1)[0]; sbl1 = ((const uint4*)pb1)[1];
    }

    const f32x4 z4 = {0.f, 0.f, 0.f, 0.f};
    f32x4 acc[2][2] = {{z4, z4}, {z4, z4}};
    const int NKT = K / 64;

    for (int kt = 0; kt < NKT; ++kt) {
        *(uint4*)&As_h[lrow * TKP + lc]     = sah0;
        *(uint4*)&As_h[lrow * TKP + lc + 8] = sah1;
        *(uint4*)&As_l[lrow * TKP + lc]     = sal0;
        *(uint4*)&As_l[lrow * TKP + lc + 8] = sal1;
        *(uint4*)&Bs_h[lrow * TKP + lc]     = sbh0;
        *(uint4*)&Bs_h[lrow * TKP + lc + 8] = sbh1;
        *(uint4*)&Bs_l[lrow * TKP + lc]     = sbl0;
        *(uint4*)&Bs_l[lrow * TKP + lc + 8] = sbl1;
        __syncthreads();

        __builtin_amdgcn_s_setprio(1);
        #pragma unroll
        for (int kc = 0; kc < 2; ++kc) {
            const int dc = kc * 32 + h4 * 8;
            half8 afh[2], afl[2], bfh[2], bfl[2];
            #pragma unroll
            for (int ab = 0; ab < 2; ++ab) {
                const int r = rh * 32 + ab * 16 + l15;
                afh[ab] = *(const half8*)&As_h[r * TKP + dc];
                afl[ab] = *(const half8*)&As_l[r * TKP + dc];
            }
            #pragma unroll
            for (int bb = 0; bb < 2; ++bb) {
                const int r = ch * 32 + bb * 16 + l15;
                bfh[bb] = *(const half8*)&Bs_h[r * TKP + dc];
                bfl[bb] = *(const half8*)&Bs_l[r * TKP + dc];
            }
            #pragma unroll
            for (int ab = 0; ab < 2; ++ab)
                #pragma unroll
                for (int bb = 0; bb < 2; ++bb) {
                    acc[ab][bb] = MFMA16(afh[ab], bfh[bb], acc[ab][bb]);
                    acc[ab][bb] = MFMA16(afh[ab], bfl[bb], acc[ab][bb]);
                    acc[ab][bb] = MFMA16(afl[ab], bfh[bb], acc[ab][bb]);
                }
        }
        __builtin_amdgcn_s_setprio(0);
        if (kt + 1 < NKT) {
            const int kb = (kt + 1) * 64 + lc;
            const u16* pa0 = Ah  + (size_t)(row0 + lrow) * K + kb;
            const u16* pa1 = Al  + (size_t)(row0 + lrow) * K + kb;
            const u16* pb0 = Bth + (size_t)(col0 + lrow) * K + kb;
            const u16* pb1 = Btl + (size_t)(col0 + lrow) * K + kb;
            sah0 = ((const uint4*)pa0)[0]; sah1 = ((const uint4*)pa0)[1];
            sal0 = ((const uint4*)pa1)[0]; sal1 = ((const uint4*)pa1)[1];
            sbh0 = ((const uint4*)pb0)[0]; sbh1 = ((const uint4*)pb0)[1];
            sbl0 = ((const uint4*)pb1)[0]; sbl1 = ((const uint4*)pb1)[1];
        }
        __syncthreads();
    }

    #pragma unroll
    for (int ab = 0; ab < 2; ++ab)
        #pragma unroll
        for (int bb = 0; bb < 2; ++bb) {
            const int c  = col0 + ch * 32 + bb * 16 + l15;
            const int r0 = row0 + rh * 32 + ab * 16 + h4 * 4;
            #pragma unroll
            for (int i = 0; i < 4; ++i) {
                const int r = r0 + i;
                float t = acc[ab][bb][i] + bias[c];
                if (MEPI == MEPI_WO) {
                    t += resid[(size_t)r * M + c];
                    u16 hh, ll;
                    split16(t, hh, ll);
                    outh[(size_t)r * M + c] = hh;
                    outl[(size_t)r * M + c] = ll;
                } else {    // FC1: bias + ELU -> fp32 feats
                    t = t > 0.f ? t : expm1f(t);
                    outf[(size_t)r * M + c] = t;
                }
            }
        }
    #undef TKP
}

// ---------------- MFMA flash attention (fp16, 3-pass QK^T) ----------------
#define QB 64
#define KB 64
#define NSPLIT 4
#define NKT (NN / KB)
#define KP 72

__global__ __launch_bounds__(256, 3) void attn_kernel(
    const u16* __restrict__ qhi, const u16* __restrict__ qlo,
    const u16* __restrict__ khi, const u16* __restrict__ klo,
    const u16* __restrict__ vT,
    float* __restrict__ op0, float* __restrict__ op1,
    float* __restrict__ op2, float* __restrict__ op3,
    float* __restrict__ mpart, float* __restrict__ lpart)
{
    __shared__ u16 lds[18560];            // 37120 B
    u16* Kh = lds;                        // [64][72]
    u16* Kl = lds + 4608;
    u16* Vt = lds + 9216;                 // [key][d] per-head
    u16* Pb = lds + 13824;                // [q][72]  P fp16
    u16* Qh = lds;                        // overlay: init phase only
    u16* Ql = lds + 4608;                 // overlay: init phase only
    float* frow = (float*)(lds + 18432);  // [64] rescale factors

    const int tid = threadIdx.x;
    const int h   = blockIdx.y;
    const int q0  = blockIdx.x * QB;
    const int sp  = blockIdx.z;
    const int kt0 = (sp * NKT) / NSPLIT;
    const int kt1 = ((sp + 1) * NKT) / NSPLIT;

    const int w   = tid >> 6;
    const int l   = tid & 63;
    const int l15 = l & 15, h4 = l >> 4;
    const int qh  = w & 1, kh = w >> 1;   // PV quadrant mapping

    const int lrow = tid & 63, lseg = tid >> 6;
    const int gq = h * DH + lseg * 16;

    {   // stage Q (once, into overlay region)
        const u16* s0 = qhi + (size_t)(q0 + lrow) * DIM + gq;
        const u16* s1 = qlo + (size_t)(q0 + lrow) * DIM + gq;
        uint4 a = ((const uint4*)s0)[0], b = ((const uint4*)s0)[1];
        uint4 c = ((const uint4*)s1)[0], d = ((const uint4*)s1)[1];
        *(uint4*)&Qh[lrow * KP + lseg * 16]     = a;
        *(uint4*)&Qh[lrow * KP + lseg * 16 + 8] = b;
        *(uint4*)&Ql[lrow * KP + lseg * 16]     = c;
        *(uint4*)&Ql[lrow * KP + lseg * 16 + 8] = d;
    }
    uint4 ska, skb, sla, slb, sva, svb;
    {
        const int key0 = kt0 * KB;
        const u16* s0 = khi + (size_t)(key0 + lrow) * DIM + gq;
        const u16* s1 = klo + (size_t)(key0 + lrow) * DIM + gq;
        const u16* s2 = vT + (size_t)(h * DH + lrow) * NN + key0 + lseg * 16;
        ska = ((const uint4*)s0)[0]; skb = ((const uint4*)s0)[1];
        sla = ((const uint4*)s1)[0]; slb = ((const uint4*)s1)[1];
        sva = ((const uint4*)s2)[0]; svb = ((const uint4*)s2)[1];
    }
    __syncthreads();                              // Q staged

    // hoist Q fragments: wave w owns q rows w*16..+15
    half8 qf[2][2];                               // [kc][hi/lo]
    #pragma unroll
    for (int kc = 0; kc < 2; ++kc) {
        const int r = w * 16 + l15;
        const int dc = kc * 32 + h4 * 8;
        qf[kc][0] = *(const half8*)&Qh[r * KP + dc];
        qf[kc][1] = *(const half8*)&Ql[r * KP + dc];
    }
    __syncthreads();                              // hoist done; overlay safe

    const f32x4 z4 = {0.f, 0.f, 0.f, 0.f};
    f32x4 oacc[2][2] = {{z4, z4}, {z4, z4}};
    float m_run[4], l_run[4];
    #pragma unroll
    for (int i = 0; i < 4; ++i) { m_run[i] = -3.0e38f; l_run[i] = 0.f; }

    for (int kt = kt0; kt < kt1; ++kt) {
        *(uint4*)&Kh[lrow * KP + lseg * 16]     = ska;
        *(uint4*)&Kh[lrow * KP + lseg * 16 + 8] = skb;
        *(uint4*)&Kl[lrow * KP + lseg * 16]     = sla;
        *(uint4*)&Kl[lrow * KP + lseg * 16 + 8] = slb;
        *(uint4*)&Vt[lrow * KP + lseg * 16]     = sva;
        *(uint4*)&Vt[lrow * KP + lseg * 16 + 8] = svb;
        __syncthreads();                          // B1: tile staged

        // ---- S = Q K^T (3-pass fp16 hi/lo): 16 q-rows x 64 k per wave ----
        f32x4 sc[4] = {z4, z4, z4, z4};
        __builtin_amdgcn_s_setprio(1);
        #pragma unroll
        for (int kc = 0; kc < 2; ++kc) {
            const int dc = kc * 32 + h4 * 8;
            half8 kfh[4], kfl[4];
            #pragma unroll
            for (int kcb = 0; kcb < 4; ++kcb) {
                const int r = kcb * 16 + l15;
                kfh[kcb] = *(const half8*)&Kh[r * KP + dc];
                kfl[kcb] = *(const half8*)&Kl[r * KP + dc];
            }
            #pragma unroll
            for (int kcb = 0; kcb < 4; ++kcb) {
                sc[kcb] = MFMA16(qf[kc][0], kfh[kcb], sc[kcb]);
                sc[kcb] = MFMA16(qf[kc][0], kfl[kcb], sc[kcb]);
                sc[kcb] = MFMA16(qf[kc][1], kfh[kcb], sc[kcb]);
            }
        }
        __builtin_amdgcn_s_setprio(0);
        // prefetch next tile while softmax runs
        if (kt + 1 < kt1) {
            const int key0 = (kt + 1) * KB;
            const u16* s0 = khi + (size_t)(key0 + lrow) * DIM + gq;
            const u16* s1 = klo + (size_t)(key0 + lrow) * DIM + gq;
            const u16* s2 = vT + (size_t)(h * DH + lrow) * NN + key0 + lseg * 16;
            ska = ((const uint4*)s0)[0]; skb = ((const uint4*)s0)[1];
            sla = ((const uint4*)s1)[0]; slb = ((const uint4*)s1)[1];
            sva = ((const uint4*)s2)[0]; svb = ((const uint4*)s2)[1];
        }
        // ---- wave-local softmax (rows w*16 + h4*4 + i) ----
        float p[4][4], fr[4];
        #pragma unroll
        for (int i = 0; i < 4; ++i) {
            float pm = fmaxf(fmaxf(sc[0][i], sc[1][i]), fmaxf(sc[2][i], sc[3][i]));
            #pragma unroll
            for (int off = 1; off < 16; off <<= 1)
                pm = fmaxf(pm, __shfl_xor(pm, off));
            const float mnew = fmaxf(m_run[i], pm);
            fr[i] = __expf(m_run[i] - mnew);
            m_run[i] = mnew;
            p[0][i] = __expf(sc[0][i] - mnew);
            p[1][i] = __expf(sc[1][i] - mnew);
            p[2][i] = __expf(sc[2][i] - mnew);
            p[3][i] = __expf(sc[3][i] - mnew);
            float ls = (p[0][i] + p[1][i]) + (p[2][i] + p[3][i]);
            #pragma unroll
            for (int off = 1; off < 16; off <<= 1) ls += __shfl_xor(ls, off);
            l_run[i] = l_run[i] * fr[i] + ls;
        }
        // P store: rows w*16+h4*4+i, cols kcb*16+l15
        #pragma unroll
        for (int kcb = 0; kcb < 4; ++kcb) {
            const int kk = kcb * 16 + l15;
            #pragma unroll
            for (int i = 0; i < 4; ++i)
                Pb[(w * 16 + h4 * 4 + i) * KP + kk] = f2h(p[kcb][i]);
        }
        if (l15 == 0) {
            #pragma unroll
            for (int i = 0; i < 4; ++i)
                frow[w * 16 + h4 * 4 + i] = fr[i];
        }
        __syncthreads();                          // B2: P + frow visible

        // ---- PV: o^T += V^T * P^T (quadrant split, P = b128 reads) ----
        float fq[2];
        #pragma unroll
        for (int qb = 0; qb < 2; ++qb) fq[qb] = frow[qh * 32 + qb * 16 + l15];
        #pragma unroll
        for (int db = 0; db < 2; ++db)
            #pragma unroll
            for (int qb = 0; qb < 2; ++qb)
                oacc[db][qb] *= fq[qb];
        __builtin_amdgcn_s_setprio(1);
        #pragma unroll
        for (int kc = 0; kc < 2; ++kc) {
            half8 vf[2], pf[2];
            #pragma unroll
            for (int db = 0; db < 2; ++db)
                vf[db] = *(const half8*)&Vt[(kh * 32 + db * 16 + l15) * KP + kc * 32 + h4 * 8];
            #pragma unroll
            for (int qb = 0; qb < 2; ++qb)
                pf[qb] = *(const half8*)&Pb[(qh * 32 + qb * 16 + l15) * KP + kc * 32 + h4 * 8];
            #pragma unroll
            for (int db = 0; db < 2; ++db)
                #pragma unroll
                for (int qb = 0; qb < 2; ++qb)
                    oacc[db][qb] = MFMA16(vf[db], pf[qb], oacc[db][qb]);
        }
        __builtin_amdgcn_s_setprio(0);
        __syncthreads();                          // B3: PV done, buffers free
    }

    float* ob = (sp == 0) ? op0 : ((sp == 1) ? op1 : ((sp == 2) ? op2 : op3));
    #pragma unroll
    for (int db = 0; db < 2; ++db)
        #pragma unroll
        for (int qb = 0; qb < 2; ++qb) {
            const int qq = q0 + qh * 32 + qb * 16 + l15;
            const int d0 = h * DH + kh * 32 + db * 16 + h4 * 4;
            *(f32x4*)&ob[(size_t)qq * DIM + d0] = oacc[db][qb];
        }
    if (l15 == 0) {
        #pragma unroll
        for (int i = 0; i < 4; ++i) {
            const int r = w * 16 + h4 * 4 + i;
            mpart[((size_t)sp * NN + q0 + r) * NH + h] = m_run[i];
            lpart[((size_t)sp * NN + q0 + r) * NH + h] = l_run[i];
        }
    }
}

// merge the 4 partials -> fp16 hi/lo planes (feeds the MFMA Wo GEMM)
__global__ __launch_bounds__(256) void attn_combine(
    const float* __restrict__ o0, const float* __restrict__ o1,
    const float* __restrict__ o2, const float* __restrict__ o3,
    const float* __restrict__ mp, const float* __restrict__ lp,
    u16* __restrict__ ohi, u16* __restrict__ olo)
{
    const int gid = blockIdx.x * 256 + threadIdx.x;
    const int row = gid >> 6;
    const int c4  = (gid & 63) * 4;
    const int h   = c4 >> 6;
    float m[4], wgt[4];
    #pragma unroll
    for (int z = 0; z < 4; ++z) m[z] = mp[((size_t)z * NN + row) * NH + h];
    const float M = fmaxf(fmaxf(m[0], m[1]), fmaxf(m[2], m[3]));
    float den = 0.f;
    #pragma unroll
    for (int z = 0; z < 4; ++z) {
        wgt[z] = __expf(m[z] - M);
        den += lp[((size_t)z * NN + row) * NH + h] * wgt[z];
    }
    const float inv = 1.f / den;
    const float4 a = *(const float4*)&o0[(size_t)row * DIM + c4];
    const float4 b = *(const float4*)&o1[(size_t)row * DIM + c4];
    const float4 c = *(const float4*)&o2[(size_t)row * DIM + c4];
    const float4 d = *(const float4*)&o3[(size_t)row * DIM + c4];
    float r[4];
    r[0] = (a.x * wgt[0] + b.x * wgt[1] + c.x * wgt[2] + d.x * wgt[3]) * inv;
    r[1] = (a.y * wgt[0] + b.y * wgt[1] + c.y * wgt[2] + d.y * wgt[3]) * inv;
    r[2] = (a.z * wgt[0] + b.z * wgt[1] + c.z * wgt[2] + d.z * wgt[3]) * inv;
    r[3] = (a.w * wgt[0] + b.w * wgt[1] + c.w * wgt[2] + d.w * wgt[3]) * inv;
    u16 hh[4], ll[4];
    #pragma unroll
    for (int j = 0; j < 4; ++j) split16(r[j], hh[j], ll[j]);
    *(uint2*)&ohi[(size_t)row * DIM + c4] =
        make_uint2((u32)hh[0] | ((u32)hh[1] << 16), (u32)hh[2] | ((u32)hh[3] << 16));
    *(uint2*)&olo[(size_t)row * DIM + c4] =
        make_uint2((u32)ll[0] | ((u32)ll[1] << 16), (u32)ll[2] | ((u32)ll[3] << 16));
}

// ---------------- per-node group adapter ----------------
__global__ __launch_bounds__(64) void adapter_kernel(
    const float* __restrict__ feats, const int* __restrict__ grp,
    const float* __restrict__ AW1, const float* __restrict__ Ab1,
    const float* __restrict__ AW2, const float* __restrict__ Ab2,
    float* __restrict__ out)
{
    const int n = blockIdx.x;
    const int lane = threadIdx.x;
    __shared__ float f[F1D];
    f[lane]      = feats[(size_t)n * F1D + lane];
    f[lane + 64] = feats[(size_t)n * F1D + 64 + lane];
    __syncthreads();
    const int g = grp[n];
    const float* W1 = AW1 + (size_t)g * F1D * AD;
    const int a = lane & 31;
    const int half = lane >> 5;
    float hsum = 0.f;
    for (int d = 0; d < 64; ++d)
        hsum = fmaf(f[half * 64 + d], W1[(half * 64 + d) * AD + a], hsum);
    hsum += __shfl_xor(hsum, 32);
    hsum = fmaxf(hsum + Ab1[g * AD + a], 0.f);
    float p = hsum * AW2[g * AD + a];
    #pragma unroll
    for (int mm = 1; mm < 32; mm <<= 1) p += __shfl_xor(p, mm);
    if (lane == 0) out[n] = p + Ab2[g];
}

// ---------------- host-side orchestration ----------------
extern "C" void kernel_launch(void* const* d_in, const int* in_sizes, int n_in,
                              void* d_out, int out_size, void* d_ws, size_t ws_size,
                              hipStream_t stream)
{
    const float* x_in   = (const float*)d_in[0];
    const float* eattr  = (const float*)d_in[1];
    const float* Wself  = (const float*)d_in[2];
    const float* Wnbr   = (const float*)d_in[3];
    const float* convb  = (const float*)d_in[4];
    const float* gamma  = (const float*)d_in[5];
    const float* beta   = (const float*)d_in[6];
    const float* bnmean = (const float*)d_in[7];
    const float* bnvar  = (const float*)d_in[8];
    const float* Wqkv   = (const float*)d_in[9];
    const float* bqkv   = (const float*)d_in[10];
    const float* Wo     = (const float*)d_in[11];
    const float* bo     = (const float*)d_in[12];
    const float* fc1W   = (const float*)d_in[13];
    const float* fc1b   = (const float*)d_in[14];
    const float* AW1    = (const float*)d_in[15];
    const float* Ab1    = (const float*)d_in[16];
    const float* AW2    = (const float*)d_in[17];
    const float* Ab2    = (const float*)d_in[18];
    const int*   eidx   = (const int*)d_in[19];
    const int*   grp    = (const int*)d_in[20];
    const int* srcArr = eidx;
    const int* dstArr = eidx + NE;

    float* fws = (float*)d_ws;
    const size_t NM = (size_t)NN * DIM;
    float* bufA  = fws;                  // x L0 / x L2 (residual)
    float* bufB  = fws + NM;             // attn op0
    float* bufC  = fws + 2 * NM;         // x L1 / attn op1
    float* feats = fws + 3 * NM;         // NN x F1D
    float* mpart = fws + 3 * NM + NM / 2;         // [4][NN][NH]
    float* lpart = mpart + 4 * NN * NH;
    u16* up = (u16*)(lpart + 4 * NN * NH);
    u16* xpAh = up;             u16* xpAl = xpAh + NM;   // x planes ping
    u16* xpBh = xpAl + NM;      u16* xpBl = xpBh + NM;   // x planes pong
    u16* aggh = xpBl + NM;      u16* aggl = aggh + NM;   // agg planes
    u16* qh = aggl + NM;        u16* ql = qh + NM;       // Q planes / combine out
    u16* kh = ql + NM;          u16* kl = kh + NM;       // K planes / Wo out
    u16* vt = kl + NM;                                   // V^T fp16 [256][NN]
    u16* wcath = vt + NM;                                // [3][256][512]
    u16* wcatl = wcath + 3 * 131072;
    u16* wt4h  = wcatl + 3 * 131072;                     // [4][256][256] qkv+wo
    u16* wt4l  = wt4h + 4 * 65536;
    u16* fc1h  = wt4l + 4 * 65536;                       // [128][256]
    u16* fc1l  = fc1h + 32768;
    int*   esrc = (int*)(fc1l + 32768);                  // NE
    float* ewt  = (float*)(esrc + NE);                   // NE
    int* off    = (int*)(ewt + NE);                      // NN+1
    int* cur    = off + NN + 1;                          // NN
    float* outp = (float*)d_out;

    // attn partial overlays (conv planes dead by attn time)
    float* op2 = (float*)xpAh;           // 2*NM u16 = NM floats
    float* op3 = (float*)xpBh;

    // one-time converts (independent of CSR/conv chain)
    xconvert<<<NM / 4 / 256, 256, 0, stream>>>(x_in, xpAh, xpAl);
    wconv_dual3<<<384, 256, 0, stream>>>(Wself, Wnbr, wcath, wcatl);
    wconvert4<<<256, 256, 0, stream>>>(Wqkv, Wo, wt4h, wt4l);
    wconvert_fc1<<<32, 256, 0, stream>>>(fc1W, fc1h, fc1l);

    // CSR build
    hipMemsetAsync(cur, 0, NN * sizeof(int), stream);
    csr_count<<<NE / 256, 256, 0, stream>>>(dstArr, cur);
    csr_scan<<<1, 64, 0, stream>>>(cur, off);
    hipMemsetAsync(cur, 0, NN * sizeof(int), stream);
    csr_fill<<<NE / 256, 256, 0, stream>>>(dstArr, srcArr, eattr, off, cur, esrc, ewt);

    const dim3 gc(DIM / 64, NN / 64);
    const int rgrid = NN * DIM / 4 / 256;

    // conv layer 0: x_in -> bufA (fp32) + xpB planes
    agg_kernel<false><<<NN / 4, 256, 0, stream>>>(x_in, esrc, ewt, off, aggh, aggl);
    conv_mfma<EPI_BNELU><<<gc, 256, 0, stream>>>(
        xpAh, xpAl, aggh, aggl, wcath, wcatl, convb,
        gamma, beta, bnmean, bnvar, bufA, xpBh, xpBl);
    // conv layer 1: bufA -> bufC + xpA planes
    agg_kernel<false><<<NN / 4, 256, 0, stream>>>(bufA, esrc, ewt, off, aggh, aggl);
    conv_mfma<EPI_BNELU><<<gc, 256, 0, stream>>>(
        xpBh, xpBl, aggh, aggl, wcath + 131072, wcatl + 131072, convb + DIM,
        gamma + DIM, beta + DIM, bnmean + DIM, bnvar + DIM, bufC, xpAh, xpAl);
    // conv layer 2 (edge-weighted, bias only): bufC -> bufA + xpB planes
    agg_kernel<true><<<NN / 4, 256, 0, stream>>>(bufC, esrc, ewt, off, aggh, aggl);
    conv_mfma<EPI_BIAS><<<gc, 256, 0, stream>>>(
        xpAh, xpAl, aggh, aggl, wcath + 262144, wcatl + 262144, convb + 2 * DIM,
        nullptr, nullptr, nullptr, nullptr, bufA, xpBh, xpBl);

    // QKV (fp16 3-pass MFMA) -> Q/K planes (Q/8) + V^T
    qkv_mfma<<<dim3(12, NN / 64), 256, 0, stream>>>(
        xpBh, xpBl, wt4h, wt4l, bqkv, qh, ql, kh, kl, vt);

    // flash attention (4-way key split) -> partials, combine -> o planes
    attn_kernel<<<dim3(NN / QB, NH, NSPLIT), 256, 0, stream>>>(
        qh, ql, kh, kl, vt, bufB, bufC, op2, op3, mpart, lpart);
    attn_combine<<<rgrid, 256, 0, stream>>>(
        bufB, bufC, op2, op3, mpart, lpart, qh, ql);

    // Wo + residual (fp16 3-pass MFMA): kh/kl = planes(bufA + o@Wo + bo)
    mfma_gemm<MEPI_WO><<<gc, 256, 0, stream>>>(
        qh, ql, wt4h + 3 * 65536, wt4l + 3 * 65536, bo, bufA,
        nullptr, kh, kl, DIM, DIM);

    // fc1 + ELU (fp16 3-pass MFMA): feats = elu(x' @ fc1W + fc1b)
    mfma_gemm<MEPI_FC1><<<dim3(F1D / 64, NN / 64), 256, 0, stream>>>(
        kh, kl, fc1h, fc1l, fc1b, nullptr, feats, nullptr, nullptr, DIM, F1D);

    // adapter routing -> out
    adapter_kernel<<<NN, 64, 0, stream>>>(feats, grp, AW1, Ab1, AW2, Ab2, outp);
}

// Round 11
// 258.725 us; speedup vs baseline: 1.3033x; 1.0997x over previous
//
#include <hip/hip_runtime.h>
#include <math.h>

#define NN   4096
#define DIM  256
#define NE   131072
#define NH   4
#define DH   64
#define F1D  128
#define NG   16
#define AD   32

typedef unsigned short u16;
typedef unsigned int   u32;
typedef _Float16 f16;
typedef __attribute__((ext_vector_type(8))) _Float16 half8;
typedef __attribute__((ext_vector_type(4))) float f32x4;

enum { EPI_BIAS = 0, EPI_BNELU = 1 };
enum { MEPI_WO = 0, MEPI_FC1 = 1 };

#define MFMA16(a, b, c) __builtin_amdgcn_mfma_f32_16x16x32_f16(a, b, c, 0, 0, 0)

__device__ inline u16 f2h(float x) { union { f16 f; u16 u; } c; c.f = (f16)x; return c.u; }
// fp16 hi/lo split: x = hi + lo + eps, |eps| <= 2^-24 |x|  (fp32-grade)
__device__ inline void split16(float x, u16& h, u16& l) {
    union { f16 f; u16 u; } ch, cl;
    ch.f = (f16)x;
    cl.f = (f16)(x - (float)ch.f);
    h = ch.u; l = cl.u;
}

// ---------------- CSR build ----------------
__global__ void csr_count(const int* __restrict__ dst, int* __restrict__ cnt) {
    int e = blockIdx.x * 256 + threadIdx.x;
    atomicAdd(&cnt[dst[e]], 1);
}

// parallel exclusive scan over 4096 counts (1 block x 1024 threads).
// Also zeroes cnt (=cur) so csr_fill can atomically re-count from 0.
__global__ __launch_bounds__(1024) void csr_scan(
    int* __restrict__ cnt, int* __restrict__ off)
{
    __shared__ int wsum[16];
    const int t = threadIdx.x;
    const int lane = t & 63;
    int4 v = *(const int4*)&cnt[t * 4];
    const int s = v.x + v.y + v.z + v.w;
    int acc = s;
    #pragma unroll
    for (int o = 1; o < 64; o <<= 1) {
        int u = __shfl_up(acc, o);
        if (lane >= o) acc += u;
    }
    if (lane == 63) wsum[t >> 6] = acc;
    __syncthreads();
    if (t < 16) {
        int w0 = wsum[t];
        int a2 = w0;
        #pragma unroll
        for (int o = 1; o < 16; o <<= 1) {
            int u = __shfl_up(a2, o);
            if (t >= o) a2 += u;
        }
        wsum[t] = a2 - w0;          // exclusive wave offset
    }
    __syncthreads();
    const int base = wsum[t >> 6] + (acc - s);
    off[t * 4 + 0] = base;
    off[t * 4 + 1] = base + v.x;
    off[t * 4 + 2] = base + v.x + v.y;
    off[t * 4 + 3] = base + v.x + v.y + v.z;
    *(int4*)&cnt[t * 4] = make_int4(0, 0, 0, 0);
    if (t == 1023) off[NN] = base + s;
}

__global__ void csr_fill(const int* __restrict__ dst, const int* __restrict__ src,
                         const float* __restrict__ eattr, const int* __restrict__ off,
                         int* __restrict__ cur, int* __restrict__ esrc,
                         float* __restrict__ ewt) {
    int e = blockIdx.x * 256 + threadIdx.x;
    int d = dst[e];
    int pos = off[d] + atomicAdd(&cur[d], 1);
    esrc[pos] = src[e];
    ewt[pos]  = eattr[e];
}

// ---------------- fused one-time prep: all weight/x converts + zero cur ----
// blockIdx ranges: [0,1024) xconvert; [1024,1408) conv weights;
// [1408,1664) qkv+wo weights; [1664,1696) fc1 weights; [1696,1700) zero cur.
__global__ __launch_bounds__(256) void prep_kernel(
    const float* __restrict__ x,
    const float* __restrict__ Ws, const float* __restrict__ Wn,
    const float* __restrict__ Wqkv, const float* __restrict__ Wo,
    const float* __restrict__ fc1W,
    u16* __restrict__ xh, u16* __restrict__ xl,
    u16* __restrict__ wch, u16* __restrict__ wcl,
    u16* __restrict__ w4h, u16* __restrict__ w4l,
    u16* __restrict__ f1h, u16* __restrict__ f1l,
    int* __restrict__ cur)
{
    const int b = blockIdx.x;
    const int t = threadIdx.x;
    if (b < 1024) {                       // x -> fp16 hi/lo planes
        const int gid = b * 256 + t;
        const float4 v = *(const float4*)&x[(size_t)gid * 4];
        u16 h[4], l[4];
        split16(v.x, h[0], l[0]); split16(v.y, h[1], l[1]);
        split16(v.z, h[2], l[2]); split16(v.w, h[3], l[3]);
        *(uint2*)&xh[(size_t)gid * 4] =
            make_uint2((u32)h[0] | ((u32)h[1] << 16), (u32)h[2] | ((u32)h[3] << 16));
        *(uint2*)&xl[(size_t)gid * 4] =
            make_uint2((u32)l[0] | ((u32)l[1] << 16), (u32)l[2] | ((u32)l[3] << 16));
    } else if (b < 1408) {                // [Wself_L | Wnbr_L]^T planes
        const int gid = (b - 1024) * 256 + t;
        const int L = gid / 32768;
        const int rem = gid % 32768;
        const int m = rem / 128;
        const int k4 = (rem % 128) * 4;
        const float* S = Ws + (size_t)L * 65536;
        const float* Nb = Wn + (size_t)L * 65536;
        u16 h[4], l[4];
        #pragma unroll
        for (int j = 0; j < 4; ++j) {
            const int k = k4 + j;
            const float v = (k < 256) ? S[(size_t)k * 256 + m]
                                      : Nb[(size_t)(k - 256) * 256 + m];
            split16(v, h[j], l[j]);
        }
        const size_t o = (size_t)L * 131072 + (size_t)m * 512 + k4;
        *(uint2*)&wch[o] = make_uint2((u32)h[0] | ((u32)h[1] << 16), (u32)h[2] | ((u32)h[3] << 16));
        *(uint2*)&wcl[o] = make_uint2((u32)l[0] | ((u32)l[1] << 16), (u32)l[2] | ((u32)l[3] << 16));
    } else if (b < 1664) {                // Wqkv(3) + Wo transposed planes
        const int gid = (b - 1408) * 256 + t;
        const int mat = gid / 16384;
        const int rem = gid % 16384;
        const int m = rem / 64;
        const int k4 = (rem % 64) * 4;
        const float* W = (mat < 3) ? Wqkv + (size_t)mat * 65536 : Wo;
        u16 h[4], l[4];
        #pragma unroll
        for (int j = 0; j < 4; ++j)
            split16(W[(size_t)(k4 + j) * 256 + m], h[j], l[j]);
        const size_t o = (size_t)mat * 65536 + (size_t)m * 256 + k4;
        *(uint2*)&w4h[o] = make_uint2((u32)h[0] | ((u32)h[1] << 16), (u32)h[2] | ((u32)h[3] << 16));
        *(uint2*)&w4l[o] = make_uint2((u32)l[0] | ((u32)l[1] << 16), (u32)l[2] | ((u32)l[3] << 16));
    } else if (b < 1696) {                // fc1W transposed planes
        const int gid = (b - 1664) * 256 + t;
        const int m = gid / 64;
        const int k4 = (gid % 64) * 4;
        u16 h[4], l[4];
        #pragma unroll
        for (int j = 0; j < 4; ++j)
            split16(fc1W[(size_t)(k4 + j) * F1D + m], h[j], l[j]);
        const size_t o = (size_t)m * 256 + k4;
        *(uint2*)&f1h[o] = make_uint2((u32)h[0] | ((u32)h[1] << 16), (u32)h[2] | ((u32)h[3] << 16));
        *(uint2*)&f1l[o] = make_uint2((u32)l[0] | ((u32)l[1] << 16), (u32)l[2] | ((u32)l[3] << 16));
    } else {                              // zero cur (4096 ints)
        const int gid = (b - 1696) * 256 + t;
        if (gid < NN / 4) *(int4*)&cur[gid * 4] = make_int4(0, 0, 0, 0);
    }
}

// ---------------- neighbor aggregation: 1 wave per node, fp16-plane out ---
template<bool LAST>
__global__ __launch_bounds__(256) void agg_kernel(
    const float* __restrict__ x, const int* __restrict__ esrc,
    const float* __restrict__ ewt, const int* __restrict__ off,
    u16* __restrict__ aggh, u16* __restrict__ aggl)
{
    const int node = blockIdx.x * 4 + (threadIdx.x >> 6);
    const int lane = threadIdx.x & 63;
    const int d4 = lane * 4;
    int j = off[node];
    const int j1 = off[node + 1];
    float4 acc = make_float4(0.f, 0.f, 0.f, 0.f);
    for (; j + 4 <= j1; j += 4) {
        const int s0 = esrc[j], s1 = esrc[j + 1], s2 = esrc[j + 2], s3 = esrc[j + 3];
        const float4 x0 = *(const float4*)&x[(size_t)s0 * DIM + d4];
        const float4 x1 = *(const float4*)&x[(size_t)s1 * DIM + d4];
        const float4 x2 = *(const float4*)&x[(size_t)s2 * DIM + d4];
        const float4 x3 = *(const float4*)&x[(size_t)s3 * DIM + d4];
        const float w0 = LAST ? ewt[j]     : 1.f;
        const float w1 = LAST ? ewt[j + 1] : 1.f;
        const float w2 = LAST ? ewt[j + 2] : 1.f;
        const float w3 = LAST ? ewt[j + 3] : 1.f;
        acc.x = fmaf(x0.x, w0, acc.x); acc.y = fmaf(x0.y, w0, acc.y);
        acc.z = fmaf(x0.z, w0, acc.z); acc.w = fmaf(x0.w, w0, acc.w);
        acc.x = fmaf(x1.x, w1, acc.x); acc.y = fmaf(x1.y, w1, acc.y);
        acc.z = fmaf(x1.z, w1, acc.z); acc.w = fmaf(x1.w, w1, acc.w);
        acc.x = fmaf(x2.x, w2, acc.x); acc.y = fmaf(x2.y, w2, acc.y);
        acc.z = fmaf(x2.z, w2, acc.z); acc.w = fmaf(x2.w, w2, acc.w);
        acc.x = fmaf(x3.x, w3, acc.x); acc.y = fmaf(x3.y, w3, acc.y);
        acc.z = fmaf(x3.z, w3, acc.z); acc.w = fmaf(x3.w, w3, acc.w);
    }
    for (; j < j1; ++j) {
        const int s = esrc[j];
        const float w = LAST ? ewt[j] : 1.f;
        const float4 xv = *(const float4*)&x[(size_t)s * DIM + d4];
        acc.x = fmaf(xv.x, w, acc.x); acc.y = fmaf(xv.y, w, acc.y);
        acc.z = fmaf(xv.z, w, acc.z); acc.w = fmaf(xv.w, w, acc.w);
    }
    u16 h[4], l[4];
    split16(acc.x, h[0], l[0]); split16(acc.y, h[1], l[1]);
    split16(acc.z, h[2], l[2]); split16(acc.w, h[3], l[3]);
    *(uint2*)&aggh[(size_t)node * DIM + d4] =
        make_uint2((u32)h[0] | ((u32)h[1] << 16), (u32)h[2] | ((u32)h[3] << 16));
    *(uint2*)&aggl[(size_t)node * DIM + d4] =
        make_uint2((u32)l[0] | ((u32)l[1] << 16), (u32)l[2] | ((u32)l[3] << 16));
}

// ---------------- conv MFMA GEMM: y = x@Wself + agg@Wnbr + b (+BN+ELU) ----
template<int EPI>
__global__ __launch_bounds__(256) void conv_mfma(
    const u16* __restrict__ xh, const u16* __restrict__ xl,
    const u16* __restrict__ gh, const u16* __restrict__ gl,
    const u16* __restrict__ bth, const u16* __restrict__ btl,
    const float* __restrict__ bias,
    const float* __restrict__ gamma, const float* __restrict__ beta,
    const float* __restrict__ bnmean, const float* __restrict__ bnvar,
    float* __restrict__ outf, u16* __restrict__ oh, u16* __restrict__ ol)
{
    __shared__ u16 lds[4 * 4608];
    u16* As_h = lds;
    u16* As_l = lds + 4608;
    u16* Bs_h = lds + 9216;
    u16* Bs_l = lds + 13824;
    #define TKP 72

    const int tid  = threadIdx.x;
    const int row0 = blockIdx.y * 64;
    const int col0 = blockIdx.x * 64;

    const int w   = tid >> 6;
    const int l15 = tid & 15, h4 = (tid & 63) >> 4;
    const int rh  = w & 1, ch = w >> 1;
    const int lrow = tid & 63, lseg = tid >> 6;
    const int lc = lseg * 16;

    uint4 sah0, sah1, sal0, sal1, sbh0, sbh1, sbl0, sbl1;
    {
        const u16* pah = xh + (size_t)(row0 + lrow) * DIM + lc;
        const u16* pal = xl + (size_t)(row0 + lrow) * DIM + lc;
        const u16* pbh = bth + (size_t)(col0 + lrow) * 512 + lc;
        const u16* pbl = btl + (size_t)(col0 + lrow) * 512 + lc;
        sah0 = ((const uint4*)pah)[0]; sah1 = ((const uint4*)pah)[1];
        sal0 = ((const uint4*)pal)[0]; sal1 = ((const uint4*)pal)[1];
        sbh0 = ((const uint4*)pbh)[0]; sbh1 = ((const uint4*)pbh)[1];
        sbl0 = ((const uint4*)pbl)[0]; sbl1 = ((const uint4*)pbl)[1];
    }

    const f32x4 z4 = {0.f, 0.f, 0.f, 0.f};
    f32x4 acc[2][2] = {{z4, z4}, {z4, z4}};

    for (int kt = 0; kt < 8; ++kt) {
        *(uint4*)&As_h[lrow * TKP + lc]     = sah0;
        *(uint4*)&As_h[lrow * TKP + lc + 8] = sah1;
        *(uint4*)&As_l[lrow * TKP + lc]     = sal0;
        *(uint4*)&As_l[lrow * TKP + lc + 8] = sal1;
        *(uint4*)&Bs_h[lrow * TKP + lc]     = sbh0;
        *(uint4*)&Bs_h[lrow * TKP + lc + 8] = sbh1;
        *(uint4*)&Bs_l[lrow * TKP + lc]     = sbl0;
        *(uint4*)&Bs_l[lrow * TKP + lc + 8] = sbl1;
        __syncthreads();

        __builtin_amdgcn_s_setprio(1);
        #pragma unroll
        for (int kc = 0; kc < 2; ++kc) {
            const int dc = kc * 32 + h4 * 8;
            half8 afh[2], afl[2], bfh[2], bfl[2];
            #pragma unroll
            for (int ab = 0; ab < 2; ++ab) {
                const int r = rh * 32 + ab * 16 + l15;
                afh[ab] = *(const half8*)&As_h[r * TKP + dc];
                afl[ab] = *(const half8*)&As_l[r * TKP + dc];
            }
            #pragma unroll
            for (int bb = 0; bb < 2; ++bb) {
                const int r = ch * 32 + bb * 16 + l15;
                bfh[bb] = *(const half8*)&Bs_h[r * TKP + dc];
                bfl[bb] = *(const half8*)&Bs_l[r * TKP + dc];
            }
            #pragma unroll
            for (int ab = 0; ab < 2; ++ab)
                #pragma unroll
                for (int bb = 0; bb < 2; ++bb) {
                    acc[ab][bb] = MFMA16(afh[ab], bfh[bb], acc[ab][bb]);
                    acc[ab][bb] = MFMA16(afh[ab], bfl[bb], acc[ab][bb]);
                    acc[ab][bb] = MFMA16(afl[ab], bfh[bb], acc[ab][bb]);
                }
        }
        __builtin_amdgcn_s_setprio(0);
        if (kt + 1 < 8) {
            const int kn = kt + 1;
            const u16 *pah, *pal;
            if (kn < 4) {
                pah = xh + (size_t)(row0 + lrow) * DIM + kn * 64 + lc;
                pal = xl + (size_t)(row0 + lrow) * DIM + kn * 64 + lc;
            } else {
                pah = gh + (size_t)(row0 + lrow) * DIM + (kn - 4) * 64 + lc;
                pal = gl + (size_t)(row0 + lrow) * DIM + (kn - 4) * 64 + lc;
            }
            const u16* pbh = bth + (size_t)(col0 + lrow) * 512 + kn * 64 + lc;
            const u16* pbl = btl + (size_t)(col0 + lrow) * 512 + kn * 64 + lc;
            sah0 = ((const uint4*)pah)[0]; sah1 = ((const uint4*)pah)[1];
            sal0 = ((const uint4*)pal)[0]; sal1 = ((const uint4*)pal)[1];
            sbh0 = ((const uint4*)pbh)[0]; sbh1 = ((const uint4*)pbh)[1];
            sbl0 = ((const uint4*)pbl)[0]; sbl1 = ((const uint4*)pbl)[1];
        }
        __syncthreads();
    }

    #pragma unroll
    for (int ab = 0; ab < 2; ++ab)
        #pragma unroll
        for (int bb = 0; bb < 2; ++bb) {
            const int c  = col0 + ch * 32 + bb * 16 + l15;
            const int r0 = row0 + rh * 32 + ab * 16 + h4 * 4;
            #pragma unroll
            for (int i = 0; i < 4; ++i) {
                const int r = r0 + i;
                float t = acc[ab][bb][i] + bias[c];
                if (EPI == EPI_BNELU) {
                    t = gamma[c] * (t - bnmean[c]) * rsqrtf(bnvar[c] + 1e-5f) + beta[c];
                    t = t > 0.f ? t : expm1f(t);
                }
                outf[(size_t)r * DIM + c] = t;
                u16 hh, ll;
                split16(t, hh, ll);
                oh[(size_t)r * DIM + c] = hh;
                ol[(size_t)r * DIM + c] = ll;
            }
        }
    #undef TKP
}

// ---------------- QKV MFMA GEMM (fp16 3-pass) -----------------------------
__global__ __launch_bounds__(256) void qkv_mfma(
    const u16* __restrict__ xh, const u16* __restrict__ xl,
    const u16* __restrict__ wth, const u16* __restrict__ wtl,
    const float* __restrict__ bias,
    u16* __restrict__ qh_o, u16* __restrict__ ql_o,
    u16* __restrict__ kh_o, u16* __restrict__ kl_o,
    u16* __restrict__ vt_o)
{
    __shared__ u16 lds[4 * 4608];
    u16* As_h = lds;
    u16* As_l = lds + 4608;
    u16* Bs_h = lds + 9216;
    u16* Bs_l = lds + 13824;
    #define TKP 72

    const int tid  = threadIdx.x;
    const int row0 = blockIdx.y * 64;
    const int mat  = blockIdx.x >> 2;
    const int col0 = (blockIdx.x & 3) * 64;
    const float* biasp = bias + mat * DIM;

    const int w   = tid >> 6;
    const int l15 = tid & 15, h4 = (tid & 63) >> 4;
    const int rh  = w & 1, ch = w >> 1;
    const int lrow = tid & 63, lseg = tid >> 6;
    const int lc = lseg * 16;

    const size_t brow = (size_t)(mat * 256 + col0 + lrow) * 256;
    uint4 sah0, sah1, sal0, sal1, sbh0, sbh1, sbl0, sbl1;
    {
        const u16* pah = xh + (size_t)(row0 + lrow) * DIM + lc;
        const u16* pal = xl + (size_t)(row0 + lrow) * DIM + lc;
        sah0 = ((const uint4*)pah)[0]; sah1 = ((const uint4*)pah)[1];
        sal0 = ((const uint4*)pal)[0]; sal1 = ((const uint4*)pal)[1];
        sbh0 = ((const uint4*)(wth + brow + lc))[0]; sbh1 = ((const uint4*)(wth + brow + lc))[1];
        sbl0 = ((const uint4*)(wtl + brow + lc))[0]; sbl1 = ((const uint4*)(wtl + brow + lc))[1];
    }

    const f32x4 z4 = {0.f, 0.f, 0.f, 0.f};
    f32x4 acc[2][2] = {{z4, z4}, {z4, z4}};

    for (int kt = 0; kt < 4; ++kt) {
        *(uint4*)&As_h[lrow * TKP + lc]     = sah0;
        *(uint4*)&As_h[lrow * TKP + lc + 8] = sah1;
        *(uint4*)&As_l[lrow * TKP + lc]     = sal0;
        *(uint4*)&As_l[lrow * TKP + lc + 8] = sal1;
        *(uint4*)&Bs_h[lrow * TKP + lc]     = sbh0;
        *(uint4*)&Bs_h[lrow * TKP + lc + 8] = sbh1;
        *(uint4*)&Bs_l[lrow * TKP + lc]     = sbl0;
        *(uint4*)&Bs_l[lrow * TKP + lc + 8] = sbl1;
        __syncthreads();

        __builtin_amdgcn_s_setprio(1);
        #pragma unroll
        for (int kc = 0; kc < 2; ++kc) {
            const int dc = kc * 32 + h4 * 8;
            half8 afh[2], afl[2], bfh[2], bfl[2];
            #pragma unroll
            for (int ab = 0; ab < 2; ++ab) {
                const int r = rh * 32 + ab * 16 + l15;
                afh[ab] = *(const half8*)&As_h[r * TKP + dc];
                afl[ab] = *(const half8*)&As_l[r * TKP + dc];
            }
            #pragma unroll
            for (int bb = 0; bb < 2; ++bb) {
                const int r = ch * 32 + bb * 16 + l15;
                bfh[bb] = *(const half8*)&Bs_h[r * TKP + dc];
                bfl[bb] = *(const half8*)&Bs_l[r * TKP + dc];
            }
            #pragma unroll
            for (int ab = 0; ab < 2; ++ab)
                #pragma unroll
                for (int bb = 0; bb < 2; ++bb) {
                    acc[ab][bb] = MFMA16(afh[ab], bfh[bb], acc[ab][bb]);
                    acc[ab][bb] = MFMA16(afh[ab], bfl[bb], acc[ab][bb]);
                    acc[ab][bb] = MFMA16(afl[ab], bfh[bb], acc[ab][bb]);
                }
        }
        __builtin_amdgcn_s_setprio(0);
        if (kt + 1 < 4) {
            const int kb = (kt + 1) * 64 + lc;
            const u16* pah = xh + (size_t)(row0 + lrow) * DIM + kb;
            const u16* pal = xl + (size_t)(row0 + lrow) * DIM + kb;
            sah0 = ((const uint4*)pah)[0]; sah1 = ((const uint4*)pah)[1];
            sal0 = ((const uint4*)pal)[0]; sal1 = ((const uint4*)pal)[1];
            sbh0 = ((const uint4*)(wth + brow + kb))[0]; sbh1 = ((const uint4*)(wth + brow + kb))[1];
            sbl0 = ((const uint4*)(wtl + brow + kb))[0]; sbl1 = ((const uint4*)(wtl + brow + kb))[1];
        }
        __syncthreads();
    }

    const float s = (mat == 0) ? 0.125f : 1.0f;
    u16* oph = (mat == 0) ? qh_o : kh_o;
    u16* opl = (mat == 0) ? ql_o : kl_o;
    #pragma unroll
    for (int ab = 0; ab < 2; ++ab)
        #pragma unroll
        for (int bb = 0; bb < 2; ++bb) {
            const int c  = col0 + ch * 32 + bb * 16 + l15;
            const int r0 = row0 + rh * 32 + ab * 16 + h4 * 4;
            if (mat < 2) {
                #pragma unroll
                for (int i = 0; i < 4; ++i) {
                    const int r = r0 + i;
                    const float t = (acc[ab][bb][i] + biasp[c]) * s;
                    u16 hh, ll;
                    split16(t, hh, ll);
                    oph[(size_t)r * DIM + c] = hh;
                    opl[(size_t)r * DIM + c] = ll;
                }
            } else {
                u16 v[4];
                #pragma unroll
                for (int i = 0; i < 4; ++i)
                    v[i] = f2h(acc[ab][bb][i] + biasp[c]);
                *(uint2*)&vt_o[(size_t)c * NN + r0] =
                    make_uint2((u32)v[0] | ((u32)v[1] << 16), (u32)v[2] | ((u32)v[3] << 16));
            }
        }
    #undef TKP
}

// ---------------- MFMA fp16 GEMM (Wo / fc1) -------------------------------
template<int MEPI>
__global__ __launch_bounds__(256) void mfma_gemm(
    const u16* __restrict__ Ah, const u16* __restrict__ Al,
    const u16* __restrict__ Bth, const u16* __restrict__ Btl,
    const float* __restrict__ bias, const float* __restrict__ resid,
    float* __restrict__ outf, u16* __restrict__ outh, u16* __restrict__ outl,
    int K, int M)
{
    __shared__ u16 lds[4 * 4608];
    u16* As_h = lds;
    u16* As_l = lds + 4608;
    u16* Bs_h = lds + 9216;
    u16* Bs_l = lds + 13824;
    #define TKP 72

    const int tid  = threadIdx.x;
    const int row0 = blockIdx.y * 64;
    const int col0 = blockIdx.x * 64;

    const int w   = tid >> 6;
    const int l15 = tid & 15, h4 = (tid & 63) >> 4;
    const int rh  = w & 1, ch = w >> 1;
    const int lrow = tid & 63, lseg = tid >> 6;
    const int lc = lseg * 16;

    uint4 sah0, sah1, sal0, sal1, sbh0, sbh1, sbl0, sbl1;
    {
        const u16* pa0 = Ah  + (size_t)(row0 + lrow) * K + lc;
        const u16* pa1 = Al  + (size_t)(row0 + lrow) * K + lc;
        const u16* pb0 = Bth + (size_t)(col0 + lrow) * K + lc;
        const u16* pb1 = Btl + (size_t)(col0 + lrow) * K + lc;
        sah0 = ((const uint4*)pa0)[0]; sah1 = ((const uint4*)pa0)[1];
        sal0 = ((const uint4*)pa1)[0]; sal1 = ((const uint4*)pa1)[1];
        sbh0 = ((const uint4*)pb0)[0]; sbh1 = ((const uint4*)pb0)[1];
        sbl0 = ((const uint4*)pb1)[0]; sbl1 = ((const uint4*)pb1)[1];
    }

    const f32x4 z4 = {0.f, 0.f, 0.f, 0.f};
    f32x4 acc[2][2] = {{z4, z4}, {z4, z4}};
    const int NKT2 = K / 64;

    for (int kt = 0; kt < NKT2; ++kt) {
        *(uint4*)&As_h[lrow * TKP + lc]     = sah0;
        *(uint4*)&As_h[lrow * TKP + lc + 8] = sah1;
        *(uint4*)&As_l[lrow * TKP + lc]     = sal0;
        *(uint4*)&As_l[lrow * TKP + lc + 8] = sal1;
        *(uint4*)&Bs_h[lrow * TKP + lc]     = sbh0;
        *(uint4*)&Bs_h[lrow * TKP + lc + 8] = sbh1;
        *(uint4*)&Bs_l[lrow * TKP + lc]     = sbl0;
        *(uint4*)&Bs_l[lrow * TKP + lc + 8] = sbl1;
        __syncthreads();

        __builtin_amdgcn_s_setprio(1);
        #pragma unroll
        for (int kc = 0; kc < 2; ++kc) {
            const int dc = kc * 32 + h4 * 8;
            half8 afh[2], afl[2], bfh[2], bfl[2];
            #pragma unroll
            for (int ab = 0; ab < 2; ++ab) {
                const int r = rh * 32 + ab * 16 + l15;
                afh[ab] = *(const half8*)&As_h[r * TKP + dc];
                afl[ab] = *(const half8*)&As_l[r * TKP + dc];
            }
            #pragma unroll
            for (int bb = 0; bb < 2; ++bb) {
                const int r = ch * 32 + bb * 16 + l15;
                bfh[bb] = *(const half8*)&Bs_h[r * TKP + dc];
                bfl[bb] = *(const half8*)&Bs_l[r * TKP + dc];
            }
            #pragma unroll
            for (int ab = 0; ab < 2; ++ab)
                #pragma unroll
                for (int bb = 0; bb < 2; ++bb) {
                    acc[ab][bb] = MFMA16(afh[ab], bfh[bb], acc[ab][bb]);
                    acc[ab][bb] = MFMA16(afh[ab], bfl[bb], acc[ab][bb]);
                    acc[ab][bb] = MFMA16(afl[ab], bfh[bb], acc[ab][bb]);
                }
        }
        __builtin_amdgcn_s_setprio(0);
        if (kt + 1 < NKT2) {
            const int kb = (kt + 1) * 64 + lc;
            const u16* pa0 = Ah  + (size_t)(row0 + lrow) * K + kb;
            const u16* pa1 = Al  + (size_t)(row0 + lrow) * K + kb;
            const u16* pb0 = Bth + (size_t)(col0 + lrow) * K + kb;
            const u16* pb1 = Btl + (size_t)(col0 + lrow) * K + kb;
            sah0 = ((const uint4*)pa0)[0]; sah1 = ((const uint4*)pa0)[1];
            sal0 = ((const uint4*)pa1)[0]; sal1 = ((const uint4*)pa1)[1];
            sbh0 = ((const uint4*)pb0)[0]; sbh1 = ((const uint4*)pb0)[1];
            sbl0 = ((const uint4*)pb1)[0]; sbl1 = ((const uint4*)pb1)[1];
        }
        __syncthreads();
    }

    #pragma unroll
    for (int ab = 0; ab < 2; ++ab)
        #pragma unroll
        for (int bb = 0; bb < 2; ++bb) {
            const int c  = col0 + ch * 32 + bb * 16 + l15;
            const int r0 = row0 + rh * 32 + ab * 16 + h4 * 4;
            #pragma unroll
            for (int i = 0; i < 4; ++i) {
                const int r = r0 + i;
                float t = acc[ab][bb][i] + bias[c];
                if (MEPI == MEPI_WO) {
                    t += resid[(size_t)r * M + c];
                    u16 hh, ll;
                    split16(t, hh, ll);
                    outh[(size_t)r * M + c] = hh;
                    outl[(size_t)r * M + c] = ll;
                } else {    // FC1: bias + ELU -> fp32 feats
                    t = t > 0.f ? t : expm1f(t);
                    outf[(size_t)r * M + c] = t;
                }
            }
        }
    #undef TKP
}

// ---------------- MFMA flash attention (fp16, wave-local PV) --------------
// QK^T: wave w owns q-rows w*16..+15 x all 64 k. PV: SAME wave ownership —
// wave w computes o^T[all 64 d][its 16 q] via 4 d-block fragments, so the
// P transpose and rescale factors are wave-local (LDS, no block barrier).
// 2 barriers per tile (stage-ready, all-reads-done).
#define QB 64
#define KB 64
#define NSPLIT 4
#define NKT (NN / KB)
#define KP 72

__global__ __launch_bounds__(256, 3) void attn_kernel(
    const u16* __restrict__ qhi, const u16* __restrict__ qlo,
    const u16* __restrict__ khi, const u16* __restrict__ klo,
    const u16* __restrict__ vT,
    float* __restrict__ op0, float* __restrict__ op1,
    float* __restrict__ op2, float* __restrict__ op3,
    float* __restrict__ mpart, float* __restrict__ lpart)
{
    __shared__ u16 lds[18560];            // 37120 B
    u16* Kh = lds;                        // [64][72]
    u16* Kl = lds + 4608;
    u16* Vt = lds + 9216;                 // [d][k] per-head
    u16* Pb = lds + 13824;                // [q][72] P fp16 (wave-local rows)
    u16* Qh = lds;                        // overlay: init phase only
    u16* Ql = lds + 4608;                 // overlay: init phase only
    float* frow = (float*)(lds + 18432);  // [64] rescale (wave-local 16 each)

    const int tid = threadIdx.x;
    const int h   = blockIdx.y;
    const int q0  = blockIdx.x * QB;
    const int sp  = blockIdx.z;
    const int kt0 = (sp * NKT) / NSPLIT;
    const int kt1 = ((sp + 1) * NKT) / NSPLIT;

    const int w   = tid >> 6;
    const int l   = tid & 63;
    const int l15 = l & 15, h4 = l >> 4;

    const int lrow = tid & 63, lseg = tid >> 6;
    const int gq = h * DH + lseg * 16;

    {   // stage Q (once, into overlay region)
        const u16* s0 = qhi + (size_t)(q0 + lrow) * DIM + gq;
        const u16* s1 = qlo + (size_t)(q0 + lrow) * DIM + gq;
        uint4 a = ((const uint4*)s0)[0], b = ((const uint4*)s0)[1];
        uint4 c = ((const uint4*)s1)[0], d = ((const uint4*)s1)[1];
        *(uint4*)&Qh[lrow * KP + lseg * 16]     = a;
        *(uint4*)&Qh[lrow * KP + lseg * 16 + 8] = b;
        *(uint4*)&Ql[lrow * KP + lseg * 16]     = c;
        *(uint4*)&Ql[lrow * KP + lseg * 16 + 8] = d;
    }
    uint4 ska, skb, sla, slb, sva, svb;
    {
        const int key0 = kt0 * KB;
        const u16* s0 = khi + (size_t)(key0 + lrow) * DIM + gq;
        const u16* s1 = klo + (size_t)(key0 + lrow) * DIM + gq;
        const u16* s2 = vT + (size_t)(h * DH + lrow) * NN + key0 + lseg * 16;
        ska = ((const uint4*)s0)[0]; skb = ((const uint4*)s0)[1];
        sla = ((const uint4*)s1)[0]; slb = ((const uint4*)s1)[1];
        sva = ((const uint4*)s2)[0]; svb = ((const uint4*)s2)[1];
    }
    __syncthreads();                              // Q staged

    // hoist Q fragments: wave w owns q rows w*16..+15
    half8 qf[2][2];                               // [kc][hi/lo]
    #pragma unroll
    for (int kc = 0; kc < 2; ++kc) {
        const int r = w * 16 + l15;
        const int dc = kc * 32 + h4 * 8;
        qf[kc][0] = *(const half8*)&Qh[r * KP + dc];
        qf[kc][1] = *(const half8*)&Ql[r * KP + dc];
    }
    __syncthreads();                              // hoist done; overlay safe

    const f32x4 z4 = {0.f, 0.f, 0.f, 0.f};
    f32x4 oacc[4] = {z4, z4, z4, z4};             // d-blocks 0..3 for own 16 q
    float m_run[4], l_run[4];
    #pragma unroll
    for (int i = 0; i < 4; ++i) { m_run[i] = -3.0e38f; l_run[i] = 0.f; }

    for (int kt = kt0; kt < kt1; ++kt) {
        *(uint4*)&Kh[lrow * KP + lseg * 16]     = ska;
        *(uint4*)&Kh[lrow * KP + lseg * 16 + 8] = skb;
        *(uint4*)&Kl[lrow * KP + lseg * 16]     = sla;
        *(uint4*)&Kl[lrow * KP + lseg * 16 + 8] = slb;
        *(uint4*)&Vt[lrow * KP + lseg * 16]     = sva;
        *(uint4*)&Vt[lrow * KP + lseg * 16 + 8] = svb;
        __syncthreads();                          // B1: tile staged

        // ---- S = Q K^T (3-pass fp16 hi/lo): 16 q-rows x 64 k per wave ----
        f32x4 sc[4] = {z4, z4, z4, z4};
        __builtin_amdgcn_s_setprio(1);
        #pragma unroll
        for (int kc = 0; kc < 2; ++kc) {
            const int dc = kc * 32 + h4 * 8;
            half8 kfh[4], kfl[4];
            #pragma unroll
            for (int kcb = 0; kcb < 4; ++kcb) {
                const int r = kcb * 16 + l15;
                kfh[kcb] = *(const half8*)&Kh[r * KP + dc];
                kfl[kcb] = *(const half8*)&Kl[r * KP + dc];
            }
            #pragma unroll
            for (int kcb = 0; kcb < 4; ++kcb) {
                sc[kcb] = MFMA16(qf[kc][0], kfh[kcb], sc[kcb]);
                sc[kcb] = MFMA16(qf[kc][0], kfl[kcb], sc[kcb]);
                sc[kcb] = MFMA16(qf[kc][1], kfh[kcb], sc[kcb]);
            }
        }
        __builtin_amdgcn_s_setprio(0);
        // prefetch next tile while softmax runs
        if (kt + 1 < kt1) {
            const int key0 = (kt + 1) * KB;
            const u16* s0 = khi + (size_t)(key0 + lrow) * DIM + gq;
            const u16* s1 = klo + (size_t)(key0 + lrow) * DIM + gq;
            const u16* s2 = vT + (size_t)(h * DH + lrow) * NN + key0 + lseg * 16;
            ska = ((const uint4*)s0)[0]; skb = ((const uint4*)s0)[1];
            sla = ((const uint4*)s1)[0]; slb = ((const uint4*)s1)[1];
            sva = ((const uint4*)s2)[0]; svb = ((const uint4*)s2)[1];
        }
        // ---- wave-local softmax (rows w*16 + h4*4 + i) ----
        float p[4][4], fr[4];
        #pragma unroll
        for (int i = 0; i < 4; ++i) {
            float pm = fmaxf(fmaxf(sc[0][i], sc[1][i]), fmaxf(sc[2][i], sc[3][i]));
            #pragma unroll
            for (int off = 1; off < 16; off <<= 1)
                pm = fmaxf(pm, __shfl_xor(pm, off));
            const float mnew = fmaxf(m_run[i], pm);
            fr[i] = __expf(m_run[i] - mnew);
            m_run[i] = mnew;
            p[0][i] = __expf(sc[0][i] - mnew);
            p[1][i] = __expf(sc[1][i] - mnew);
            p[2][i] = __expf(sc[2][i] - mnew);
            p[3][i] = __expf(sc[3][i] - mnew);
            float ls = (p[0][i] + p[1][i]) + (p[2][i] + p[3][i]);
            #pragma unroll
            for (int off = 1; off < 16; off <<= 1) ls += __shfl_xor(ls, off);
            l_run[i] = l_run[i] * fr[i] + ls;
        }
        // P store (wave-local rows): rows w*16+h4*4+i, cols kcb*16+l15
        #pragma unroll
        for (int kcb = 0; kcb < 4; ++kcb) {
            const int kk = kcb * 16 + l15;
            #pragma unroll
            for (int i = 0; i < 4; ++i)
                Pb[(w * 16 + h4 * 4 + i) * KP + kk] = f2h(p[kcb][i]);
        }
        if (l15 == 0) {
            #pragma unroll
            for (int i = 0; i < 4; ++i)
                frow[w * 16 + h4 * 4 + i] = fr[i];
        }
        // NO block barrier: Pb rows + frow entries are this wave's own;
        // compiler inserts the lgkmcnt wait before the reads below.
        const float frq = frow[w * 16 + l15];
        #pragma unroll
        for (int db = 0; db < 4; ++db) oacc[db] *= frq;
        // ---- PV: wave-local. pf = P[own q=w*16+l15][k-slice] ----
        __builtin_amdgcn_s_setprio(1);
        #pragma unroll
        for (int kc = 0; kc < 2; ++kc) {
            const half8 pf = *(const half8*)&Pb[(w * 16 + l15) * KP + kc * 32 + h4 * 8];
            #pragma unroll
            for (int db = 0; db < 4; ++db) {
                const half8 vf = *(const half8*)&Vt[(db * 16 + l15) * KP + kc * 32 + h4 * 8];
                oacc[db] = MFMA16(vf, pf, oacc[db]);
            }
        }
        __builtin_amdgcn_s_setprio(0);
        __syncthreads();                          // B2: all reads done
    }

    float* ob = (sp == 0) ? op0 : ((sp == 1) ? op1 : ((sp == 2) ? op2 : op3));
    #pragma unroll
    for (int db = 0; db < 4; ++db)
        *(f32x4*)&ob[(size_t)(q0 + w * 16 + l15) * DIM + h * DH + db * 16 + h4 * 4] = oacc[db];
    if (l15 == 0) {
        #pragma unroll
        for (int i = 0; i < 4; ++i) {
            const int r = w * 16 + h4 * 4 + i;
            mpart[((size_t)sp * NN + q0 + r) * NH + h] = m_run[i];
            lpart[((size_t)sp * NN + q0 + r) * NH + h] = l_run[i];
        }
    }
}

// merge the 4 partials -> fp16 hi/lo planes (feeds the MFMA Wo GEMM)
__global__ __launch_bounds__(256) void attn_combine(
    const float* __restrict__ o0, const float* __restrict__ o1,
    const float* __restrict__ o2, const float* __restrict__ o3,
    const float* __restrict__ mp, const float* __restrict__ lp,
    u16* __restrict__ ohi, u16* __restrict__ olo)
{
    const int gid = blockIdx.x * 256 + threadIdx.x;
    const int row = gid >> 6;
    const int c4  = (gid & 63) * 4;
    const int h   = c4 >> 6;
    float m[4], wgt[4];
    #pragma unroll
    for (int z = 0; z < 4; ++z) m[z] = mp[((size_t)z * NN + row) * NH + h];
    const float M = fmaxf(fmaxf(m[0], m[1]), fmaxf(m[2], m[3]));
    float den = 0.f;
    #pragma unroll
    for (int z = 0; z < 4; ++z) {
        wgt[z] = __expf(m[z] - M);
        den += lp[((size_t)z * NN + row) * NH + h] * wgt[z];
    }
    const float inv = 1.f / den;
    const float4 a = *(const float4*)&o0[(size_t)row * DIM + c4];
    const float4 b = *(const float4*)&o1[(size_t)row * DIM + c4];
    const float4 c = *(const float4*)&o2[(size_t)row * DIM + c4];
    const float4 d = *(const float4*)&o3[(size_t)row * DIM + c4];
    float r[4];
    r[0] = (a.x * wgt[0] + b.x * wgt[1] + c.x * wgt[2] + d.x * wgt[3]) * inv;
    r[1] = (a.y * wgt[0] + b.y * wgt[1] + c.y * wgt[2] + d.y * wgt[3]) * inv;
    r[2] = (a.z * wgt[0] + b.z * wgt[1] + c.z * wgt[2] + d.z * wgt[3]) * inv;
    r[3] = (a.w * wgt[0] + b.w * wgt[1] + c.w * wgt[2] + d.w * wgt[3]) * inv;
    u16 hh[4], ll[4];
    #pragma unroll
    for (int j = 0; j < 4; ++j) split16(r[j], hh[j], ll[j]);
    *(uint2*)&ohi[(size_t)row * DIM + c4] =
        make_uint2((u32)hh[0] | ((u32)hh[1] << 16), (u32)hh[2] | ((u32)hh[3] << 16));
    *(uint2*)&olo[(size_t)row * DIM + c4] =
        make_uint2((u32)ll[0] | ((u32)ll[1] << 16), (u32)ll[2] | ((u32)ll[3] << 16));
}

// ---------------- per-node group adapter ----------------
__global__ __launch_bounds__(64) void adapter_kernel(
    const float* __restrict__ feats, const int* __restrict__ grp,
    const float* __restrict__ AW1, const float* __restrict__ Ab1,
    const float* __restrict__ AW2, const float* __restrict__ Ab2,
    float* __restrict__ out)
{
    const int n = blockIdx.x;
    const int lane = threadIdx.x;
    __shared__ float f[F1D];
    f[lane]      = feats[(size_t)n * F1D + lane];
    f[lane + 64] = feats[(size_t)n * F1D + 64 + lane];
    __syncthreads();
    const int g = grp[n];
    const float* W1 = AW1 + (size_t)g * F1D * AD;
    const int a = lane & 31;
    const int half = lane >> 5;
    float hsum = 0.f;
    for (int d = 0; d < 64; ++d)
        hsum = fmaf(f[half * 64 + d], W1[(half * 64 + d) * AD + a], hsum);
    hsum += __shfl_xor(hsum, 32);
    hsum = fmaxf(hsum + Ab1[g * AD + a], 0.f);
    float p = hsum * AW2[g * AD + a];
    #pragma unroll
    for (int mm = 1; mm < 32; mm <<= 1) p += __shfl_xor(p, mm);
    if (lane == 0) out[n] = p + Ab2[g];
}

// ---------------- host-side orchestration ----------------
extern "C" void kernel_launch(void* const* d_in, const int* in_sizes, int n_in,
                              void* d_out, int out_size, void* d_ws, size_t ws_size,
                              hipStream_t stream)
{
    const float* x_in   = (const float*)d_in[0];
    const float* eattr  = (const float*)d_in[1];
    const float* Wself  = (const float*)d_in[2];
    const float* Wnbr   = (const float*)d_in[3];
    const float* convb  = (const float*)d_in[4];
    const float* gamma  = (const float*)d_in[5];
    const float* beta   = (const float*)d_in[6];
    const float* bnmean = (const float*)d_in[7];
    const float* bnvar  = (const float*)d_in[8];
    const float* Wqkv   = (const float*)d_in[9];
    const float* bqkv   = (const float*)d_in[10];
    const float* Wo     = (const float*)d_in[11];
    const float* bo     = (const float*)d_in[12];
    const float* fc1W   = (const float*)d_in[13];
    const float* fc1b   = (const float*)d_in[14];
    const float* AW1    = (const float*)d_in[15];
    const float* Ab1    = (const float*)d_in[16];
    const float* AW2    = (const float*)d_in[17];
    const float* Ab2    = (const float*)d_in[18];
    const int*   eidx   = (const int*)d_in[19];
    const int*   grp    = (const int*)d_in[20];
    const int* srcArr = eidx;
    const int* dstArr = eidx + NE;

    float* fws = (float*)d_ws;
    const size_t NM = (size_t)NN * DIM;
    float* bufA  = fws;                  // x L0 / x L2 (residual)
    float* bufB  = fws + NM;             // attn op0
    float* bufC  = fws + 2 * NM;         // x L1 / attn op1
    float* feats = fws + 3 * NM;         // NN x F1D
    float* mpart = fws + 3 * NM + NM / 2;         // [4][NN][NH]
    float* lpart = mpart + 4 * NN * NH;
    u16* up = (u16*)(lpart + 4 * NN * NH);
    u16* xpAh = up;             u16* xpAl = xpAh + NM;   // x planes ping
    u16* xpBh = xpAl + NM;      u16* xpBl = xpBh + NM;   // x planes pong
    u16* aggh = xpBl + NM;      u16* aggl = aggh + NM;   // agg planes
    u16* qh = aggl + NM;        u16* ql = qh + NM;       // Q planes / combine out
    u16* kh = ql + NM;          u16* kl = kh + NM;       // K planes / Wo out
    u16* vt = kl + NM;                                   // V^T fp16 [256][NN]
    u16* wcath = vt + NM;                                // [3][256][512]
    u16* wcatl = wcath + 3 * 131072;
    u16* wt4h  = wcatl + 3 * 131072;                     // [4][256][256] qkv+wo
    u16* wt4l  = wt4h + 4 * 65536;
    u16* fc1h  = wt4l + 4 * 65536;                       // [128][256]
    u16* fc1l  = fc1h + 32768;
    int*   esrc = (int*)(fc1l + 32768);                  // NE
    float* ewt  = (float*)(esrc + NE);                   // NE
    int* off    = (int*)(ewt + NE);                      // NN+1
    int* cur    = off + NN + 1;                          // NN
    float* outp = (float*)d_out;

    // attn partial overlays (conv planes dead by attn time)
    float* op2 = (float*)xpAh;           // 2*NM u16 = NM floats
    float* op3 = (float*)xpBh;

    // fused prep: all converts + zero(cur)
    prep_kernel<<<1700, 256, 0, stream>>>(
        x_in, Wself, Wnbr, Wqkv, Wo, fc1W,
        xpAh, xpAl, wcath, wcatl, wt4h, wt4l, fc1h, fc1l, cur);

    // CSR build (csr_scan zeroes cur for csr_fill)
    csr_count<<<NE / 256, 256, 0, stream>>>(dstArr, cur);
    csr_scan<<<1, 1024, 0, stream>>>(cur, off);
    csr_fill<<<NE / 256, 256, 0, stream>>>(dstArr, srcArr, eattr, off, cur, esrc, ewt);

    const dim3 gc(DIM / 64, NN / 64);
    const int rgrid = NN * DIM / 4 / 256;

    // conv layer 0: x_in -> bufA (fp32) + xpB planes
    agg_kernel<false><<<NN / 4, 256, 0, stream>>>(x_in, esrc, ewt, off, aggh, aggl);
    conv_mfma<EPI_BNELU><<<gc, 256, 0, stream>>>(
        xpAh, xpAl, aggh, aggl, wcath, wcatl, convb,
        gamma, beta, bnmean, bnvar, bufA, xpBh, xpBl);
    // conv layer 1: bufA -> bufC + xpA planes
    agg_kernel<false><<<NN / 4, 256, 0, stream>>>(bufA, esrc, ewt, off, aggh, aggl);
    conv_mfma<EPI_BNELU><<<gc, 256, 0, stream>>>(
        xpBh, xpBl, aggh, aggl, wcath + 131072, wcatl + 131072, convb + DIM,
        gamma + DIM, beta + DIM, bnmean + DIM, bnvar + DIM, bufC, xpAh, xpAl);
    // conv layer 2 (edge-weighted, bias only): bufC -> bufA + xpB planes
    agg_kernel<true><<<NN / 4, 256, 0, stream>>>(bufC, esrc, ewt, off, aggh, aggl);
    conv_mfma<EPI_BIAS><<<gc, 256, 0, stream>>>(
        xpAh, xpAl, aggh, aggl, wcath + 262144, wcatl + 262144, convb + 2 * DIM,
        nullptr, nullptr, nullptr, nullptr, bufA, xpBh, xpBl);

    // QKV (fp16 3-pass MFMA) -> Q/K planes (Q/8) + V^T
    qkv_mfma<<<dim3(12, NN / 64), 256, 0, stream>>>(
        xpBh, xpBl, wt4h, wt4l, bqkv, qh, ql, kh, kl, vt);

    // flash attention (4-way key split) -> partials, combine -> o planes
    attn_kernel<<<dim3(NN / QB, NH, NSPLIT), 256, 0, stream>>>(
        qh, ql, kh, kl, vt, bufB, bufC, op2, op3, mpart, lpart);
    attn_combine<<<rgrid, 256, 0, stream>>>(
        bufB, bufC, op2, op3, mpart, lpart, qh, ql);

    // Wo + residual (fp16 3-pass MFMA): kh/kl = planes(bufA + o@Wo + bo)
    mfma_gemm<MEPI_WO><<<gc, 256, 0, stream>>>(
        qh, ql, wt4h + 3 * 65536, wt4l + 3 * 65536, bo, bufA,
        nullptr, kh, kl, DIM, DIM);

    // fc1 + ELU (fp16 3-pass MFMA): feats = elu(x' @ fc1W + fc1b)
    mfma_gemm<MEPI_FC1><<<dim3(F1D / 64, NN / 64), 256, 0, stream>>>(
        kh, kl, fc1h, fc1l, fc1b, nullptr, feats, nullptr, nullptr, DIM, F1D);

    // adapter routing -> out
    adapter_kernel<<<NN, 64, 0, stream>>>(feats, grp, AW1, Ab1, AW2, Ab2, outp);
}

// Round 12
// 244.479 us; speedup vs baseline: 1.3792x; 1.0583x over previous
//
#include <hip/hip_runtime.h>
#include <math.h>

#define NN   4096
#define DIM  256
#define NE   131072
#define NH   4
#define DH   64
#define F1D  128
#define NG   16
#define AD   32

typedef unsigned short u16;
typedef unsigned int   u32;
typedef _Float16 f16;
typedef __attribute__((ext_vector_type(8))) _Float16 half8;
typedef __attribute__((ext_vector_type(4))) float f32x4;

enum { EPI_BIAS = 0, EPI_BNELU = 1 };
enum { MEPI_WO = 0, MEPI_FC1 = 1 };

#define MFMA16(a, b, c) __builtin_amdgcn_mfma_f32_16x16x32_f16(a, b, c, 0, 0, 0)

__device__ inline u16 f2h(float x) { union { f16 f; u16 u; } c; c.f = (f16)x; return c.u; }
// fp16 hi/lo split: x = hi + lo + eps, |eps| <= 2^-24 |x|  (fp32-grade)
__device__ inline void split16(float x, u16& h, u16& l) {
    union { f16 f; u16 u; } ch, cl;
    ch.f = (f16)x;
    cl.f = (f16)(x - (float)ch.f);
    h = ch.u; l = cl.u;
}

// ---------------- CSR build ----------------
__global__ void csr_count(const int* __restrict__ dst, int* __restrict__ cnt) {
    int e = blockIdx.x * 256 + threadIdx.x;
    atomicAdd(&cnt[dst[e]], 1);
}

// parallel exclusive scan over 4096 counts (1 block x 1024 threads).
// Also zeroes cnt (=cur) so csr_fill can atomically re-count from 0.
__global__ __launch_bounds__(1024) void csr_scan(
    int* __restrict__ cnt, int* __restrict__ off)
{
    __shared__ int wsum[16];
    const int t = threadIdx.x;
    const int lane = t & 63;
    int4 v = *(const int4*)&cnt[t * 4];
    const int s = v.x + v.y + v.z + v.w;
    int acc = s;
    #pragma unroll
    for (int o = 1; o < 64; o <<= 1) {
        int u = __shfl_up(acc, o);
        if (lane >= o) acc += u;
    }
    if (lane == 63) wsum[t >> 6] = acc;
    __syncthreads();
    if (t < 16) {
        int w0 = wsum[t];
        int a2 = w0;
        #pragma unroll
        for (int o = 1; o < 16; o <<= 1) {
            int u = __shfl_up(a2, o);
            if (t >= o) a2 += u;
        }
        wsum[t] = a2 - w0;          // exclusive wave offset
    }
    __syncthreads();
    const int base = wsum[t >> 6] + (acc - s);
    off[t * 4 + 0] = base;
    off[t * 4 + 1] = base + v.x;
    off[t * 4 + 2] = base + v.x + v.y;
    off[t * 4 + 3] = base + v.x + v.y + v.z;
    *(int4*)&cnt[t * 4] = make_int4(0, 0, 0, 0);
    if (t == 1023) off[NN] = base + s;
}

__global__ void csr_fill(const int* __restrict__ dst, const int* __restrict__ src,
                         const float* __restrict__ eattr, const int* __restrict__ off,
                         int* __restrict__ cur, int* __restrict__ esrc,
                         float* __restrict__ ewt) {
    int e = blockIdx.x * 256 + threadIdx.x;
    int d = dst[e];
    int pos = off[d] + atomicAdd(&cur[d], 1);
    esrc[pos] = src[e];
    ewt[pos]  = eattr[e];
}

// ---------------- fused one-time prep: all weight/x converts + zero cur ----
__global__ __launch_bounds__(256) void prep_kernel(
    const float* __restrict__ x,
    const float* __restrict__ Ws, const float* __restrict__ Wn,
    const float* __restrict__ Wqkv, const float* __restrict__ Wo,
    const float* __restrict__ fc1W,
    u16* __restrict__ xh, u16* __restrict__ xl,
    u16* __restrict__ wch, u16* __restrict__ wcl,
    u16* __restrict__ w4h, u16* __restrict__ w4l,
    u16* __restrict__ f1h, u16* __restrict__ f1l,
    int* __restrict__ cur)
{
    const int b = blockIdx.x;
    const int t = threadIdx.x;
    if (b < 1024) {                       // x -> fp16 hi/lo planes
        const int gid = b * 256 + t;
        const float4 v = *(const float4*)&x[(size_t)gid * 4];
        u16 h[4], l[4];
        split16(v.x, h[0], l[0]); split16(v.y, h[1], l[1]);
        split16(v.z, h[2], l[2]); split16(v.w, h[3], l[3]);
        *(uint2*)&xh[(size_t)gid * 4] =
            make_uint2((u32)h[0] | ((u32)h[1] << 16), (u32)h[2] | ((u32)h[3] << 16));
        *(uint2*)&xl[(size_t)gid * 4] =
            make_uint2((u32)l[0] | ((u32)l[1] << 16), (u32)l[2] | ((u32)l[3] << 16));
    } else if (b < 1408) {                // [Wself_L | Wnbr_L]^T planes
        const int gid = (b - 1024) * 256 + t;
        const int L = gid / 32768;
        const int rem = gid % 32768;
        const int m = rem / 128;
        const int k4 = (rem % 128) * 4;
        const float* S = Ws + (size_t)L * 65536;
        const float* Nb = Wn + (size_t)L * 65536;
        u16 h[4], l[4];
        #pragma unroll
        for (int j = 0; j < 4; ++j) {
            const int k = k4 + j;
            const float v = (k < 256) ? S[(size_t)k * 256 + m]
                                      : Nb[(size_t)(k - 256) * 256 + m];
            split16(v, h[j], l[j]);
        }
        const size_t o = (size_t)L * 131072 + (size_t)m * 512 + k4;
        *(uint2*)&wch[o] = make_uint2((u32)h[0] | ((u32)h[1] << 16), (u32)h[2] | ((u32)h[3] << 16));
        *(uint2*)&wcl[o] = make_uint2((u32)l[0] | ((u32)l[1] << 16), (u32)l[2] | ((u32)l[3] << 16));
    } else if (b < 1664) {                // Wqkv(3) + Wo transposed planes
        const int gid = (b - 1408) * 256 + t;
        const int mat = gid / 16384;
        const int rem = gid % 16384;
        const int m = rem / 64;
        const int k4 = (rem % 64) * 4;
        const float* W = (mat < 3) ? Wqkv + (size_t)mat * 65536 : Wo;
        u16 h[4], l[4];
        #pragma unroll
        for (int j = 0; j < 4; ++j)
            split16(W[(size_t)(k4 + j) * 256 + m], h[j], l[j]);
        const size_t o = (size_t)mat * 65536 + (size_t)m * 256 + k4;
        *(uint2*)&w4h[o] = make_uint2((u32)h[0] | ((u32)h[1] << 16), (u32)h[2] | ((u32)h[3] << 16));
        *(uint2*)&w4l[o] = make_uint2((u32)l[0] | ((u32)l[1] << 16), (u32)l[2] | ((u32)l[3] << 16));
    } else if (b < 1696) {                // fc1W transposed planes
        const int gid = (b - 1664) * 256 + t;
        const int m = gid / 64;
        const int k4 = (gid % 64) * 4;
        u16 h[4], l[4];
        #pragma unroll
        for (int j = 0; j < 4; ++j)
            split16(fc1W[(size_t)(k4 + j) * F1D + m], h[j], l[j]);
        const size_t o = (size_t)m * 256 + k4;
        *(uint2*)&f1h[o] = make_uint2((u32)h[0] | ((u32)h[1] << 16), (u32)h[2] | ((u32)h[3] << 16));
        *(uint2*)&f1l[o] = make_uint2((u32)l[0] | ((u32)l[1] << 16), (u32)l[2] | ((u32)l[3] << 16));
    } else {                              // zero cur (4096 ints)
        const int gid = (b - 1696) * 256 + t;
        if (gid < NN / 4) *(int4*)&cur[gid * 4] = make_int4(0, 0, 0, 0);
    }
}

// ---------------- neighbor aggregation: 1 wave per node, fp16-plane out ---
template<bool LAST>
__global__ __launch_bounds__(256) void agg_kernel(
    const float* __restrict__ x, const int* __restrict__ esrc,
    const float* __restrict__ ewt, const int* __restrict__ off,
    u16* __restrict__ aggh, u16* __restrict__ aggl)
{
    const int node = blockIdx.x * 4 + (threadIdx.x >> 6);
    const int lane = threadIdx.x & 63;
    const int d4 = lane * 4;
    int j = off[node];
    const int j1 = off[node + 1];
    float4 acc = make_float4(0.f, 0.f, 0.f, 0.f);
    for (; j + 4 <= j1; j += 4) {
        const int s0 = esrc[j], s1 = esrc[j + 1], s2 = esrc[j + 2], s3 = esrc[j + 3];
        const float4 x0 = *(const float4*)&x[(size_t)s0 * DIM + d4];
        const float4 x1 = *(const float4*)&x[(size_t)s1 * DIM + d4];
        const float4 x2 = *(const float4*)&x[(size_t)s2 * DIM + d4];
        const float4 x3 = *(const float4*)&x[(size_t)s3 * DIM + d4];
        const float w0 = LAST ? ewt[j]     : 1.f;
        const float w1 = LAST ? ewt[j + 1] : 1.f;
        const float w2 = LAST ? ewt[j + 2] : 1.f;
        const float w3 = LAST ? ewt[j + 3] : 1.f;
        acc.x = fmaf(x0.x, w0, acc.x); acc.y = fmaf(x0.y, w0, acc.y);
        acc.z = fmaf(x0.z, w0, acc.z); acc.w = fmaf(x0.w, w0, acc.w);
        acc.x = fmaf(x1.x, w1, acc.x); acc.y = fmaf(x1.y, w1, acc.y);
        acc.z = fmaf(x1.z, w1, acc.z); acc.w = fmaf(x1.w, w1, acc.w);
        acc.x = fmaf(x2.x, w2, acc.x); acc.y = fmaf(x2.y, w2, acc.y);
        acc.z = fmaf(x2.z, w2, acc.z); acc.w = fmaf(x2.w, w2, acc.w);
        acc.x = fmaf(x3.x, w3, acc.x); acc.y = fmaf(x3.y, w3, acc.y);
        acc.z = fmaf(x3.z, w3, acc.z); acc.w = fmaf(x3.w, w3, acc.w);
    }
    for (; j < j1; ++j) {
        const int s = esrc[j];
        const float w = LAST ? ewt[j] : 1.f;
        const float4 xv = *(const float4*)&x[(size_t)s * DIM + d4];
        acc.x = fmaf(xv.x, w, acc.x); acc.y = fmaf(xv.y, w, acc.y);
        acc.z = fmaf(xv.z, w, acc.z); acc.w = fmaf(xv.w, w, acc.w);
    }
    u16 h[4], l[4];
    split16(acc.x, h[0], l[0]); split16(acc.y, h[1], l[1]);
    split16(acc.z, h[2], l[2]); split16(acc.w, h[3], l[3]);
    *(uint2*)&aggh[(size_t)node * DIM + d4] =
        make_uint2((u32)h[0] | ((u32)h[1] << 16), (u32)h[2] | ((u32)h[3] << 16));
    *(uint2*)&aggl[(size_t)node * DIM + d4] =
        make_uint2((u32)l[0] | ((u32)l[1] << 16), (u32)l[2] | ((u32)l[3] << 16));
}

// ---------------- conv MFMA GEMM: y = x@Wself + agg@Wnbr + b (+BN+ELU) ----
// Next-tile prefetch issued BEFORE the first barrier (early-issue: cover =
// MFMA block instead of ~nothing — round-12 fix).
template<int EPI>
__global__ __launch_bounds__(256) void conv_mfma(
    const u16* __restrict__ xh, const u16* __restrict__ xl,
    const u16* __restrict__ gh, const u16* __restrict__ gl,
    const u16* __restrict__ bth, const u16* __restrict__ btl,
    const float* __restrict__ bias,
    const float* __restrict__ gamma, const float* __restrict__ beta,
    const float* __restrict__ bnmean, const float* __restrict__ bnvar,
    float* __restrict__ outf, u16* __restrict__ oh, u16* __restrict__ ol)
{
    __shared__ u16 lds[4 * 4608];
    u16* As_h = lds;
    u16* As_l = lds + 4608;
    u16* Bs_h = lds + 9216;
    u16* Bs_l = lds + 13824;
    #define TKP 72

    const int tid  = threadIdx.x;
    const int row0 = blockIdx.y * 64;
    const int col0 = blockIdx.x * 64;

    const int w   = tid >> 6;
    const int l15 = tid & 15, h4 = (tid & 63) >> 4;
    const int rh  = w & 1, ch = w >> 1;
    const int lrow = tid & 63, lseg = tid >> 6;
    const int lc = lseg * 16;

    uint4 sah0, sah1, sal0, sal1, sbh0, sbh1, sbl0, sbl1;
    {
        const u16* pah = xh + (size_t)(row0 + lrow) * DIM + lc;
        const u16* pal = xl + (size_t)(row0 + lrow) * DIM + lc;
        const u16* pbh = bth + (size_t)(col0 + lrow) * 512 + lc;
        const u16* pbl = btl + (size_t)(col0 + lrow) * 512 + lc;
        sah0 = ((const uint4*)pah)[0]; sah1 = ((const uint4*)pah)[1];
        sal0 = ((const uint4*)pal)[0]; sal1 = ((const uint4*)pal)[1];
        sbh0 = ((const uint4*)pbh)[0]; sbh1 = ((const uint4*)pbh)[1];
        sbl0 = ((const uint4*)pbl)[0]; sbl1 = ((const uint4*)pbl)[1];
    }

    const f32x4 z4 = {0.f, 0.f, 0.f, 0.f};
    f32x4 acc[2][2] = {{z4, z4}, {z4, z4}};

    for (int kt = 0; kt < 8; ++kt) {
        *(uint4*)&As_h[lrow * TKP + lc]     = sah0;
        *(uint4*)&As_h[lrow * TKP + lc + 8] = sah1;
        *(uint4*)&As_l[lrow * TKP + lc]     = sal0;
        *(uint4*)&As_l[lrow * TKP + lc + 8] = sal1;
        *(uint4*)&Bs_h[lrow * TKP + lc]     = sbh0;
        *(uint4*)&Bs_h[lrow * TKP + lc + 8] = sbh1;
        *(uint4*)&Bs_l[lrow * TKP + lc]     = sbl0;
        *(uint4*)&Bs_l[lrow * TKP + lc + 8] = sbl1;
        if (kt + 1 < 8) {                 // early-issue prefetch
            const int kn = kt + 1;
            const u16 *pah, *pal;
            if (kn < 4) {
                pah = xh + (size_t)(row0 + lrow) * DIM + kn * 64 + lc;
                pal = xl + (size_t)(row0 + lrow) * DIM + kn * 64 + lc;
            } else {
                pah = gh + (size_t)(row0 + lrow) * DIM + (kn - 4) * 64 + lc;
                pal = gl + (size_t)(row0 + lrow) * DIM + (kn - 4) * 64 + lc;
            }
            const u16* pbh = bth + (size_t)(col0 + lrow) * 512 + kn * 64 + lc;
            const u16* pbl = btl + (size_t)(col0 + lrow) * 512 + kn * 64 + lc;
            sah0 = ((const uint4*)pah)[0]; sah1 = ((const uint4*)pah)[1];
            sal0 = ((const uint4*)pal)[0]; sal1 = ((const uint4*)pal)[1];
            sbh0 = ((const uint4*)pbh)[0]; sbh1 = ((const uint4*)pbh)[1];
            sbl0 = ((const uint4*)pbl)[0]; sbl1 = ((const uint4*)pbl)[1];
        }
        __syncthreads();

        __builtin_amdgcn_s_setprio(1);
        #pragma unroll
        for (int kc = 0; kc < 2; ++kc) {
            const int dc = kc * 32 + h4 * 8;
            half8 afh[2], afl[2], bfh[2], bfl[2];
            #pragma unroll
            for (int ab = 0; ab < 2; ++ab) {
                const int r = rh * 32 + ab * 16 + l15;
                afh[ab] = *(const half8*)&As_h[r * TKP + dc];
                afl[ab] = *(const half8*)&As_l[r * TKP + dc];
            }
            #pragma unroll
            for (int bb = 0; bb < 2; ++bb) {
                const int r = ch * 32 + bb * 16 + l15;
                bfh[bb] = *(const half8*)&Bs_h[r * TKP + dc];
                bfl[bb] = *(const half8*)&Bs_l[r * TKP + dc];
            }
            #pragma unroll
            for (int ab = 0; ab < 2; ++ab)
                #pragma unroll
                for (int bb = 0; bb < 2; ++bb) {
                    acc[ab][bb] = MFMA16(afh[ab], bfh[bb], acc[ab][bb]);
                    acc[ab][bb] = MFMA16(afh[ab], bfl[bb], acc[ab][bb]);
                    acc[ab][bb] = MFMA16(afl[ab], bfh[bb], acc[ab][bb]);
                }
        }
        __builtin_amdgcn_s_setprio(0);
        __syncthreads();
    }

    #pragma unroll
    for (int ab = 0; ab < 2; ++ab)
        #pragma unroll
        for (int bb = 0; bb < 2; ++bb) {
            const int c  = col0 + ch * 32 + bb * 16 + l15;
            const int r0 = row0 + rh * 32 + ab * 16 + h4 * 4;
            #pragma unroll
            for (int i = 0; i < 4; ++i) {
                const int r = r0 + i;
                float t = acc[ab][bb][i] + bias[c];
                if (EPI == EPI_BNELU) {
                    t = gamma[c] * (t - bnmean[c]) * rsqrtf(bnvar[c] + 1e-5f) + beta[c];
                    t = t > 0.f ? t : expm1f(t);
                }
                outf[(size_t)r * DIM + c] = t;
                u16 hh, ll;
                split16(t, hh, ll);
                oh[(size_t)r * DIM + c] = hh;
                ol[(size_t)r * DIM + c] = ll;
            }
        }
    #undef TKP
}

// ---------------- QKV MFMA GEMM (fp16 3-pass, early prefetch) -------------
__global__ __launch_bounds__(256) void qkv_mfma(
    const u16* __restrict__ xh, const u16* __restrict__ xl,
    const u16* __restrict__ wth, const u16* __restrict__ wtl,
    const float* __restrict__ bias,
    u16* __restrict__ qh_o, u16* __restrict__ ql_o,
    u16* __restrict__ kh_o, u16* __restrict__ kl_o,
    u16* __restrict__ vt_o)
{
    __shared__ u16 lds[4 * 4608];
    u16* As_h = lds;
    u16* As_l = lds + 4608;
    u16* Bs_h = lds + 9216;
    u16* Bs_l = lds + 13824;
    #define TKP 72

    const int tid  = threadIdx.x;
    const int row0 = blockIdx.y * 64;
    const int mat  = blockIdx.x >> 2;
    const int col0 = (blockIdx.x & 3) * 64;
    const float* biasp = bias + mat * DIM;

    const int w   = tid >> 6;
    const int l15 = tid & 15, h4 = (tid & 63) >> 4;
    const int rh  = w & 1, ch = w >> 1;
    const int lrow = tid & 63, lseg = tid >> 6;
    const int lc = lseg * 16;

    const size_t brow = (size_t)(mat * 256 + col0 + lrow) * 256;
    uint4 sah0, sah1, sal0, sal1, sbh0, sbh1, sbl0, sbl1;
    {
        const u16* pah = xh + (size_t)(row0 + lrow) * DIM + lc;
        const u16* pal = xl + (size_t)(row0 + lrow) * DIM + lc;
        sah0 = ((const uint4*)pah)[0]; sah1 = ((const uint4*)pah)[1];
        sal0 = ((const uint4*)pal)[0]; sal1 = ((const uint4*)pal)[1];
        sbh0 = ((const uint4*)(wth + brow + lc))[0]; sbh1 = ((const uint4*)(wth + brow + lc))[1];
        sbl0 = ((const uint4*)(wtl + brow + lc))[0]; sbl1 = ((const uint4*)(wtl + brow + lc))[1];
    }

    const f32x4 z4 = {0.f, 0.f, 0.f, 0.f};
    f32x4 acc[2][2] = {{z4, z4}, {z4, z4}};

    for (int kt = 0; kt < 4; ++kt) {
        *(uint4*)&As_h[lrow * TKP + lc]     = sah0;
        *(uint4*)&As_h[lrow * TKP + lc + 8] = sah1;
        *(uint4*)&As_l[lrow * TKP + lc]     = sal0;
        *(uint4*)&As_l[lrow * TKP + lc + 8] = sal1;
        *(uint4*)&Bs_h[lrow * TKP + lc]     = sbh0;
        *(uint4*)&Bs_h[lrow * TKP + lc + 8] = sbh1;
        *(uint4*)&Bs_l[lrow * TKP + lc]     = sbl0;
        *(uint4*)&Bs_l[lrow * TKP + lc + 8] = sbl1;
        if (kt + 1 < 4) {                 // early-issue prefetch
            const int kb = (kt + 1) * 64 + lc;
            const u16* pah = xh + (size_t)(row0 + lrow) * DIM + kb;
            const u16* pal = xl + (size_t)(row0 + lrow) * DIM + kb;
            sah0 = ((const uint4*)pah)[0]; sah1 = ((const uint4*)pah)[1];
            sal0 = ((const uint4*)pal)[0]; sal1 = ((const uint4*)pal)[1];
            sbh0 = ((const uint4*)(wth + brow + kb))[0]; sbh1 = ((const uint4*)(wth + brow + kb))[1];
            sbl0 = ((const uint4*)(wtl + brow + kb))[0]; sbl1 = ((const uint4*)(wtl + brow + kb))[1];
        }
        __syncthreads();

        __builtin_amdgcn_s_setprio(1);
        #pragma unroll
        for (int kc = 0; kc < 2; ++kc) {
            const int dc = kc * 32 + h4 * 8;
            half8 afh[2], afl[2], bfh[2], bfl[2];
            #pragma unroll
            for (int ab = 0; ab < 2; ++ab) {
                const int r = rh * 32 + ab * 16 + l15;
                afh[ab] = *(const half8*)&As_h[r * TKP + dc];
                afl[ab] = *(const half8*)&As_l[r * TKP + dc];
            }
            #pragma unroll
            for (int bb = 0; bb < 2; ++bb) {
                const int r = ch * 32 + bb * 16 + l15;
                bfh[bb] = *(const half8*)&Bs_h[r * TKP + dc];
                bfl[bb] = *(const half8*)&Bs_l[r * TKP + dc];
            }
            #pragma unroll
            for (int ab = 0; ab < 2; ++ab)
                #pragma unroll
                for (int bb = 0; bb < 2; ++bb) {
                    acc[ab][bb] = MFMA16(afh[ab], bfh[bb], acc[ab][bb]);
                    acc[ab][bb] = MFMA16(afh[ab], bfl[bb], acc[ab][bb]);
                    acc[ab][bb] = MFMA16(afl[ab], bfh[bb], acc[ab][bb]);
                }
        }
        __builtin_amdgcn_s_setprio(0);
        __syncthreads();
    }

    const float s = (mat == 0) ? 0.125f : 1.0f;
    u16* oph = (mat == 0) ? qh_o : kh_o;
    u16* opl = (mat == 0) ? ql_o : kl_o;
    #pragma unroll
    for (int ab = 0; ab < 2; ++ab)
        #pragma unroll
        for (int bb = 0; bb < 2; ++bb) {
            const int c  = col0 + ch * 32 + bb * 16 + l15;
            const int r0 = row0 + rh * 32 + ab * 16 + h4 * 4;
            if (mat < 2) {
                #pragma unroll
                for (int i = 0; i < 4; ++i) {
                    const int r = r0 + i;
                    const float t = (acc[ab][bb][i] + biasp[c]) * s;
                    u16 hh, ll;
                    split16(t, hh, ll);
                    oph[(size_t)r * DIM + c] = hh;
                    opl[(size_t)r * DIM + c] = ll;
                }
            } else {
                u16 v[4];
                #pragma unroll
                for (int i = 0; i < 4; ++i)
                    v[i] = f2h(acc[ab][bb][i] + biasp[c]);
                *(uint2*)&vt_o[(size_t)c * NN + r0] =
                    make_uint2((u32)v[0] | ((u32)v[1] << 16), (u32)v[2] | ((u32)v[3] << 16));
            }
        }
    #undef TKP
}

// ---------------- MFMA fp16 GEMM (Wo / fc1, early prefetch) ---------------
template<int MEPI>
__global__ __launch_bounds__(256) void mfma_gemm(
    const u16* __restrict__ Ah, const u16* __restrict__ Al,
    const u16* __restrict__ Bth, const u16* __restrict__ Btl,
    const float* __restrict__ bias, const float* __restrict__ resid,
    float* __restrict__ outf, u16* __restrict__ outh, u16* __restrict__ outl,
    int K, int M)
{
    __shared__ u16 lds[4 * 4608];
    u16* As_h = lds;
    u16* As_l = lds + 4608;
    u16* Bs_h = lds + 9216;
    u16* Bs_l = lds + 13824;
    #define TKP 72

    const int tid  = threadIdx.x;
    const int row0 = blockIdx.y * 64;
    const int col0 = blockIdx.x * 64;

    const int w   = tid >> 6;
    const int l15 = tid & 15, h4 = (tid & 63) >> 4;
    const int rh  = w & 1, ch = w >> 1;
    const int lrow = tid & 63, lseg = tid >> 6;
    const int lc = lseg * 16;

    uint4 sah0, sah1, sal0, sal1, sbh0, sbh1, sbl0, sbl1;
    {
        const u16* pa0 = Ah  + (size_t)(row0 + lrow) * K + lc;
        const u16* pa1 = Al  + (size_t)(row0 + lrow) * K + lc;
        const u16* pb0 = Bth + (size_t)(col0 + lrow) * K + lc;
        const u16* pb1 = Btl + (size_t)(col0 + lrow) * K + lc;
        sah0 = ((const uint4*)pa0)[0]; sah1 = ((const uint4*)pa0)[1];
        sal0 = ((const uint4*)pa1)[0]; sal1 = ((const uint4*)pa1)[1];
        sbh0 = ((const uint4*)pb0)[0]; sbh1 = ((const uint4*)pb0)[1];
        sbl0 = ((const uint4*)pb1)[0]; sbl1 = ((const uint4*)pb1)[1];
    }

    const f32x4 z4 = {0.f, 0.f, 0.f, 0.f};
    f32x4 acc[2][2] = {{z4, z4}, {z4, z4}};
    const int NKT2 = K / 64;

    for (int kt = 0; kt < NKT2; ++kt) {
        *(uint4*)&As_h[lrow * TKP + lc]     = sah0;
        *(uint4*)&As_h[lrow * TKP + lc + 8] = sah1;
        *(uint4*)&As_l[lrow * TKP + lc]     = sal0;
        *(uint4*)&As_l[lrow * TKP + lc + 8] = sal1;
        *(uint4*)&Bs_h[lrow * TKP + lc]     = sbh0;
        *(uint4*)&Bs_h[lrow * TKP + lc + 8] = sbh1;
        *(uint4*)&Bs_l[lrow * TKP + lc]     = sbl0;
        *(uint4*)&Bs_l[lrow * TKP + lc + 8] = sbl1;
        if (kt + 1 < NKT2) {              // early-issue prefetch
            const int kb = (kt + 1) * 64 + lc;
            const u16* pa0 = Ah  + (size_t)(row0 + lrow) * K + kb;
            const u16* pa1 = Al  + (size_t)(row0 + lrow) * K + kb;
            const u16* pb0 = Bth + (size_t)(col0 + lrow) * K + kb;
            const u16* pb1 = Btl + (size_t)(col0 + lrow) * K + kb;
            sah0 = ((const uint4*)pa0)[0]; sah1 = ((const uint4*)pa0)[1];
            sal0 = ((const uint4*)pa1)[0]; sal1 = ((const uint4*)pa1)[1];
            sbh0 = ((const uint4*)pb0)[0]; sbh1 = ((const uint4*)pb0)[1];
            sbl0 = ((const uint4*)pb1)[0]; sbl1 = ((const uint4*)pb1)[1];
        }
        __syncthreads();

        __builtin_amdgcn_s_setprio(1);
        #pragma unroll
        for (int kc = 0; kc < 2; ++kc) {
            const int dc = kc * 32 + h4 * 8;
            half8 afh[2], afl[2], bfh[2], bfl[2];
            #pragma unroll
            for (int ab = 0; ab < 2; ++ab) {
                const int r = rh * 32 + ab * 16 + l15;
                afh[ab] = *(const half8*)&As_h[r * TKP + dc];
                afl[ab] = *(const half8*)&As_l[r * TKP + dc];
            }
            #pragma unroll
            for (int bb = 0; bb < 2; ++bb) {
                const int r = ch * 32 + bb * 16 + l15;
                bfh[bb] = *(const half8*)&Bs_h[r * TKP + dc];
                bfl[bb] = *(const half8*)&Bs_l[r * TKP + dc];
            }
            #pragma unroll
            for (int ab = 0; ab < 2; ++ab)
                #pragma unroll
                for (int bb = 0; bb < 2; ++bb) {
                    acc[ab][bb] = MFMA16(afh[ab], bfh[bb], acc[ab][bb]);
                    acc[ab][bb] = MFMA16(afh[ab], bfl[bb], acc[ab][bb]);
                    acc[ab][bb] = MFMA16(afl[ab], bfh[bb], acc[ab][bb]);
                }
        }
        __builtin_amdgcn_s_setprio(0);
        __syncthreads();
    }

    #pragma unroll
    for (int ab = 0; ab < 2; ++ab)
        #pragma unroll
        for (int bb = 0; bb < 2; ++bb) {
            const int c  = col0 + ch * 32 + bb * 16 + l15;
            const int r0 = row0 + rh * 32 + ab * 16 + h4 * 4;
            #pragma unroll
            for (int i = 0; i < 4; ++i) {
                const int r = r0 + i;
                float t = acc[ab][bb][i] + bias[c];
                if (MEPI == MEPI_WO) {
                    t += resid[(size_t)r * M + c];
                    u16 hh, ll;
                    split16(t, hh, ll);
                    outh[(size_t)r * M + c] = hh;
                    outl[(size_t)r * M + c] = ll;
                } else {    // FC1: bias + ELU -> fp32 feats
                    t = t > 0.f ? t : expm1f(t);
                    outf[(size_t)r * M + c] = t;
                }
            }
        }
    #undef TKP
}

// ---------------- MFMA flash attention (fp16, wave-local PV) --------------
// Round 12: 2-deep ping-pong register prefetch (sets A/B, loop unrolled x2),
// loads issued right after LDS stage-writes -> load-to-use ~2 tiles.
#define QB 64
#define KB 64
#define NSPLIT 4
#define NKT (NN / KB)
#define KP 72

__global__ __launch_bounds__(256, 3) void attn_kernel(
    const u16* __restrict__ qhi, const u16* __restrict__ qlo,
    const u16* __restrict__ khi, const u16* __restrict__ klo,
    const u16* __restrict__ vT,
    float* __restrict__ op0, float* __restrict__ op1,
    float* __restrict__ op2, float* __restrict__ op3,
    float* __restrict__ mpart, float* __restrict__ lpart)
{
    __shared__ u16 lds[18560];            // 37120 B
    u16* Kh = lds;                        // [64][72]
    u16* Kl = lds + 4608;
    u16* Vt = lds + 9216;                 // [d][k] per-head
    u16* Pb = lds + 13824;                // [q][72] P fp16 (wave-local rows)
    u16* Qh = lds;                        // overlay: init phase only
    u16* Ql = lds + 4608;                 // overlay: init phase only
    float* frow = (float*)(lds + 18432);  // [64] rescale (wave-local 16 each)

    const int tid = threadIdx.x;
    const int h   = blockIdx.y;
    const int q0  = blockIdx.x * QB;
    const int sp  = blockIdx.z;
    const int kt0 = sp * (NKT / NSPLIT);  // 16 tiles per block (even count)
    const int kt1 = kt0 + NKT / NSPLIT;

    const int w   = tid >> 6;
    const int l   = tid & 63;
    const int l15 = l & 15, h4 = l >> 4;

    const int lrow = tid & 63, lseg = tid >> 6;
    const int gq = h * DH + lseg * 16;

    {   // stage Q (once, into overlay region)
        const u16* s0 = qhi + (size_t)(q0 + lrow) * DIM + gq;
        const u16* s1 = qlo + (size_t)(q0 + lrow) * DIM + gq;
        uint4 a = ((const uint4*)s0)[0], b = ((const uint4*)s0)[1];
        uint4 c = ((const uint4*)s1)[0], d = ((const uint4*)s1)[1];
        *(uint4*)&Qh[lrow * KP + lseg * 16]     = a;
        *(uint4*)&Qh[lrow * KP + lseg * 16 + 8] = b;
        *(uint4*)&Ql[lrow * KP + lseg * 16]     = c;
        *(uint4*)&Ql[lrow * KP + lseg * 16 + 8] = d;
    }

    auto load_tile = [&](int kt_ld, uint4& k0, uint4& k1, uint4& l0, uint4& l1,
                         uint4& v0, uint4& v1) {
        const int key0 = kt_ld * KB;
        const u16* s0 = khi + (size_t)(key0 + lrow) * DIM + gq;
        const u16* s1 = klo + (size_t)(key0 + lrow) * DIM + gq;
        const u16* s2 = vT + (size_t)(h * DH + lrow) * NN + key0 + lseg * 16;
        k0 = ((const uint4*)s0)[0]; k1 = ((const uint4*)s0)[1];
        l0 = ((const uint4*)s1)[0]; l1 = ((const uint4*)s1)[1];
        v0 = ((const uint4*)s2)[0]; v1 = ((const uint4*)s2)[1];
    };

    // prefetch tiles kt0 (set A) and kt0+1 (set B)
    uint4 kA0, kA1, lA0, lA1, vA0, vA1;
    uint4 kB0, kB1, lB0, lB1, vB0, vB1;
    load_tile(kt0,     kA0, kA1, lA0, lA1, vA0, vA1);
    load_tile(kt0 + 1, kB0, kB1, lB0, lB1, vB0, vB1);
    __syncthreads();                              // Q staged

    // hoist Q fragments: wave w owns q rows w*16..+15
    half8 qf[2][2];                               // [kc][hi/lo]
    #pragma unroll
    for (int kc = 0; kc < 2; ++kc) {
        const int r = w * 16 + l15;
        const int dc = kc * 32 + h4 * 8;
        qf[kc][0] = *(const half8*)&Qh[r * KP + dc];
        qf[kc][1] = *(const half8*)&Ql[r * KP + dc];
    }
    __syncthreads();                              // hoist done; overlay safe

    const f32x4 z4 = {0.f, 0.f, 0.f, 0.f};
    f32x4 oacc[4] = {z4, z4, z4, z4};             // d-blocks 0..3 for own 16 q
    float m_run[4], l_run[4];
    #pragma unroll
    for (int i = 0; i < 4; ++i) { m_run[i] = -3.0e38f; l_run[i] = 0.f; }

    auto tile_body = [&](uint4& k0, uint4& k1, uint4& l0, uint4& l1,
                         uint4& v0, uint4& v1, int ldnext) {
        *(uint4*)&Kh[lrow * KP + lseg * 16]     = k0;
        *(uint4*)&Kh[lrow * KP + lseg * 16 + 8] = k1;
        *(uint4*)&Kl[lrow * KP + lseg * 16]     = l0;
        *(uint4*)&Kl[lrow * KP + lseg * 16 + 8] = l1;
        *(uint4*)&Vt[lrow * KP + lseg * 16]     = v0;
        *(uint4*)&Vt[lrow * KP + lseg * 16 + 8] = v1;
        if (ldnext < kt1)                 // early-issue 2-deep prefetch
            load_tile(ldnext, k0, k1, l0, l1, v0, v1);
        __syncthreads();                          // B1: tile staged

        // ---- S = Q K^T (3-pass fp16 hi/lo): 16 q-rows x 64 k per wave ----
        f32x4 sc[4] = {z4, z4, z4, z4};
        __builtin_amdgcn_s_setprio(1);
        #pragma unroll
        for (int kc = 0; kc < 2; ++kc) {
            const int dc = kc * 32 + h4 * 8;
            half8 kfh[4], kfl[4];
            #pragma unroll
            for (int kcb = 0; kcb < 4; ++kcb) {
                const int r = kcb * 16 + l15;
                kfh[kcb] = *(const half8*)&Kh[r * KP + dc];
                kfl[kcb] = *(const half8*)&Kl[r * KP + dc];
            }
            #pragma unroll
            for (int kcb = 0; kcb < 4; ++kcb) {
                sc[kcb] = MFMA16(qf[kc][0], kfh[kcb], sc[kcb]);
                sc[kcb] = MFMA16(qf[kc][0], kfl[kcb], sc[kcb]);
                sc[kcb] = MFMA16(qf[kc][1], kfh[kcb], sc[kcb]);
            }
        }
        __builtin_amdgcn_s_setprio(0);
        // ---- wave-local softmax (rows w*16 + h4*4 + i) ----
        float p[4][4], fr[4];
        #pragma unroll
        for (int i = 0; i < 4; ++i) {
            float pm = fmaxf(fmaxf(sc[0][i], sc[1][i]), fmaxf(sc[2][i], sc[3][i]));
            #pragma unroll
            for (int off = 1; off < 16; off <<= 1)
                pm = fmaxf(pm, __shfl_xor(pm, off));
            const float mnew = fmaxf(m_run[i], pm);
            fr[i] = __expf(m_run[i] - mnew);
            m_run[i] = mnew;
            p[0][i] = __expf(sc[0][i] - mnew);
            p[1][i] = __expf(sc[1][i] - mnew);
            p[2][i] = __expf(sc[2][i] - mnew);
            p[3][i] = __expf(sc[3][i] - mnew);
            float ls = (p[0][i] + p[1][i]) + (p[2][i] + p[3][i]);
            #pragma unroll
            for (int off = 1; off < 16; off <<= 1) ls += __shfl_xor(ls, off);
            l_run[i] = l_run[i] * fr[i] + ls;
        }
        // P store (wave-local rows): rows w*16+h4*4+i, cols kcb*16+l15
        #pragma unroll
        for (int kcb = 0; kcb < 4; ++kcb) {
            const int kk = kcb * 16 + l15;
            #pragma unroll
            for (int i = 0; i < 4; ++i)
                Pb[(w * 16 + h4 * 4 + i) * KP + kk] = f2h(p[kcb][i]);
        }
        if (l15 == 0) {
            #pragma unroll
            for (int i = 0; i < 4; ++i)
                frow[w * 16 + h4 * 4 + i] = fr[i];
        }
        // wave-local: compiler inserts lgkmcnt wait before the reads below
        const float frq = frow[w * 16 + l15];
        #pragma unroll
        for (int db = 0; db < 4; ++db) oacc[db] *= frq;
        // ---- PV: wave-local. pf = P[own q=w*16+l15][k-slice] ----
        __builtin_amdgcn_s_setprio(1);
        #pragma unroll
        for (int kc = 0; kc < 2; ++kc) {
            const half8 pf = *(const half8*)&Pb[(w * 16 + l15) * KP + kc * 32 + h4 * 8];
            #pragma unroll
            for (int db = 0; db < 4; ++db) {
                const half8 vf = *(const half8*)&Vt[(db * 16 + l15) * KP + kc * 32 + h4 * 8];
                oacc[db] = MFMA16(vf, pf, oacc[db]);
            }
        }
        __builtin_amdgcn_s_setprio(0);
        __syncthreads();                          // B2: all reads done
    };

    for (int kt = kt0; kt < kt1; kt += 2) {
        tile_body(kA0, kA1, lA0, lA1, vA0, vA1, kt + 2);
        tile_body(kB0, kB1, lB0, lB1, vB0, vB1, kt + 3);
    }

    float* ob = (sp == 0) ? op0 : ((sp == 1) ? op1 : ((sp == 2) ? op2 : op3));
    #pragma unroll
    for (int db = 0; db < 4; ++db)
        *(f32x4*)&ob[(size_t)(q0 + w * 16 + l15) * DIM + h * DH + db * 16 + h4 * 4] = oacc[db];
    if (l15 == 0) {
        #pragma unroll
        for (int i = 0; i < 4; ++i) {
            const int r = w * 16 + h4 * 4 + i;
            mpart[((size_t)sp * NN + q0 + r) * NH + h] = m_run[i];
            lpart[((size_t)sp * NN + q0 + r) * NH + h] = l_run[i];
        }
    }
}

// merge the 4 partials -> fp16 hi/lo planes (feeds the MFMA Wo GEMM)
__global__ __launch_bounds__(256) void attn_combine(
    const float* __restrict__ o0, const float* __restrict__ o1,
    const float* __restrict__ o2, const float* __restrict__ o3,
    const float* __restrict__ mp, const float* __restrict__ lp,
    u16* __restrict__ ohi, u16* __restrict__ olo)
{
    const int gid = blockIdx.x * 256 + threadIdx.x;
    const int row = gid >> 6;
    const int c4  = (gid & 63) * 4;
    const int h   = c4 >> 6;
    float m[4], wgt[4];
    #pragma unroll
    for (int z = 0; z < 4; ++z) m[z] = mp[((size_t)z * NN + row) * NH + h];
    const float M = fmaxf(fmaxf(m[0], m[1]), fmaxf(m[2], m[3]));
    float den = 0.f;
    #pragma unroll
    for (int z = 0; z < 4; ++z) {
        wgt[z] = __expf(m[z] - M);
        den += lp[((size_t)z * NN + row) * NH + h] * wgt[z];
    }
    const float inv = 1.f / den;
    const float4 a = *(const float4*)&o0[(size_t)row * DIM + c4];
    const float4 b = *(const float4*)&o1[(size_t)row * DIM + c4];
    const float4 c = *(const float4*)&o2[(size_t)row * DIM + c4];
    const float4 d = *(const float4*)&o3[(size_t)row * DIM + c4];
    float r[4];
    r[0] = (a.x * wgt[0] + b.x * wgt[1] + c.x * wgt[2] + d.x * wgt[3]) * inv;
    r[1] = (a.y * wgt[0] + b.y * wgt[1] + c.y * wgt[2] + d.y * wgt[3]) * inv;
    r[2] = (a.z * wgt[0] + b.z * wgt[1] + c.z * wgt[2] + d.z * wgt[3]) * inv;
    r[3] = (a.w * wgt[0] + b.w * wgt[1] + c.w * wgt[2] + d.w * wgt[3]) * inv;
    u16 hh[4], ll[4];
    #pragma unroll
    for (int j = 0; j < 4; ++j) split16(r[j], hh[j], ll[j]);
    *(uint2*)&ohi[(size_t)row * DIM + c4] =
        make_uint2((u32)hh[0] | ((u32)hh[1] << 16), (u32)hh[2] | ((u32)hh[3] << 16));
    *(uint2*)&olo[(size_t)row * DIM + c4] =
        make_uint2((u32)ll[0] | ((u32)ll[1] << 16), (u32)ll[2] | ((u32)ll[3] << 16));
}

// ---------------- per-node group adapter ----------------
__global__ __launch_bounds__(64) void adapter_kernel(
    const float* __restrict__ feats, const int* __restrict__ grp,
    const float* __restrict__ AW1, const float* __restrict__ Ab1,
    const float* __restrict__ AW2, const float* __restrict__ Ab2,
    float* __restrict__ out)
{
    const int n = blockIdx.x;
    const int lane = threadIdx.x;
    __shared__ float f[F1D];
    f[lane]      = feats[(size_t)n * F1D + lane];
    f[lane + 64] = feats[(size_t)n * F1D + 64 + lane];
    __syncthreads();
    const int g = grp[n];
    const float* W1 = AW1 + (size_t)g * F1D * AD;
    const int a = lane & 31;
    const int half = lane >> 5;
    float hsum = 0.f;
    for (int d = 0; d < 64; ++d)
        hsum = fmaf(f[half * 64 + d], W1[(half * 64 + d) * AD + a], hsum);
    hsum += __shfl_xor(hsum, 32);
    hsum = fmaxf(hsum + Ab1[g * AD + a], 0.f);
    float p = hsum * AW2[g * AD + a];
    #pragma unroll
    for (int mm = 1; mm < 32; mm <<= 1) p += __shfl_xor(p, mm);
    if (lane == 0) out[n] = p + Ab2[g];
}

// ---------------- host-side orchestration ----------------
extern "C" void kernel_launch(void* const* d_in, const int* in_sizes, int n_in,
                              void* d_out, int out_size, void* d_ws, size_t ws_size,
                              hipStream_t stream)
{
    const float* x_in   = (const float*)d_in[0];
    const float* eattr  = (const float*)d_in[1];
    const float* Wself  = (const float*)d_in[2];
    const float* Wnbr   = (const float*)d_in[3];
    const float* convb  = (const float*)d_in[4];
    const float* gamma  = (const float*)d_in[5];
    const float* beta   = (const float*)d_in[6];
    const float* bnmean = (const float*)d_in[7];
    const float* bnvar  = (const float*)d_in[8];
    const float* Wqkv   = (const float*)d_in[9];
    const float* bqkv   = (const float*)d_in[10];
    const float* Wo     = (const float*)d_in[11];
    const float* bo     = (const float*)d_in[12];
    const float* fc1W   = (const float*)d_in[13];
    const float* fc1b   = (const float*)d_in[14];
    const float* AW1    = (const float*)d_in[15];
    const float* Ab1    = (const float*)d_in[16];
    const float* AW2    = (const float*)d_in[17];
    const float* Ab2    = (const float*)d_in[18];
    const int*   eidx   = (const int*)d_in[19];
    const int*   grp    = (const int*)d_in[20];
    const int* srcArr = eidx;
    const int* dstArr = eidx + NE;

    float* fws = (float*)d_ws;
    const size_t NM = (size_t)NN * DIM;
    float* bufA  = fws;                  // x L0 / x L2 (residual)
    float* bufB  = fws + NM;             // attn op0
    float* bufC  = fws + 2 * NM;         // x L1 / attn op1
    float* feats = fws + 3 * NM;         // NN x F1D
    float* mpart = fws + 3 * NM + NM / 2;         // [4][NN][NH]
    float* lpart = mpart + 4 * NN * NH;
    u16* up = (u16*)(lpart + 4 * NN * NH);
    u16* xpAh = up;             u16* xpAl = xpAh + NM;   // x planes ping
    u16* xpBh = xpAl + NM;      u16* xpBl = xpBh + NM;   // x planes pong
    u16* aggh = xpBl + NM;      u16* aggl = aggh + NM;   // agg planes
    u16* qh = aggl + NM;        u16* ql = qh + NM;       // Q planes / combine out
    u16* kh = ql + NM;          u16* kl = kh + NM;       // K planes / Wo out
    u16* vt = kl + NM;                                   // V^T fp16 [256][NN]
    u16* wcath = vt + NM;                                // [3][256][512]
    u16* wcatl = wcath + 3 * 131072;
    u16* wt4h  = wcatl + 3 * 131072;                     // [4][256][256] qkv+wo
    u16* wt4l  = wt4h + 4 * 65536;
    u16* fc1h  = wt4l + 4 * 65536;                       // [128][256]
    u16* fc1l  = fc1h + 32768;
    int*   esrc = (int*)(fc1l + 32768);                  // NE
    float* ewt  = (float*)(esrc + NE);                   // NE
    int* off    = (int*)(ewt + NE);                      // NN+1
    int* cur    = off + NN + 1;                          // NN
    float* outp = (float*)d_out;

    // attn partial overlays (conv planes dead by attn time)
    float* op2 = (float*)xpAh;           // 2*NM u16 = NM floats
    float* op3 = (float*)xpBh;

    // fused prep: all converts + zero(cur)
    prep_kernel<<<1700, 256, 0, stream>>>(
        x_in, Wself, Wnbr, Wqkv, Wo, fc1W,
        xpAh, xpAl, wcath, wcatl, wt4h, wt4l, fc1h, fc1l, cur);

    // CSR build (csr_scan zeroes cur for csr_fill)
    csr_count<<<NE / 256, 256, 0, stream>>>(dstArr, cur);
    csr_scan<<<1, 1024, 0, stream>>>(cur, off);
    csr_fill<<<NE / 256, 256, 0, stream>>>(dstArr, srcArr, eattr, off, cur, esrc, ewt);

    const dim3 gc(DIM / 64, NN / 64);
    const int rgrid = NN * DIM / 4 / 256;

    // conv layer 0: x_in -> bufA (fp32) + xpB planes
    agg_kernel<false><<<NN / 4, 256, 0, stream>>>(x_in, esrc, ewt, off, aggh, aggl);
    conv_mfma<EPI_BNELU><<<gc, 256, 0, stream>>>(
        xpAh, xpAl, aggh, aggl, wcath, wcatl, convb,
        gamma, beta, bnmean, bnvar, bufA, xpBh, xpBl);
    // conv layer 1: bufA -> bufC + xpA planes
    agg_kernel<false><<<NN / 4, 256, 0, stream>>>(bufA, esrc, ewt, off, aggh, aggl);
    conv_mfma<EPI_BNELU><<<gc, 256, 0, stream>>>(
        xpBh, xpBl, aggh, aggl, wcath + 131072, wcatl + 131072, convb + DIM,
        gamma + DIM, beta + DIM, bnmean + DIM, bnvar + DIM, bufC, xpAh, xpAl);
    // conv layer 2 (edge-weighted, bias only): bufC -> bufA + xpB planes
    agg_kernel<true><<<NN / 4, 256, 0, stream>>>(bufC, esrc, ewt, off, aggh, aggl);
    conv_mfma<EPI_BIAS><<<gc, 256, 0, stream>>>(
        xpAh, xpAl, aggh, aggl, wcath + 262144, wcatl + 262144, convb + 2 * DIM,
        nullptr, nullptr, nullptr, nullptr, bufA, xpBh, xpBl);

    // QKV (fp16 3-pass MFMA) -> Q/K planes (Q/8) + V^T
    qkv_mfma<<<dim3(12, NN / 64), 256, 0, stream>>>(
        xpBh, xpBl, wt4h, wt4l, bqkv, qh, ql, kh, kl, vt);

    // flash attention (4-way key split) -> partials, combine -> o planes
    attn_kernel<<<dim3(NN / QB, NH, NSPLIT), 256, 0, stream>>>(
        qh, ql, kh, kl, vt, bufB, bufC, op2, op3, mpart, lpart);
    attn_combine<<<rgrid, 256, 0, stream>>>(
        bufB, bufC, op2, op3, mpart, lpart, qh, ql);

    // Wo + residual (fp16 3-pass MFMA): kh/kl = planes(bufA + o@Wo + bo)
    mfma_gemm<MEPI_WO><<<gc, 256, 0, stream>>>(
        qh, ql, wt4h + 3 * 65536, wt4l + 3 * 65536, bo, bufA,
        nullptr, kh, kl, DIM, DIM);

    // fc1 + ELU (fp16 3-pass MFMA): feats = elu(x' @ fc1W + fc1b)
    mfma_gemm<MEPI_FC1><<<dim3(F1D / 64, NN / 64), 256, 0, stream>>>(
        kh, kl, fc1h, fc1l, fc1b, nullptr, feats, nullptr, nullptr, DIM, F1D);

    // adapter routing -> out
    adapter_kernel<<<NN, 64, 0, stream>>>(feats, grp, AW1, Ab1, AW2, Ab2, outp);
}

// Round 13
// 243.078 us; speedup vs baseline: 1.3872x; 1.0058x over previous
//
#include <hip/hip_runtime.h>
#include <math.h>

#define NN   4096
#define DIM  256
#define NE   131072
#define NH   4
#define DH   64
#define F1D  128
#define NG   16
#define AD   32

typedef unsigned short u16;
typedef unsigned int   u32;
typedef _Float16 f16;
typedef __attribute__((ext_vector_type(8))) _Float16 half8;
typedef __attribute__((ext_vector_type(4))) float f32x4;

enum { EPI_BIAS = 0, EPI_BNELU = 1 };
enum { MEPI_WO = 0, MEPI_FC1 = 1 };

#define MFMA16(a, b, c) __builtin_amdgcn_mfma_f32_16x16x32_f16(a, b, c, 0, 0, 0)

__device__ inline u16 f2h(float x) { union { f16 f; u16 u; } c; c.f = (f16)x; return c.u; }
// fp16 hi/lo split: x = hi + lo + eps, |eps| <= 2^-24 |x|  (fp32-grade)
__device__ inline void split16(float x, u16& h, u16& l) {
    union { f16 f; u16 u; } ch, cl;
    ch.f = (f16)x;
    cl.f = (f16)(x - (float)ch.f);
    h = ch.u; l = cl.u;
}

// ---------------- CSR build ----------------
__global__ void csr_count(const int* __restrict__ dst, int* __restrict__ cnt) {
    int e = blockIdx.x * 256 + threadIdx.x;
    atomicAdd(&cnt[dst[e]], 1);
}

__global__ __launch_bounds__(1024) void csr_scan(
    int* __restrict__ cnt, int* __restrict__ off)
{
    __shared__ int wsum[16];
    const int t = threadIdx.x;
    const int lane = t & 63;
    int4 v = *(const int4*)&cnt[t * 4];
    const int s = v.x + v.y + v.z + v.w;
    int acc = s;
    #pragma unroll
    for (int o = 1; o < 64; o <<= 1) {
        int u = __shfl_up(acc, o);
        if (lane >= o) acc += u;
    }
    if (lane == 63) wsum[t >> 6] = acc;
    __syncthreads();
    if (t < 16) {
        int w0 = wsum[t];
        int a2 = w0;
        #pragma unroll
        for (int o = 1; o < 16; o <<= 1) {
            int u = __shfl_up(a2, o);
            if (t >= o) a2 += u;
        }
        wsum[t] = a2 - w0;
    }
    __syncthreads();
    const int base = wsum[t >> 6] + (acc - s);
    off[t * 4 + 0] = base;
    off[t * 4 + 1] = base + v.x;
    off[t * 4 + 2] = base + v.x + v.y;
    off[t * 4 + 3] = base + v.x + v.y + v.z;
    *(int4*)&cnt[t * 4] = make_int4(0, 0, 0, 0);
    if (t == 1023) off[NN] = base + s;
}

__global__ void csr_fill(const int* __restrict__ dst, const int* __restrict__ src,
                         const float* __restrict__ eattr, const int* __restrict__ off,
                         int* __restrict__ cur, int* __restrict__ esrc,
                         float* __restrict__ ewt) {
    int e = blockIdx.x * 256 + threadIdx.x;
    int d = dst[e];
    int pos = off[d] + atomicAdd(&cur[d], 1);
    esrc[pos] = src[e];
    ewt[pos]  = eattr[e];
}

// ---------------- fused one-time prep: all weight/x converts + zero cur ----
__global__ __launch_bounds__(256) void prep_kernel(
    const float* __restrict__ x,
    const float* __restrict__ Ws, const float* __restrict__ Wn,
    const float* __restrict__ Wqkv, const float* __restrict__ Wo,
    const float* __restrict__ fc1W,
    u16* __restrict__ xh, u16* __restrict__ xl,
    u16* __restrict__ wch, u16* __restrict__ wcl,
    u16* __restrict__ w4h, u16* __restrict__ w4l,
    u16* __restrict__ f1h, u16* __restrict__ f1l,
    int* __restrict__ cur)
{
    const int b = blockIdx.x;
    const int t = threadIdx.x;
    if (b < 1024) {
        const int gid = b * 256 + t;
        const float4 v = *(const float4*)&x[(size_t)gid * 4];
        u16 h[4], l[4];
        split16(v.x, h[0], l[0]); split16(v.y, h[1], l[1]);
        split16(v.z, h[2], l[2]); split16(v.w, h[3], l[3]);
        *(uint2*)&xh[(size_t)gid * 4] =
            make_uint2((u32)h[0] | ((u32)h[1] << 16), (u32)h[2] | ((u32)h[3] << 16));
        *(uint2*)&xl[(size_t)gid * 4] =
            make_uint2((u32)l[0] | ((u32)l[1] << 16), (u32)l[2] | ((u32)l[3] << 16));
    } else if (b < 1408) {
        const int gid = (b - 1024) * 256 + t;
        const int L = gid / 32768;
        const int rem = gid % 32768;
        const int m = rem / 128;
        const int k4 = (rem % 128) * 4;
        const float* S = Ws + (size_t)L * 65536;
        const float* Nb = Wn + (size_t)L * 65536;
        u16 h[4], l[4];
        #pragma unroll
        for (int j = 0; j < 4; ++j) {
            const int k = k4 + j;
            const float v = (k < 256) ? S[(size_t)k * 256 + m]
                                      : Nb[(size_t)(k - 256) * 256 + m];
            split16(v, h[j], l[j]);
        }
        const size_t o = (size_t)L * 131072 + (size_t)m * 512 + k4;
        *(uint2*)&wch[o] = make_uint2((u32)h[0] | ((u32)h[1] << 16), (u32)h[2] | ((u32)h[3] << 16));
        *(uint2*)&wcl[o] = make_uint2((u32)l[0] | ((u32)l[1] << 16), (u32)l[2] | ((u32)l[3] << 16));
    } else if (b < 1664) {
        const int gid = (b - 1408) * 256 + t;
        const int mat = gid / 16384;
        const int rem = gid % 16384;
        const int m = rem / 64;
        const int k4 = (rem % 64) * 4;
        const float* W = (mat < 3) ? Wqkv + (size_t)mat * 65536 : Wo;
        u16 h[4], l[4];
        #pragma unroll
        for (int j = 0; j < 4; ++j)
            split16(W[(size_t)(k4 + j) * 256 + m], h[j], l[j]);
        const size_t o = (size_t)mat * 65536 + (size_t)m * 256 + k4;
        *(uint2*)&w4h[o] = make_uint2((u32)h[0] | ((u32)h[1] << 16), (u32)h[2] | ((u32)h[3] << 16));
        *(uint2*)&w4l[o] = make_uint2((u32)l[0] | ((u32)l[1] << 16), (u32)l[2] | ((u32)l[3] << 16));
    } else if (b < 1696) {
        const int gid = (b - 1664) * 256 + t;
        const int m = gid / 64;
        const int k4 = (gid % 64) * 4;
        u16 h[4], l[4];
        #pragma unroll
        for (int j = 0; j < 4; ++j)
            split16(fc1W[(size_t)(k4 + j) * F1D + m], h[j], l[j]);
        const size_t o = (size_t)m * 256 + k4;
        *(uint2*)&f1h[o] = make_uint2((u32)h[0] | ((u32)h[1] << 16), (u32)h[2] | ((u32)h[3] << 16));
        *(uint2*)&f1l[o] = make_uint2((u32)l[0] | ((u32)l[1] << 16), (u32)l[2] | ((u32)l[3] << 16));
    } else {
        const int gid = (b - 1696) * 256 + t;
        if (gid < NN / 4) *(int4*)&cur[gid * 4] = make_int4(0, 0, 0, 0);
    }
}

// ---------------- neighbor aggregation: 1 wave per node, fp16-plane out ---
template<bool LAST>
__global__ __launch_bounds__(256) void agg_kernel(
    const float* __restrict__ x, const int* __restrict__ esrc,
    const float* __restrict__ ewt, const int* __restrict__ off,
    u16* __restrict__ aggh, u16* __restrict__ aggl)
{
    const int node = blockIdx.x * 4 + (threadIdx.x >> 6);
    const int lane = threadIdx.x & 63;
    const int d4 = lane * 4;
    int j = off[node];
    const int j1 = off[node + 1];
    float4 acc = make_float4(0.f, 0.f, 0.f, 0.f);
    for (; j + 4 <= j1; j += 4) {
        const int s0 = esrc[j], s1 = esrc[j + 1], s2 = esrc[j + 2], s3 = esrc[j + 3];
        const float4 x0 = *(const float4*)&x[(size_t)s0 * DIM + d4];
        const float4 x1 = *(const float4*)&x[(size_t)s1 * DIM + d4];
        const float4 x2 = *(const float4*)&x[(size_t)s2 * DIM + d4];
        const float4 x3 = *(const float4*)&x[(size_t)s3 * DIM + d4];
        const float w0 = LAST ? ewt[j]     : 1.f;
        const float w1 = LAST ? ewt[j + 1] : 1.f;
        const float w2 = LAST ? ewt[j + 2] : 1.f;
        const float w3 = LAST ? ewt[j + 3] : 1.f;
        acc.x = fmaf(x0.x, w0, acc.x); acc.y = fmaf(x0.y, w0, acc.y);
        acc.z = fmaf(x0.z, w0, acc.z); acc.w = fmaf(x0.w, w0, acc.w);
        acc.x = fmaf(x1.x, w1, acc.x); acc.y = fmaf(x1.y, w1, acc.y);
        acc.z = fmaf(x1.z, w1, acc.z); acc.w = fmaf(x1.w, w1, acc.w);
        acc.x = fmaf(x2.x, w2, acc.x); acc.y = fmaf(x2.y, w2, acc.y);
        acc.z = fmaf(x2.z, w2, acc.z); acc.w = fmaf(x2.w, w2, acc.w);
        acc.x = fmaf(x3.x, w3, acc.x); acc.y = fmaf(x3.y, w3, acc.y);
        acc.z = fmaf(x3.z, w3, acc.z); acc.w = fmaf(x3.w, w3, acc.w);
    }
    for (; j < j1; ++j) {
        const int s = esrc[j];
        const float w = LAST ? ewt[j] : 1.f;
        const float4 xv = *(const float4*)&x[(size_t)s * DIM + d4];
        acc.x = fmaf(xv.x, w, acc.x); acc.y = fmaf(xv.y, w, acc.y);
        acc.z = fmaf(xv.z, w, acc.z); acc.w = fmaf(xv.w, w, acc.w);
    }
    u16 h[4], l[4];
    split16(acc.x, h[0], l[0]); split16(acc.y, h[1], l[1]);
    split16(acc.z, h[2], l[2]); split16(acc.w, h[3], l[3]);
    *(uint2*)&aggh[(size_t)node * DIM + d4] =
        make_uint2((u32)h[0] | ((u32)h[1] << 16), (u32)h[2] | ((u32)h[3] << 16));
    *(uint2*)&aggl[(size_t)node * DIM + d4] =
        make_uint2((u32)l[0] | ((u32)l[1] << 16), (u32)l[2] | ((u32)l[3] << 16));
}

// ---------------- conv MFMA GEMM: 32x64 tile (round-13: 2 blocks/CU) ------
// y = x@Wself + agg@Wnbr + b (+BN+ELU). Kcat=512. Same k-loop order as the
// 64x64 version -> bit-identical outputs. grid (4, 128).
template<int EPI>
__global__ __launch_bounds__(256) void conv_mfma(
    const u16* __restrict__ xh, const u16* __restrict__ xl,
    const u16* __restrict__ gh, const u16* __restrict__ gl,
    const u16* __restrict__ bth, const u16* __restrict__ btl,
    const float* __restrict__ bias,
    const float* __restrict__ gamma, const float* __restrict__ beta,
    const float* __restrict__ bnmean, const float* __restrict__ bnvar,
    float* __restrict__ outf, u16* __restrict__ oh, u16* __restrict__ ol)
{
    __shared__ u16 lds[13824];           // 27648 B
    u16* As_h = lds;                     // [32][72]
    u16* As_l = lds + 2304;
    u16* Bs_h = lds + 4608;              // [64][72]
    u16* Bs_l = lds + 9216;
    #define TKP 72

    const int tid  = threadIdx.x;
    const int row0 = blockIdx.y * 32;
    const int col0 = blockIdx.x * 64;

    const int w   = tid >> 6;
    const int l15 = tid & 15, h4 = (tid & 63) >> 4;
    const int rh  = w & 1, ch = w >> 1;
    const int arow = tid >> 3, acs = (tid & 7) * 8;   // A stage: 32 rows x 64 k
    const int brow = tid & 63, bseg = tid >> 6;       // B stage: 64 rows x 64 k
    const int bc = bseg * 16;

    uint4 sah, sal, sbh0, sbh1, sbl0, sbl1;
    {
        sah = *((const uint4*)&xh[(size_t)(row0 + arow) * DIM + acs]);
        sal = *((const uint4*)&xl[(size_t)(row0 + arow) * DIM + acs]);
        const u16* pbh = bth + (size_t)(col0 + brow) * 512 + bc;
        const u16* pbl = btl + (size_t)(col0 + brow) * 512 + bc;
        sbh0 = ((const uint4*)pbh)[0]; sbh1 = ((const uint4*)pbh)[1];
        sbl0 = ((const uint4*)pbl)[0]; sbl1 = ((const uint4*)pbl)[1];
    }

    const f32x4 z4 = {0.f, 0.f, 0.f, 0.f};
    f32x4 acc[2] = {z4, z4};

    for (int kt = 0; kt < 8; ++kt) {
        *(uint4*)&As_h[arow * TKP + acs] = sah;
        *(uint4*)&As_l[arow * TKP + acs] = sal;
        *(uint4*)&Bs_h[brow * TKP + bc]     = sbh0;
        *(uint4*)&Bs_h[brow * TKP + bc + 8] = sbh1;
        *(uint4*)&Bs_l[brow * TKP + bc]     = sbl0;
        *(uint4*)&Bs_l[brow * TKP + bc + 8] = sbl1;
        if (kt + 1 < 8) {                 // early-issue prefetch
            const int kn = kt + 1;
            const u16 *pah, *pal;
            if (kn < 4) {
                pah = xh + (size_t)(row0 + arow) * DIM + kn * 64 + acs;
                pal = xl + (size_t)(row0 + arow) * DIM + kn * 64 + acs;
            } else {
                pah = gh + (size_t)(row0 + arow) * DIM + (kn - 4) * 64 + acs;
                pal = gl + (size_t)(row0 + arow) * DIM + (kn - 4) * 64 + acs;
            }
            sah = *((const uint4*)pah);
            sal = *((const uint4*)pal);
            const u16* pbh = bth + (size_t)(col0 + brow) * 512 + kn * 64 + bc;
            const u16* pbl = btl + (size_t)(col0 + brow) * 512 + kn * 64 + bc;
            sbh0 = ((const uint4*)pbh)[0]; sbh1 = ((const uint4*)pbh)[1];
            sbl0 = ((const uint4*)pbl)[0]; sbl1 = ((const uint4*)pbl)[1];
        }
        __syncthreads();

        __builtin_amdgcn_s_setprio(1);
        #pragma unroll
        for (int kc = 0; kc < 2; ++kc) {
            const int dc = kc * 32 + h4 * 8;
            half8 afh, afl, bfh[2], bfl[2];
            afh = *(const half8*)&As_h[(rh * 16 + l15) * TKP + dc];
            afl = *(const half8*)&As_l[(rh * 16 + l15) * TKP + dc];
            #pragma unroll
            for (int bb = 0; bb < 2; ++bb) {
                const int r = ch * 32 + bb * 16 + l15;
                bfh[bb] = *(const half8*)&Bs_h[r * TKP + dc];
                bfl[bb] = *(const half8*)&Bs_l[r * TKP + dc];
            }
            #pragma unroll
            for (int bb = 0; bb < 2; ++bb) {
                acc[bb] = MFMA16(afh, bfh[bb], acc[bb]);
                acc[bb] = MFMA16(afh, bfl[bb], acc[bb]);
                acc[bb] = MFMA16(afl, bfh[bb], acc[bb]);
            }
        }
        __builtin_amdgcn_s_setprio(0);
        __syncthreads();
    }

    #pragma unroll
    for (int bb = 0; bb < 2; ++bb) {
        const int c  = col0 + ch * 32 + bb * 16 + l15;
        const int r0 = row0 + rh * 16 + h4 * 4;
        #pragma unroll
        for (int i = 0; i < 4; ++i) {
            const int r = r0 + i;
            float t = acc[bb][i] + bias[c];
            if (EPI == EPI_BNELU) {
                t = gamma[c] * (t - bnmean[c]) * rsqrtf(bnvar[c] + 1e-5f) + beta[c];
                t = t > 0.f ? t : expm1f(t);
            }
            outf[(size_t)r * DIM + c] = t;
            u16 hh, ll;
            split16(t, hh, ll);
            oh[(size_t)r * DIM + c] = hh;
            ol[(size_t)r * DIM + c] = ll;
        }
    }
    #undef TKP
}

// ---------------- QKV MFMA GEMM (fp16 3-pass, early prefetch) -------------
__global__ __launch_bounds__(256) void qkv_mfma(
    const u16* __restrict__ xh, const u16* __restrict__ xl,
    const u16* __restrict__ wth, const u16* __restrict__ wtl,
    const float* __restrict__ bias,
    u16* __restrict__ qh_o, u16* __restrict__ ql_o,
    u16* __restrict__ kh_o, u16* __restrict__ kl_o,
    u16* __restrict__ vt_o)
{
    __shared__ u16 lds[4 * 4608];
    u16* As_h = lds;
    u16* As_l = lds + 4608;
    u16* Bs_h = lds + 9216;
    u16* Bs_l = lds + 13824;
    #define TKP 72

    const int tid  = threadIdx.x;
    const int row0 = blockIdx.y * 64;
    const int mat  = blockIdx.x >> 2;
    const int col0 = (blockIdx.x & 3) * 64;
    const float* biasp = bias + mat * DIM;

    const int w   = tid >> 6;
    const int l15 = tid & 15, h4 = (tid & 63) >> 4;
    const int rh  = w & 1, ch = w >> 1;
    const int lrow = tid & 63, lseg = tid >> 6;
    const int lc = lseg * 16;

    const size_t brow = (size_t)(mat * 256 + col0 + lrow) * 256;
    uint4 sah0, sah1, sal0, sal1, sbh0, sbh1, sbl0, sbl1;
    {
        const u16* pah = xh + (size_t)(row0 + lrow) * DIM + lc;
        const u16* pal = xl + (size_t)(row0 + lrow) * DIM + lc;
        sah0 = ((const uint4*)pah)[0]; sah1 = ((const uint4*)pah)[1];
        sal0 = ((const uint4*)pal)[0]; sal1 = ((const uint4*)pal)[1];
        sbh0 = ((const uint4*)(wth + brow + lc))[0]; sbh1 = ((const uint4*)(wth + brow + lc))[1];
        sbl0 = ((const uint4*)(wtl + brow + lc))[0]; sbl1 = ((const uint4*)(wtl + brow + lc))[1];
    }

    const f32x4 z4 = {0.f, 0.f, 0.f, 0.f};
    f32x4 acc[2][2] = {{z4, z4}, {z4, z4}};

    for (int kt = 0; kt < 4; ++kt) {
        *(uint4*)&As_h[lrow * TKP + lc]     = sah0;
        *(uint4*)&As_h[lrow * TKP + lc + 8] = sah1;
        *(uint4*)&As_l[lrow * TKP + lc]     = sal0;
        *(uint4*)&As_l[lrow * TKP + lc + 8] = sal1;
        *(uint4*)&Bs_h[lrow * TKP + lc]     = sbh0;
        *(uint4*)&Bs_h[lrow * TKP + lc + 8] = sbh1;
        *(uint4*)&Bs_l[lrow * TKP + lc]     = sbl0;
        *(uint4*)&Bs_l[lrow * TKP + lc + 8] = sbl1;
        if (kt + 1 < 4) {
            const int kb = (kt + 1) * 64 + lc;
            const u16* pah = xh + (size_t)(row0 + lrow) * DIM + kb;
            const u16* pal = xl + (size_t)(row0 + lrow) * DIM + kb;
            sah0 = ((const uint4*)pah)[0]; sah1 = ((const uint4*)pah)[1];
            sal0 = ((const uint4*)pal)[0]; sal1 = ((const uint4*)pal)[1];
            sbh0 = ((const uint4*)(wth + brow + kb))[0]; sbh1 = ((const uint4*)(wth + brow + kb))[1];
            sbl0 = ((const uint4*)(wtl + brow + kb))[0]; sbl1 = ((const uint4*)(wtl + brow + kb))[1];
        }
        __syncthreads();

        __builtin_amdgcn_s_setprio(1);
        #pragma unroll
        for (int kc = 0; kc < 2; ++kc) {
            const int dc = kc * 32 + h4 * 8;
            half8 afh[2], afl[2], bfh[2], bfl[2];
            #pragma unroll
            for (int ab = 0; ab < 2; ++ab) {
                const int r = rh * 32 + ab * 16 + l15;
                afh[ab] = *(const half8*)&As_h[r * TKP + dc];
                afl[ab] = *(const half8*)&As_l[r * TKP + dc];
            }
            #pragma unroll
            for (int bb = 0; bb < 2; ++bb) {
                const int r = ch * 32 + bb * 16 + l15;
                bfh[bb] = *(const half8*)&Bs_h[r * TKP + dc];
                bfl[bb] = *(const half8*)&Bs_l[r * TKP + dc];
            }
            #pragma unroll
            for (int ab = 0; ab < 2; ++ab)
                #pragma unroll
                for (int bb = 0; bb < 2; ++bb) {
                    acc[ab][bb] = MFMA16(afh[ab], bfh[bb], acc[ab][bb]);
                    acc[ab][bb] = MFMA16(afh[ab], bfl[bb], acc[ab][bb]);
                    acc[ab][bb] = MFMA16(afl[ab], bfh[bb], acc[ab][bb]);
                }
        }
        __builtin_amdgcn_s_setprio(0);
        __syncthreads();
    }

    const float s = (mat == 0) ? 0.125f : 1.0f;
    u16* oph = (mat == 0) ? qh_o : kh_o;
    u16* opl = (mat == 0) ? ql_o : kl_o;
    #pragma unroll
    for (int ab = 0; ab < 2; ++ab)
        #pragma unroll
        for (int bb = 0; bb < 2; ++bb) {
            const int c  = col0 + ch * 32 + bb * 16 + l15;
            const int r0 = row0 + rh * 32 + ab * 16 + h4 * 4;
            if (mat < 2) {
                #pragma unroll
                for (int i = 0; i < 4; ++i) {
                    const int r = r0 + i;
                    const float t = (acc[ab][bb][i] + biasp[c]) * s;
                    u16 hh, ll;
                    split16(t, hh, ll);
                    oph[(size_t)r * DIM + c] = hh;
                    opl[(size_t)r * DIM + c] = ll;
                }
            } else {
                u16 v[4];
                #pragma unroll
                for (int i = 0; i < 4; ++i)
                    v[i] = f2h(acc[ab][bb][i] + biasp[c]);
                *(uint2*)&vt_o[(size_t)c * NN + r0] =
                    make_uint2((u32)v[0] | ((u32)v[1] << 16), (u32)v[2] | ((u32)v[3] << 16));
            }
        }
    #undef TKP
}

// ---------------- MFMA fp16 GEMM (Wo / fc1, early prefetch) ---------------
template<int MEPI>
__global__ __launch_bounds__(256) void mfma_gemm(
    const u16* __restrict__ Ah, const u16* __restrict__ Al,
    const u16* __restrict__ Bth, const u16* __restrict__ Btl,
    const float* __restrict__ bias, const float* __restrict__ resid,
    float* __restrict__ outf, u16* __restrict__ outh, u16* __restrict__ outl,
    int K, int M)
{
    __shared__ u16 lds[4 * 4608];
    u16* As_h = lds;
    u16* As_l = lds + 4608;
    u16* Bs_h = lds + 9216;
    u16* Bs_l = lds + 13824;
    #define TKP 72

    const int tid  = threadIdx.x;
    const int row0 = blockIdx.y * 64;
    const int col0 = blockIdx.x * 64;

    const int w   = tid >> 6;
    const int l15 = tid & 15, h4 = (tid & 63) >> 4;
    const int rh  = w & 1, ch = w >> 1;
    const int lrow = tid & 63, lseg = tid >> 6;
    const int lc = lseg * 16;

    uint4 sah0, sah1, sal0, sal1, sbh0, sbh1, sbl0, sbl1;
    {
        const u16* pa0 = Ah  + (size_t)(row0 + lrow) * K + lc;
        const u16* pa1 = Al  + (size_t)(row0 + lrow) * K + lc;
        const u16* pb0 = Bth + (size_t)(col0 + lrow) * K + lc;
        const u16* pb1 = Btl + (size_t)(col0 + lrow) * K + lc;
        sah0 = ((const uint4*)pa0)[0]; sah1 = ((const uint4*)pa0)[1];
        sal0 = ((const uint4*)pa1)[0]; sal1 = ((const uint4*)pa1)[1];
        sbh0 = ((const uint4*)pb0)[0]; sbh1 = ((const uint4*)pb0)[1];
        sbl0 = ((const uint4*)pb1)[0]; sbl1 = ((const uint4*)pb1)[1];
    }

    const f32x4 z4 = {0.f, 0.f, 0.f, 0.f};
    f32x4 acc[2][2] = {{z4, z4}, {z4, z4}};
    const int NKT2 = K / 64;

    for (int kt = 0; kt < NKT2; ++kt) {
        *(uint4*)&As_h[lrow * TKP + lc]     = sah0;
        *(uint4*)&As_h[lrow * TKP + lc + 8] = sah1;
        *(uint4*)&As_l[lrow * TKP + lc]     = sal0;
        *(uint4*)&As_l[lrow * TKP + lc + 8] = sal1;
        *(uint4*)&Bs_h[lrow * TKP + lc]     = sbh0;
        *(uint4*)&Bs_h[lrow * TKP + lc + 8] = sbh1;
        *(uint4*)&Bs_l[lrow * TKP + lc]     = sbl0;
        *(uint4*)&Bs_l[lrow * TKP + lc + 8] = sbl1;
        if (kt + 1 < NKT2) {
            const int kb = (kt + 1) * 64 + lc;
            const u16* pa0 = Ah  + (size_t)(row0 + lrow) * K + kb;
            const u16* pa1 = Al  + (size_t)(row0 + lrow) * K + kb;
            const u16* pb0 = Bth + (size_t)(col0 + lrow) * K + kb;
            const u16* pb1 = Btl + (size_t)(col0 + lrow) * K + kb;
            sah0 = ((const uint4*)pa0)[0]; sah1 = ((const uint4*)pa0)[1];
            sal0 = ((const uint4*)pa1)[0]; sal1 = ((const uint4*)pa1)[1];
            sbh0 = ((const uint4*)pb0)[0]; sbh1 = ((const uint4*)pb0)[1];
            sbl0 = ((const uint4*)pb1)[0]; sbl1 = ((const uint4*)pb1)[1];
        }
        __syncthreads();

        __builtin_amdgcn_s_setprio(1);
        #pragma unroll
        for (int kc = 0; kc < 2; ++kc) {
            const int dc = kc * 32 + h4 * 8;
            half8 afh[2], afl[2], bfh[2], bfl[2];
            #pragma unroll
            for (int ab = 0; ab < 2; ++ab) {
                const int r = rh * 32 + ab * 16 + l15;
                afh[ab] = *(const half8*)&As_h[r * TKP + dc];
                afl[ab] = *(const half8*)&As_l[r * TKP + dc];
            }
            #pragma unroll
            for (int bb = 0; bb < 2; ++bb) {
                const int r = ch * 32 + bb * 16 + l15;
                bfh[bb] = *(const half8*)&Bs_h[r * TKP + dc];
                bfl[bb] = *(const half8*)&Bs_l[r * TKP + dc];
            }
            #pragma unroll
            for (int ab = 0; ab < 2; ++ab)
                #pragma unroll
                for (int bb = 0; bb < 2; ++bb) {
                    acc[ab][bb] = MFMA16(afh[ab], bfh[bb], acc[ab][bb]);
                    acc[ab][bb] = MFMA16(afh[ab], bfl[bb], acc[ab][bb]);
                    acc[ab][bb] = MFMA16(afl[ab], bfh[bb], acc[ab][bb]);
                }
        }
        __builtin_amdgcn_s_setprio(0);
        __syncthreads();
    }

    #pragma unroll
    for (int ab = 0; ab < 2; ++ab)
        #pragma unroll
        for (int bb = 0; bb < 2; ++bb) {
            const int c  = col0 + ch * 32 + bb * 16 + l15;
            const int r0 = row0 + rh * 32 + ab * 16 + h4 * 4;
            #pragma unroll
            for (int i = 0; i < 4; ++i) {
                const int r = r0 + i;
                float t = acc[ab][bb][i] + bias[c];
                if (MEPI == MEPI_WO) {
                    t += resid[(size_t)r * M + c];
                    u16 hh, ll;
                    split16(t, hh, ll);
                    outh[(size_t)r * M + c] = hh;
                    outl[(size_t)r * M + c] = ll;
                } else {
                    t = t > 0.f ? t : expm1f(t);
                    outf[(size_t)r * M + c] = t;
                }
            }
        }
    #undef TKP
}

// ---------------- MFMA flash attention (round-13: LDS dbuf, 1 barrier) ----
// Two K/V LDS buffer sets: stage tile t+1 into buf^1 at top of iter t (its
// last readers drained at the t-1 barrier), then single end-of-tile barrier.
// Softmax/P/frow stay wave-local (no extra barrier). Bit-identical math.
#define QB 64
#define KB 64
#define NSPLIT 4
#define NKT (NN / KB)
#define KP 72

__global__ __launch_bounds__(256, 2) void attn_kernel(
    const u16* __restrict__ qhi, const u16* __restrict__ qlo,
    const u16* __restrict__ khi, const u16* __restrict__ klo,
    const u16* __restrict__ vT,
    float* __restrict__ op0, float* __restrict__ op1,
    float* __restrict__ op2, float* __restrict__ op3,
    float* __restrict__ mpart, float* __restrict__ lpart)
{
    __shared__ u16 lds[32384];            // 64768 B -> 2 blocks/CU
    u16* Kh0 = lds;                       // buf0 [64][72] x3
    u16* Kl0 = lds + 4608;
    u16* Vt0 = lds + 9216;
    u16* Kh1 = lds + 13824;               // buf1
    u16* Kl1 = lds + 18432;
    u16* Vt1 = lds + 23040;
    u16* Pb  = lds + 27648;               // [64][72] P fp16 (wave-local rows)
    u16* Qh  = lds;                       // overlay buf0 (init phase only)
    u16* Ql  = lds + 4608;
    float* frow = (float*)(lds + 32256);  // [64]

    const int tid = threadIdx.x;
    const int h   = blockIdx.y;
    const int q0  = blockIdx.x * QB;
    const int sp  = blockIdx.z;
    const int kt0 = sp * (NKT / NSPLIT);  // 16 tiles/block (even)
    const int kt1 = kt0 + NKT / NSPLIT;

    const int w   = tid >> 6;
    const int l15 = tid & 15, h4 = (tid & 63) >> 4;
    const int lrow = tid & 63, lseg = tid >> 6;
    const int gq = h * DH + lseg * 16;

    {   // stage Q (once, into overlay region)
        const u16* s0 = qhi + (size_t)(q0 + lrow) * DIM + gq;
        const u16* s1 = qlo + (size_t)(q0 + lrow) * DIM + gq;
        uint4 a = ((const uint4*)s0)[0], b = ((const uint4*)s0)[1];
        uint4 c = ((const uint4*)s1)[0], d = ((const uint4*)s1)[1];
        *(uint4*)&Qh[lrow * KP + lseg * 16]     = a;
        *(uint4*)&Qh[lrow * KP + lseg * 16 + 8] = b;
        *(uint4*)&Ql[lrow * KP + lseg * 16]     = c;
        *(uint4*)&Ql[lrow * KP + lseg * 16 + 8] = d;
    }

    uint4 rk0, rk1, rl0, rl1, rv0, rv1;   // single staging register set
    auto load_tile = [&](int kt_ld) {
        const int key0 = kt_ld * KB;
        const u16* s0 = khi + (size_t)(key0 + lrow) * DIM + gq;
        const u16* s1 = klo + (size_t)(key0 + lrow) * DIM + gq;
        const u16* s2 = vT + (size_t)(h * DH + lrow) * NN + key0 + lseg * 16;
        rk0 = ((const uint4*)s0)[0]; rk1 = ((const uint4*)s0)[1];
        rl0 = ((const uint4*)s1)[0]; rl1 = ((const uint4*)s1)[1];
        rv0 = ((const uint4*)s2)[0]; rv1 = ((const uint4*)s2)[1];
    };
    load_tile(kt0);
    __syncthreads();                              // Q staged

    half8 qf[2][2];                               // [kc][hi/lo]
    #pragma unroll
    for (int kc = 0; kc < 2; ++kc) {
        const int r = w * 16 + l15;
        const int dc = kc * 32 + h4 * 8;
        qf[kc][0] = *(const half8*)&Qh[r * KP + dc];
        qf[kc][1] = *(const half8*)&Ql[r * KP + dc];
    }
    __syncthreads();                              // hoist done; overlay safe

    auto stage_to = [&](u16* Kh, u16* Kl, u16* Vt) {
        *(uint4*)&Kh[lrow * KP + lseg * 16]     = rk0;
        *(uint4*)&Kh[lrow * KP + lseg * 16 + 8] = rk1;
        *(uint4*)&Kl[lrow * KP + lseg * 16]     = rl0;
        *(uint4*)&Kl[lrow * KP + lseg * 16 + 8] = rl1;
        *(uint4*)&Vt[lrow * KP + lseg * 16]     = rv0;
        *(uint4*)&Vt[lrow * KP + lseg * 16 + 8] = rv1;
    };

    stage_to(Kh0, Kl0, Vt0);                      // tile kt0 -> buf0
    load_tile(kt0 + 1);                           // tile kt0+1 -> regs
    __syncthreads();                              // buf0 ready

    const f32x4 z4 = {0.f, 0.f, 0.f, 0.f};
    f32x4 oacc[4] = {z4, z4, z4, z4};
    float m_run[4], l_run[4];
    #pragma unroll
    for (int i = 0; i < 4; ++i) { m_run[i] = -3.0e38f; l_run[i] = 0.f; }

    // body for tile t reading (Kc,Lc,Vc); stages regs(t+1) into (Kn,Ln,Vn)
    auto tile_body = [&](int t, u16* Kc, u16* Lc, u16* Vc,
                         u16* Kn, u16* Ln, u16* Vn) {
        if (t + 1 < kt1) stage_to(Kn, Ln, Vn);    // writes to the idle buffer
        if (t + 2 < kt1) load_tile(t + 2);        // early-issue global loads

        // ---- S = Q K^T (3-pass fp16 hi/lo): 16 q-rows x 64 k per wave ----
        f32x4 sc[4] = {z4, z4, z4, z4};
        __builtin_amdgcn_s_setprio(1);
        #pragma unroll
        for (int kc = 0; kc < 2; ++kc) {
            const int dc = kc * 32 + h4 * 8;
            half8 kfh[4], kfl[4];
            #pragma unroll
            for (int kcb = 0; kcb < 4; ++kcb) {
                const int r = kcb * 16 + l15;
                kfh[kcb] = *(const half8*)&Kc[r * KP + dc];
                kfl[kcb] = *(const half8*)&Lc[r * KP + dc];
            }
            #pragma unroll
            for (int kcb = 0; kcb < 4; ++kcb) {
                sc[kcb] = MFMA16(qf[kc][0], kfh[kcb], sc[kcb]);
                sc[kcb] = MFMA16(qf[kc][0], kfl[kcb], sc[kcb]);
                sc[kcb] = MFMA16(qf[kc][1], kfh[kcb], sc[kcb]);
            }
        }
        __builtin_amdgcn_s_setprio(0);
        // ---- wave-local softmax ----
        float p[4][4], fr[4];
        #pragma unroll
        for (int i = 0; i < 4; ++i) {
            float pm = fmaxf(fmaxf(sc[0][i], sc[1][i]), fmaxf(sc[2][i], sc[3][i]));
            #pragma unroll
            for (int off = 1; off < 16; off <<= 1)
                pm = fmaxf(pm, __shfl_xor(pm, off));
            const float mnew = fmaxf(m_run[i], pm);
            fr[i] = __expf(m_run[i] - mnew);
            m_run[i] = mnew;
            p[0][i] = __expf(sc[0][i] - mnew);
            p[1][i] = __expf(sc[1][i] - mnew);
            p[2][i] = __expf(sc[2][i] - mnew);
            p[3][i] = __expf(sc[3][i] - mnew);
            float ls = (p[0][i] + p[1][i]) + (p[2][i] + p[3][i]);
            #pragma unroll
            for (int off = 1; off < 16; off <<= 1) ls += __shfl_xor(ls, off);
            l_run[i] = l_run[i] * fr[i] + ls;
        }
        #pragma unroll
        for (int kcb = 0; kcb < 4; ++kcb) {
            const int kk = kcb * 16 + l15;
            #pragma unroll
            for (int i = 0; i < 4; ++i)
                Pb[(w * 16 + h4 * 4 + i) * KP + kk] = f2h(p[kcb][i]);
        }
        if (l15 == 0) {
            #pragma unroll
            for (int i = 0; i < 4; ++i)
                frow[w * 16 + h4 * 4 + i] = fr[i];
        }
        // wave-local: compiler waitcnt orders the reads below
        const float frq = frow[w * 16 + l15];
        #pragma unroll
        for (int db = 0; db < 4; ++db) oacc[db] *= frq;
        // ---- PV: wave-local ----
        __builtin_amdgcn_s_setprio(1);
        #pragma unroll
        for (int kc = 0; kc < 2; ++kc) {
            const half8 pf = *(const half8*)&Pb[(w * 16 + l15) * KP + kc * 32 + h4 * 8];
            #pragma unroll
            for (int db = 0; db < 4; ++db) {
                const half8 vf = *(const half8*)&Vc[(db * 16 + l15) * KP + kc * 32 + h4 * 8];
                oacc[db] = MFMA16(vf, pf, oacc[db]);
            }
        }
        __builtin_amdgcn_s_setprio(0);
        __syncthreads();   // single per-tile barrier: buf^1 staged + cur reads done
    };

    for (int t = kt0; t < kt1; t += 2) {
        tile_body(t,     Kh0, Kl0, Vt0, Kh1, Kl1, Vt1);
        tile_body(t + 1, Kh1, Kl1, Vt1, Kh0, Kl0, Vt0);
    }

    float* ob = (sp == 0) ? op0 : ((sp == 1) ? op1 : ((sp == 2) ? op2 : op3));
    #pragma unroll
    for (int db = 0; db < 4; ++db)
        *(f32x4*)&ob[(size_t)(q0 + w * 16 + l15) * DIM + h * DH + db * 16 + h4 * 4] = oacc[db];
    if (l15 == 0) {
        #pragma unroll
        for (int i = 0; i < 4; ++i) {
            const int r = w * 16 + h4 * 4 + i;
            mpart[((size_t)sp * NN + q0 + r) * NH + h] = m_run[i];
            lpart[((size_t)sp * NN + q0 + r) * NH + h] = l_run[i];
        }
    }
}

// merge the 4 partials -> fp16 hi/lo planes (feeds the MFMA Wo GEMM)
__global__ __launch_bounds__(256) void attn_combine(
    const float* __restrict__ o0, const float* __restrict__ o1,
    const float* __restrict__ o2, const float* __restrict__ o3,
    const float* __restrict__ mp, const float* __restrict__ lp,
    u16* __restrict__ ohi, u16* __restrict__ olo)
{
    const int gid = blockIdx.x * 256 + threadIdx.x;
    const int row = gid >> 6;
    const int c4  = (gid & 63) * 4;
    const int h   = c4 >> 6;
    float m[4], wgt[4];
    #pragma unroll
    for (int z = 0; z < 4; ++z) m[z] = mp[((size_t)z * NN + row) * NH + h];
    const float M = fmaxf(fmaxf(m[0], m[1]), fmaxf(m[2], m[3]));
    float den = 0.f;
    #pragma unroll
    for (int z = 0; z < 4; ++z) {
        wgt[z] = __expf(m[z] - M);
        den += lp[((size_t)z * NN + row) * NH + h] * wgt[z];
    }
    const float inv = 1.f / den;
    const float4 a = *(const float4*)&o0[(size_t)row * DIM + c4];
    const float4 b = *(const float4*)&o1[(size_t)row * DIM + c4];
    const float4 c = *(const float4*)&o2[(size_t)row * DIM + c4];
    const float4 d = *(const float4*)&o3[(size_t)row * DIM + c4];
    float r[4];
    r[0] = (a.x * wgt[0] + b.x * wgt[1] + c.x * wgt[2] + d.x * wgt[3]) * inv;
    r[1] = (a.y * wgt[0] + b.y * wgt[1] + c.y * wgt[2] + d.y * wgt[3]) * inv;
    r[2] = (a.z * wgt[0] + b.z * wgt[1] + c.z * wgt[2] + d.z * wgt[3]) * inv;
    r[3] = (a.w * wgt[0] + b.w * wgt[1] + c.w * wgt[2] + d.w * wgt[3]) * inv;
    u16 hh[4], ll[4];
    #pragma unroll
    for (int j = 0; j < 4; ++j) split16(r[j], hh[j], ll[j]);
    *(uint2*)&ohi[(size_t)row * DIM + c4] =
        make_uint2((u32)hh[0] | ((u32)hh[1] << 16), (u32)hh[2] | ((u32)hh[3] << 16));
    *(uint2*)&olo[(size_t)row * DIM + c4] =
        make_uint2((u32)ll[0] | ((u32)ll[1] << 16), (u32)ll[2] | ((u32)ll[3] << 16));
}

// ---------------- per-node group adapter ----------------
__global__ __launch_bounds__(64) void adapter_kernel(
    const float* __restrict__ feats, const int* __restrict__ grp,
    const float* __restrict__ AW1, const float* __restrict__ Ab1,
    const float* __restrict__ AW2, const float* __restrict__ Ab2,
    float* __restrict__ out)
{
    const int n = blockIdx.x;
    const int lane = threadIdx.x;
    __shared__ float f[F1D];
    f[lane]      = feats[(size_t)n * F1D + lane];
    f[lane + 64] = feats[(size_t)n * F1D + 64 + lane];
    __syncthreads();
    const int g = grp[n];
    const float* W1 = AW1 + (size_t)g * F1D * AD;
    const int a = lane & 31;
    const int half = lane >> 5;
    float hsum = 0.f;
    for (int d = 0; d < 64; ++d)
        hsum = fmaf(f[half * 64 + d], W1[(half * 64 + d) * AD + a], hsum);
    hsum += __shfl_xor(hsum, 32);
    hsum = fmaxf(hsum + Ab1[g * AD + a], 0.f);
    float p = hsum * AW2[g * AD + a];
    #pragma unroll
    for (int mm = 1; mm < 32; mm <<= 1) p += __shfl_xor(p, mm);
    if (lane == 0) out[n] = p + Ab2[g];
}

// ---------------- host-side orchestration ----------------
extern "C" void kernel_launch(void* const* d_in, const int* in_sizes, int n_in,
                              void* d_out, int out_size, void* d_ws, size_t ws_size,
                              hipStream_t stream)
{
    const float* x_in   = (const float*)d_in[0];
    const float* eattr  = (const float*)d_in[1];
    const float* Wself  = (const float*)d_in[2];
    const float* Wnbr   = (const float*)d_in[3];
    const float* convb  = (const float*)d_in[4];
    const float* gamma  = (const float*)d_in[5];
    const float* beta   = (const float*)d_in[6];
    const float* bnmean = (const float*)d_in[7];
    const float* bnvar  = (const float*)d_in[8];
    const float* Wqkv   = (const float*)d_in[9];
    const float* bqkv   = (const float*)d_in[10];
    const float* Wo     = (const float*)d_in[11];
    const float* bo     = (const float*)d_in[12];
    const float* fc1W   = (const float*)d_in[13];
    const float* fc1b   = (const float*)d_in[14];
    const float* AW1    = (const float*)d_in[15];
    const float* Ab1    = (const float*)d_in[16];
    const float* AW2    = (const float*)d_in[17];
    const float* Ab2    = (const float*)d_in[18];
    const int*   eidx   = (const int*)d_in[19];
    const int*   grp    = (const int*)d_in[20];
    const int* srcArr = eidx;
    const int* dstArr = eidx + NE;

    float* fws = (float*)d_ws;
    const size_t NM = (size_t)NN * DIM;
    float* bufA  = fws;                  // x L0 / x L2 (residual)
    float* bufB  = fws + NM;             // attn op0
    float* bufC  = fws + 2 * NM;         // x L1 / attn op1
    float* feats = fws + 3 * NM;         // NN x F1D
    float* mpart = fws + 3 * NM + NM / 2;         // [4][NN][NH]
    float* lpart = mpart + 4 * NN * NH;
    u16* up = (u16*)(lpart + 4 * NN * NH);
    u16* xpAh = up;             u16* xpAl = xpAh + NM;   // x planes ping
    u16* xpBh = xpAl + NM;      u16* xpBl = xpBh + NM;   // x planes pong
    u16* aggh = xpBl + NM;      u16* aggl = aggh + NM;   // agg planes
    u16* qh = aggl + NM;        u16* ql = qh + NM;       // Q planes / combine out
    u16* kh = ql + NM;          u16* kl = kh + NM;       // K planes / Wo out
    u16* vt = kl + NM;                                   // V^T fp16 [256][NN]
    u16* wcath = vt + NM;                                // [3][256][512]
    u16* wcatl = wcath + 3 * 131072;
    u16* wt4h  = wcatl + 3 * 131072;                     // [4][256][256] qkv+wo
    u16* wt4l  = wt4h + 4 * 65536;
    u16* fc1h  = wt4l + 4 * 65536;                       // [128][256]
    u16* fc1l  = fc1h + 32768;
    int*   esrc = (int*)(fc1l + 32768);                  // NE
    float* ewt  = (float*)(esrc + NE);                   // NE
    int* off    = (int*)(ewt + NE);                      // NN+1
    int* cur    = off + NN + 1;                          // NN
    float* outp = (float*)d_out;

    float* op2 = (float*)xpAh;           // attn partial overlays
    float* op3 = (float*)xpBh;

    // fused prep: all converts + zero(cur)
    prep_kernel<<<1700, 256, 0, stream>>>(
        x_in, Wself, Wnbr, Wqkv, Wo, fc1W,
        xpAh, xpAl, wcath, wcatl, wt4h, wt4l, fc1h, fc1l, cur);

    // CSR build (csr_scan zeroes cur for csr_fill)
    csr_count<<<NE / 256, 256, 0, stream>>>(dstArr, cur);
    csr_scan<<<1, 1024, 0, stream>>>(cur, off);
    csr_fill<<<NE / 256, 256, 0, stream>>>(dstArr, srcArr, eattr, off, cur, esrc, ewt);

    const dim3 gc(DIM / 64, NN / 32);    // 32-row conv tiles: 512 blocks
    const int rgrid = NN * DIM / 4 / 256;

    // conv layer 0: x_in -> bufA (fp32) + xpB planes
    agg_kernel<false><<<NN / 4, 256, 0, stream>>>(x_in, esrc, ewt, off, aggh, aggl);
    conv_mfma<EPI_BNELU><<<gc, 256, 0, stream>>>(
        xpAh, xpAl, aggh, aggl, wcath, wcatl, convb,
        gamma, beta, bnmean, bnvar, bufA, xpBh, xpBl);
    // conv layer 1: bufA -> bufC + xpA planes
    agg_kernel<false><<<NN / 4, 256, 0, stream>>>(bufA, esrc, ewt, off, aggh, aggl);
    conv_mfma<EPI_BNELU><<<gc, 256, 0, stream>>>(
        xpBh, xpBl, aggh, aggl, wcath + 131072, wcatl + 131072, convb + DIM,
        gamma + DIM, beta + DIM, bnmean + DIM, bnvar + DIM, bufC, xpAh, xpAl);
    // conv layer 2 (edge-weighted, bias only): bufC -> bufA + xpB planes
    agg_kernel<true><<<NN / 4, 256, 0, stream>>>(bufC, esrc, ewt, off, aggh, aggl);
    conv_mfma<EPI_BIAS><<<gc, 256, 0, stream>>>(
        xpAh, xpAl, aggh, aggl, wcath + 262144, wcatl + 262144, convb + 2 * DIM,
        nullptr, nullptr, nullptr, nullptr, bufA, xpBh, xpBl);

    // QKV (fp16 3-pass MFMA) -> Q/K planes (Q/8) + V^T
    qkv_mfma<<<dim3(12, NN / 64), 256, 0, stream>>>(
        xpBh, xpBl, wt4h, wt4l, bqkv, qh, ql, kh, kl, vt);

    // flash attention (4-way key split) -> partials, combine -> o planes
    attn_kernel<<<dim3(NN / QB, NH, NSPLIT), 256, 0, stream>>>(
        qh, ql, kh, kl, vt, bufB, bufC, op2, op3, mpart, lpart);
    attn_combine<<<rgrid, 256, 0, stream>>>(
        bufB, bufC, op2, op3, mpart, lpart, qh, ql);

    // Wo + residual (fp16 3-pass MFMA): kh/kl = planes(bufA + o@Wo + bo)
    mfma_gemm<MEPI_WO><<<dim3(DIM / 64, NN / 64), 256, 0, stream>>>(
        qh, ql, wt4h + 3 * 65536, wt4l + 3 * 65536, bo, bufA,
        nullptr, kh, kl, DIM, DIM);

    // fc1 + ELU (fp16 3-pass MFMA): feats = elu(x' @ fc1W + fc1b)
    mfma_gemm<MEPI_FC1><<<dim3(F1D / 64, NN / 64), 256, 0, stream>>>(
        kh, kl, fc1h, fc1l, fc1b, nullptr, feats, nullptr, nullptr, DIM, F1D);

    // adapter routing -> out
    adapter_kernel<<<NN, 64, 0, stream>>>(feats, grp, AW1, Ab1, AW2, Ab2, outp);
}

// Round 14
// 237.115 us; speedup vs baseline: 1.4220x; 1.0251x over previous
//
#include <hip/hip_runtime.h>
#include <math.h>

#define NN   4096
#define DIM  256
#define NE   131072
#define NH   4
#define DH   64
#define F1D  128
#define NG   16
#define AD   32

typedef unsigned short u16;
typedef unsigned int   u32;
typedef _Float16 f16;
typedef __attribute__((ext_vector_type(8))) _Float16 half8;
typedef __attribute__((ext_vector_type(4))) float f32x4;

enum { EPI_BIAS = 0, EPI_BNELU = 1 };
enum { MEPI_WO = 0, MEPI_FC1 = 1 };

#define MFMA16(a, b, c) __builtin_amdgcn_mfma_f32_16x16x32_f16(a, b, c, 0, 0, 0)

__device__ inline u16 f2h(float x) { union { f16 f; u16 u; } c; c.f = (f16)x; return c.u; }
// fp16 hi/lo split: x = hi + lo + eps, |eps| <= 2^-24 |x|  (fp32-grade)
__device__ inline void split16(float x, u16& h, u16& l) {
    union { f16 f; u16 u; } ch, cl;
    ch.f = (f16)x;
    cl.f = (f16)(x - (float)ch.f);
    h = ch.u; l = cl.u;
}

// ---------------- CSR build ----------------
__global__ void csr_count(const int* __restrict__ dst, int* __restrict__ cnt) {
    int e = blockIdx.x * 256 + threadIdx.x;
    atomicAdd(&cnt[dst[e]], 1);
}

__global__ __launch_bounds__(1024) void csr_scan(
    int* __restrict__ cnt, int* __restrict__ off)
{
    __shared__ int wsum[16];
    const int t = threadIdx.x;
    const int lane = t & 63;
    int4 v = *(const int4*)&cnt[t * 4];
    const int s = v.x + v.y + v.z + v.w;
    int acc = s;
    #pragma unroll
    for (int o = 1; o < 64; o <<= 1) {
        int u = __shfl_up(acc, o);
        if (lane >= o) acc += u;
    }
    if (lane == 63) wsum[t >> 6] = acc;
    __syncthreads();
    if (t < 16) {
        int w0 = wsum[t];
        int a2 = w0;
        #pragma unroll
        for (int o = 1; o < 16; o <<= 1) {
            int u = __shfl_up(a2, o);
            if (t >= o) a2 += u;
        }
        wsum[t] = a2 - w0;
    }
    __syncthreads();
    const int base = wsum[t >> 6] + (acc - s);
    off[t * 4 + 0] = base;
    off[t * 4 + 1] = base + v.x;
    off[t * 4 + 2] = base + v.x + v.y;
    off[t * 4 + 3] = base + v.x + v.y + v.z;
    *(int4*)&cnt[t * 4] = make_int4(0, 0, 0, 0);
    if (t == 1023) off[NN] = base + s;
}

__global__ void csr_fill(const int* __restrict__ dst, const int* __restrict__ src,
                         const float* __restrict__ eattr, const int* __restrict__ off,
                         int* __restrict__ cur, int* __restrict__ esrc,
                         float* __restrict__ ewt) {
    int e = blockIdx.x * 256 + threadIdx.x;
    int d = dst[e];
    int pos = off[d] + atomicAdd(&cur[d], 1);
    esrc[pos] = src[e];
    ewt[pos]  = eattr[e];
}

// ---------------- fused one-time prep: all weight/x converts + zero cur ----
__global__ __launch_bounds__(256) void prep_kernel(
    const float* __restrict__ x,
    const float* __restrict__ Ws, const float* __restrict__ Wn,
    const float* __restrict__ Wqkv, const float* __restrict__ Wo,
    const float* __restrict__ fc1W,
    u16* __restrict__ xh, u16* __restrict__ xl,
    u16* __restrict__ wch, u16* __restrict__ wcl,
    u16* __restrict__ w4h, u16* __restrict__ w4l,
    u16* __restrict__ f1h, u16* __restrict__ f1l,
    int* __restrict__ cur)
{
    const int b = blockIdx.x;
    const int t = threadIdx.x;
    if (b < 1024) {
        const int gid = b * 256 + t;
        const float4 v = *(const float4*)&x[(size_t)gid * 4];
        u16 h[4], l[4];
        split16(v.x, h[0], l[0]); split16(v.y, h[1], l[1]);
        split16(v.z, h[2], l[2]); split16(v.w, h[3], l[3]);
        *(uint2*)&xh[(size_t)gid * 4] =
            make_uint2((u32)h[0] | ((u32)h[1] << 16), (u32)h[2] | ((u32)h[3] << 16));
        *(uint2*)&xl[(size_t)gid * 4] =
            make_uint2((u32)l[0] | ((u32)l[1] << 16), (u32)l[2] | ((u32)l[3] << 16));
    } else if (b < 1408) {
        const int gid = (b - 1024) * 256 + t;
        const int L = gid / 32768;
        const int rem = gid % 32768;
        const int m = rem / 128;
        const int k4 = (rem % 128) * 4;
        const float* S = Ws + (size_t)L * 65536;
        const float* Nb = Wn + (size_t)L * 65536;
        u16 h[4], l[4];
        #pragma unroll
        for (int j = 0; j < 4; ++j) {
            const int k = k4 + j;
            const float v = (k < 256) ? S[(size_t)k * 256 + m]
                                      : Nb[(size_t)(k - 256) * 256 + m];
            split16(v, h[j], l[j]);
        }
        const size_t o = (size_t)L * 131072 + (size_t)m * 512 + k4;
        *(uint2*)&wch[o] = make_uint2((u32)h[0] | ((u32)h[1] << 16), (u32)h[2] | ((u32)h[3] << 16));
        *(uint2*)&wcl[o] = make_uint2((u32)l[0] | ((u32)l[1] << 16), (u32)l[2] | ((u32)l[3] << 16));
    } else if (b < 1664) {
        const int gid = (b - 1408) * 256 + t;
        const int mat = gid / 16384;
        const int rem = gid % 16384;
        const int m = rem / 64;
        const int k4 = (rem % 64) * 4;
        const float* W = (mat < 3) ? Wqkv + (size_t)mat * 65536 : Wo;
        u16 h[4], l[4];
        #pragma unroll
        for (int j = 0; j < 4; ++j)
            split16(W[(size_t)(k4 + j) * 256 + m], h[j], l[j]);
        const size_t o = (size_t)mat * 65536 + (size_t)m * 256 + k4;
        *(uint2*)&w4h[o] = make_uint2((u32)h[0] | ((u32)h[1] << 16), (u32)h[2] | ((u32)h[3] << 16));
        *(uint2*)&w4l[o] = make_uint2((u32)l[0] | ((u32)l[1] << 16), (u32)l[2] | ((u32)l[3] << 16));
    } else if (b < 1696) {
        const int gid = (b - 1664) * 256 + t;
        const int m = gid / 64;
        const int k4 = (gid % 64) * 4;
        u16 h[4], l[4];
        #pragma unroll
        for (int j = 0; j < 4; ++j)
            split16(fc1W[(size_t)(k4 + j) * F1D + m], h[j], l[j]);
        const size_t o = (size_t)m * 256 + k4;
        *(uint2*)&f1h[o] = make_uint2((u32)h[0] | ((u32)h[1] << 16), (u32)h[2] | ((u32)h[3] << 16));
        *(uint2*)&f1l[o] = make_uint2((u32)l[0] | ((u32)l[1] << 16), (u32)l[2] | ((u32)l[3] << 16));
    } else {
        const int gid = (b - 1696) * 256 + t;
        if (gid < NN / 4) *(int4*)&cur[gid * 4] = make_int4(0, 0, 0, 0);
    }
}

// ---------------- neighbor aggregation: 1 wave per node, fp16-plane out ---
template<bool LAST>
__global__ __launch_bounds__(256) void agg_kernel(
    const float* __restrict__ x, const int* __restrict__ esrc,
    const float* __restrict__ ewt, const int* __restrict__ off,
    u16* __restrict__ aggh, u16* __restrict__ aggl)
{
    const int node = blockIdx.x * 4 + (threadIdx.x >> 6);
    const int lane = threadIdx.x & 63;
    const int d4 = lane * 4;
    int j = off[node];
    const int j1 = off[node + 1];
    float4 acc = make_float4(0.f, 0.f, 0.f, 0.f);
    for (; j + 4 <= j1; j += 4) {
        const int s0 = esrc[j], s1 = esrc[j + 1], s2 = esrc[j + 2], s3 = esrc[j + 3];
        const float4 x0 = *(const float4*)&x[(size_t)s0 * DIM + d4];
        const float4 x1 = *(const float4*)&x[(size_t)s1 * DIM + d4];
        const float4 x2 = *(const float4*)&x[(size_t)s2 * DIM + d4];
        const float4 x3 = *(const float4*)&x[(size_t)s3 * DIM + d4];
        const float w0 = LAST ? ewt[j]     : 1.f;
        const float w1 = LAST ? ewt[j + 1] : 1.f;
        const float w2 = LAST ? ewt[j + 2] : 1.f;
        const float w3 = LAST ? ewt[j + 3] : 1.f;
        acc.x = fmaf(x0.x, w0, acc.x); acc.y = fmaf(x0.y, w0, acc.y);
        acc.z = fmaf(x0.z, w0, acc.z); acc.w = fmaf(x0.w, w0, acc.w);
        acc.x = fmaf(x1.x, w1, acc.x); acc.y = fmaf(x1.y, w1, acc.y);
        acc.z = fmaf(x1.z, w1, acc.z); acc.w = fmaf(x1.w, w1, acc.w);
        acc.x = fmaf(x2.x, w2, acc.x); acc.y = fmaf(x2.y, w2, acc.y);
        acc.z = fmaf(x2.z, w2, acc.z); acc.w = fmaf(x2.w, w2, acc.w);
        acc.x = fmaf(x3.x, w3, acc.x); acc.y = fmaf(x3.y, w3, acc.y);
        acc.z = fmaf(x3.z, w3, acc.z); acc.w = fmaf(x3.w, w3, acc.w);
    }
    for (; j < j1; ++j) {
        const int s = esrc[j];
        const float w = LAST ? ewt[j] : 1.f;
        const float4 xv = *(const float4*)&x[(size_t)s * DIM + d4];
        acc.x = fmaf(xv.x, w, acc.x); acc.y = fmaf(xv.y, w, acc.y);
        acc.z = fmaf(xv.z, w, acc.z); acc.w = fmaf(xv.w, w, acc.w);
    }
    u16 h[4], l[4];
    split16(acc.x, h[0], l[0]); split16(acc.y, h[1], l[1]);
    split16(acc.z, h[2], l[2]); split16(acc.w, h[3], l[3]);
    *(uint2*)&aggh[(size_t)node * DIM + d4] =
        make_uint2((u32)h[0] | ((u32)h[1] << 16), (u32)h[2] | ((u32)h[3] << 16));
    *(uint2*)&aggl[(size_t)node * DIM + d4] =
        make_uint2((u32)l[0] | ((u32)l[1] << 16), (u32)l[2] | ((u32)l[3] << 16));
}

// ---------------- conv MFMA GEMM: 32x64 tile (2 blocks/CU) ----------------
template<int EPI>
__global__ __launch_bounds__(256) void conv_mfma(
    const u16* __restrict__ xh, const u16* __restrict__ xl,
    const u16* __restrict__ gh, const u16* __restrict__ gl,
    const u16* __restrict__ bth, const u16* __restrict__ btl,
    const float* __restrict__ bias,
    const float* __restrict__ gamma, const float* __restrict__ beta,
    const float* __restrict__ bnmean, const float* __restrict__ bnvar,
    float* __restrict__ outf, u16* __restrict__ oh, u16* __restrict__ ol)
{
    __shared__ u16 lds[13824];           // 27648 B
    u16* As_h = lds;                     // [32][72]
    u16* As_l = lds + 2304;
    u16* Bs_h = lds + 4608;              // [64][72]
    u16* Bs_l = lds + 9216;
    #define TKP 72

    const int tid  = threadIdx.x;
    const int row0 = blockIdx.y * 32;
    const int col0 = blockIdx.x * 64;

    const int w   = tid >> 6;
    const int l15 = tid & 15, h4 = (tid & 63) >> 4;
    const int rh  = w & 1, ch = w >> 1;
    const int arow = tid >> 3, acs = (tid & 7) * 8;
    const int brow = tid & 63, bseg = tid >> 6;
    const int bc = bseg * 16;

    uint4 sah, sal, sbh0, sbh1, sbl0, sbl1;
    {
        sah = *((const uint4*)&xh[(size_t)(row0 + arow) * DIM + acs]);
        sal = *((const uint4*)&xl[(size_t)(row0 + arow) * DIM + acs]);
        const u16* pbh = bth + (size_t)(col0 + brow) * 512 + bc;
        const u16* pbl = btl + (size_t)(col0 + brow) * 512 + bc;
        sbh0 = ((const uint4*)pbh)[0]; sbh1 = ((const uint4*)pbh)[1];
        sbl0 = ((const uint4*)pbl)[0]; sbl1 = ((const uint4*)pbl)[1];
    }

    const f32x4 z4 = {0.f, 0.f, 0.f, 0.f};
    f32x4 acc[2] = {z4, z4};

    for (int kt = 0; kt < 8; ++kt) {
        *(uint4*)&As_h[arow * TKP + acs] = sah;
        *(uint4*)&As_l[arow * TKP + acs] = sal;
        *(uint4*)&Bs_h[brow * TKP + bc]     = sbh0;
        *(uint4*)&Bs_h[brow * TKP + bc + 8] = sbh1;
        *(uint4*)&Bs_l[brow * TKP + bc]     = sbl0;
        *(uint4*)&Bs_l[brow * TKP + bc + 8] = sbl1;
        if (kt + 1 < 8) {
            const int kn = kt + 1;
            const u16 *pah, *pal;
            if (kn < 4) {
                pah = xh + (size_t)(row0 + arow) * DIM + kn * 64 + acs;
                pal = xl + (size_t)(row0 + arow) * DIM + kn * 64 + acs;
            } else {
                pah = gh + (size_t)(row0 + arow) * DIM + (kn - 4) * 64 + acs;
                pal = gl + (size_t)(row0 + arow) * DIM + (kn - 4) * 64 + acs;
            }
            sah = *((const uint4*)pah);
            sal = *((const uint4*)pal);
            const u16* pbh = bth + (size_t)(col0 + brow) * 512 + kn * 64 + bc;
            const u16* pbl = btl + (size_t)(col0 + brow) * 512 + kn * 64 + bc;
            sbh0 = ((const uint4*)pbh)[0]; sbh1 = ((const uint4*)pbh)[1];
            sbl0 = ((const uint4*)pbl)[0]; sbl1 = ((const uint4*)pbl)[1];
        }
        __syncthreads();

        __builtin_amdgcn_s_setprio(1);
        #pragma unroll
        for (int kc = 0; kc < 2; ++kc) {
            const int dc = kc * 32 + h4 * 8;
            half8 afh, afl, bfh[2], bfl[2];
            afh = *(const half8*)&As_h[(rh * 16 + l15) * TKP + dc];
            afl = *(const half8*)&As_l[(rh * 16 + l15) * TKP + dc];
            #pragma unroll
            for (int bb = 0; bb < 2; ++bb) {
                const int r = ch * 32 + bb * 16 + l15;
                bfh[bb] = *(const half8*)&Bs_h[r * TKP + dc];
                bfl[bb] = *(const half8*)&Bs_l[r * TKP + dc];
            }
            #pragma unroll
            for (int bb = 0; bb < 2; ++bb) {
                acc[bb] = MFMA16(afh, bfh[bb], acc[bb]);
                acc[bb] = MFMA16(afh, bfl[bb], acc[bb]);
                acc[bb] = MFMA16(afl, bfh[bb], acc[bb]);
            }
        }
        __builtin_amdgcn_s_setprio(0);
        __syncthreads();
    }

    #pragma unroll
    for (int bb = 0; bb < 2; ++bb) {
        const int c  = col0 + ch * 32 + bb * 16 + l15;
        const int r0 = row0 + rh * 16 + h4 * 4;
        #pragma unroll
        for (int i = 0; i < 4; ++i) {
            const int r = r0 + i;
            float t = acc[bb][i] + bias[c];
            if (EPI == EPI_BNELU) {
                t = gamma[c] * (t - bnmean[c]) * rsqrtf(bnvar[c] + 1e-5f) + beta[c];
                t = t > 0.f ? t : expm1f(t);
            }
            outf[(size_t)r * DIM + c] = t;
            u16 hh, ll;
            split16(t, hh, ll);
            oh[(size_t)r * DIM + c] = hh;
            ol[(size_t)r * DIM + c] = ll;
        }
    }
    #undef TKP
}

// ---------------- QKV MFMA GEMM (fp16 3-pass, early prefetch) -------------
__global__ __launch_bounds__(256) void qkv_mfma(
    const u16* __restrict__ xh, const u16* __restrict__ xl,
    const u16* __restrict__ wth, const u16* __restrict__ wtl,
    const float* __restrict__ bias,
    u16* __restrict__ qh_o, u16* __restrict__ ql_o,
    u16* __restrict__ kh_o, u16* __restrict__ kl_o,
    u16* __restrict__ vt_o)
{
    __shared__ u16 lds[4 * 4608];
    u16* As_h = lds;
    u16* As_l = lds + 4608;
    u16* Bs_h = lds + 9216;
    u16* Bs_l = lds + 13824;
    #define TKP 72

    const int tid  = threadIdx.x;
    const int row0 = blockIdx.y * 64;
    const int mat  = blockIdx.x >> 2;
    const int col0 = (blockIdx.x & 3) * 64;
    const float* biasp = bias + mat * DIM;

    const int w   = tid >> 6;
    const int l15 = tid & 15, h4 = (tid & 63) >> 4;
    const int rh  = w & 1, ch = w >> 1;
    const int lrow = tid & 63, lseg = tid >> 6;
    const int lc = lseg * 16;

    const size_t brow = (size_t)(mat * 256 + col0 + lrow) * 256;
    uint4 sah0, sah1, sal0, sal1, sbh0, sbh1, sbl0, sbl1;
    {
        const u16* pah = xh + (size_t)(row0 + lrow) * DIM + lc;
        const u16* pal = xl + (size_t)(row0 + lrow) * DIM + lc;
        sah0 = ((const uint4*)pah)[0]; sah1 = ((const uint4*)pah)[1];
        sal0 = ((const uint4*)pal)[0]; sal1 = ((const uint4*)pal)[1];
        sbh0 = ((const uint4*)(wth + brow + lc))[0]; sbh1 = ((const uint4*)(wth + brow + lc))[1];
        sbl0 = ((const uint4*)(wtl + brow + lc))[0]; sbl1 = ((const uint4*)(wtl + brow + lc))[1];
    }

    const f32x4 z4 = {0.f, 0.f, 0.f, 0.f};
    f32x4 acc[2][2] = {{z4, z4}, {z4, z4}};

    for (int kt = 0; kt < 4; ++kt) {
        *(uint4*)&As_h[lrow * TKP + lc]     = sah0;
        *(uint4*)&As_h[lrow * TKP + lc + 8] = sah1;
        *(uint4*)&As_l[lrow * TKP + lc]     = sal0;
        *(uint4*)&As_l[lrow * TKP + lc + 8] = sal1;
        *(uint4*)&Bs_h[lrow * TKP + lc]     = sbh0;
        *(uint4*)&Bs_h[lrow * TKP + lc + 8] = sbh1;
        *(uint4*)&Bs_l[lrow * TKP + lc]     = sbl0;
        *(uint4*)&Bs_l[lrow * TKP + lc + 8] = sbl1;
        if (kt + 1 < 4) {
            const int kb = (kt + 1) * 64 + lc;
            const u16* pah = xh + (size_t)(row0 + lrow) * DIM + kb;
            const u16* pal = xl + (size_t)(row0 + lrow) * DIM + kb;
            sah0 = ((const uint4*)pah)[0]; sah1 = ((const uint4*)pah)[1];
            sal0 = ((const uint4*)pal)[0]; sal1 = ((const uint4*)pal)[1];
            sbh0 = ((const uint4*)(wth + brow + kb))[0]; sbh1 = ((const uint4*)(wth + brow + kb))[1];
            sbl0 = ((const uint4*)(wtl + brow + kb))[0]; sbl1 = ((const uint4*)(wtl + brow + kb))[1];
        }
        __syncthreads();

        __builtin_amdgcn_s_setprio(1);
        #pragma unroll
        for (int kc = 0; kc < 2; ++kc) {
            const int dc = kc * 32 + h4 * 8;
            half8 afh[2], afl[2], bfh[2], bfl[2];
            #pragma unroll
            for (int ab = 0; ab < 2; ++ab) {
                const int r = rh * 32 + ab * 16 + l15;
                afh[ab] = *(const half8*)&As_h[r * TKP + dc];
                afl[ab] = *(const half8*)&As_l[r * TKP + dc];
            }
            #pragma unroll
            for (int bb = 0; bb < 2; ++bb) {
                const int r = ch * 32 + bb * 16 + l15;
                bfh[bb] = *(const half8*)&Bs_h[r * TKP + dc];
                bfl[bb] = *(const half8*)&Bs_l[r * TKP + dc];
            }
            #pragma unroll
            for (int ab = 0; ab < 2; ++ab)
                #pragma unroll
                for (int bb = 0; bb < 2; ++bb) {
                    acc[ab][bb] = MFMA16(afh[ab], bfh[bb], acc[ab][bb]);
                    acc[ab][bb] = MFMA16(afh[ab], bfl[bb], acc[ab][bb]);
                    acc[ab][bb] = MFMA16(afl[ab], bfh[bb], acc[ab][bb]);
                }
        }
        __builtin_amdgcn_s_setprio(0);
        __syncthreads();
    }

    const float s = (mat == 0) ? 0.125f : 1.0f;
    u16* oph = (mat == 0) ? qh_o : kh_o;
    u16* opl = (mat == 0) ? ql_o : kl_o;
    #pragma unroll
    for (int ab = 0; ab < 2; ++ab)
        #pragma unroll
        for (int bb = 0; bb < 2; ++bb) {
            const int c  = col0 + ch * 32 + bb * 16 + l15;
            const int r0 = row0 + rh * 32 + ab * 16 + h4 * 4;
            if (mat < 2) {
                #pragma unroll
                for (int i = 0; i < 4; ++i) {
                    const int r = r0 + i;
                    const float t = (acc[ab][bb][i] + biasp[c]) * s;
                    u16 hh, ll;
                    split16(t, hh, ll);
                    oph[(size_t)r * DIM + c] = hh;
                    opl[(size_t)r * DIM + c] = ll;
                }
            } else {
                u16 v[4];
                #pragma unroll
                for (int i = 0; i < 4; ++i)
                    v[i] = f2h(acc[ab][bb][i] + biasp[c]);
                *(uint2*)&vt_o[(size_t)c * NN + r0] =
                    make_uint2((u32)v[0] | ((u32)v[1] << 16), (u32)v[2] | ((u32)v[3] << 16));
            }
        }
    #undef TKP
}

// ---------------- MFMA fp16 GEMM (Wo / fc1, early prefetch) ---------------
template<int MEPI>
__global__ __launch_bounds__(256) void mfma_gemm(
    const u16* __restrict__ Ah, const u16* __restrict__ Al,
    const u16* __restrict__ Bth, const u16* __restrict__ Btl,
    const float* __restrict__ bias, const float* __restrict__ resid,
    float* __restrict__ outf, u16* __restrict__ outh, u16* __restrict__ outl,
    int K, int M)
{
    __shared__ u16 lds[4 * 4608];
    u16* As_h = lds;
    u16* As_l = lds + 4608;
    u16* Bs_h = lds + 9216;
    u16* Bs_l = lds + 13824;
    #define TKP 72

    const int tid  = threadIdx.x;
    const int row0 = blockIdx.y * 64;
    const int col0 = blockIdx.x * 64;

    const int w   = tid >> 6;
    const int l15 = tid & 15, h4 = (tid & 63) >> 4;
    const int rh  = w & 1, ch = w >> 1;
    const int lrow = tid & 63, lseg = tid >> 6;
    const int lc = lseg * 16;

    uint4 sah0, sah1, sal0, sal1, sbh0, sbh1, sbl0, sbl1;
    {
        const u16* pa0 = Ah  + (size_t)(row0 + lrow) * K + lc;
        const u16* pa1 = Al  + (size_t)(row0 + lrow) * K + lc;
        const u16* pb0 = Bth + (size_t)(col0 + lrow) * K + lc;
        const u16* pb1 = Btl + (size_t)(col0 + lrow) * K + lc;
        sah0 = ((const uint4*)pa0)[0]; sah1 = ((const uint4*)pa0)[1];
        sal0 = ((const uint4*)pa1)[0]; sal1 = ((const uint4*)pa1)[1];
        sbh0 = ((const uint4*)pb0)[0]; sbh1 = ((const uint4*)pb0)[1];
        sbl0 = ((const uint4*)pb1)[0]; sbl1 = ((const uint4*)pb1)[1];
    }

    const f32x4 z4 = {0.f, 0.f, 0.f, 0.f};
    f32x4 acc[2][2] = {{z4, z4}, {z4, z4}};
    const int NKT2 = K / 64;

    for (int kt = 0; kt < NKT2; ++kt) {
        *(uint4*)&As_h[lrow * TKP + lc]     = sah0;
        *(uint4*)&As_h[lrow * TKP + lc + 8] = sah1;
        *(uint4*)&As_l[lrow * TKP + lc]     = sal0;
        *(uint4*)&As_l[lrow * TKP + lc + 8] = sal1;
        *(uint4*)&Bs_h[lrow * TKP + lc]     = sbh0;
        *(uint4*)&Bs_h[lrow * TKP + lc + 8] = sbh1;
        *(uint4*)&Bs_l[lrow * TKP + lc]     = sbl0;
        *(uint4*)&Bs_l[lrow * TKP + lc + 8] = sbl1;
        if (kt + 1 < NKT2) {
            const int kb = (kt + 1) * 64 + lc;
            const u16* pa0 = Ah  + (size_t)(row0 + lrow) * K + kb;
            const u16* pa1 = Al  + (size_t)(row0 + lrow) * K + kb;
            const u16* pb0 = Bth + (size_t)(col0 + lrow) * K + kb;
            const u16* pb1 = Btl + (size_t)(col0 + lrow) * K + kb;
            sah0 = ((const uint4*)pa0)[0]; sah1 = ((const uint4*)pa0)[1];
            sal0 = ((const uint4*)pa1)[0]; sal1 = ((const uint4*)pa1)[1];
            sbh0 = ((const uint4*)pb0)[0]; sbh1 = ((const uint4*)pb0)[1];
            sbl0 = ((const uint4*)pb1)[0]; sbl1 = ((const uint4*)pb1)[1];
        }
        __syncthreads();

        __builtin_amdgcn_s_setprio(1);
        #pragma unroll
        for (int kc = 0; kc < 2; ++kc) {
            const int dc = kc * 32 + h4 * 8;
            half8 afh[2], afl[2], bfh[2], bfl[2];
            #pragma unroll
            for (int ab = 0; ab < 2; ++ab) {
                const int r = rh * 32 + ab * 16 + l15;
                afh[ab] = *(const half8*)&As_h[r * TKP + dc];
                afl[ab] = *(const half8*)&As_l[r * TKP + dc];
            }
            #pragma unroll
            for (int bb = 0; bb < 2; ++bb) {
                const int r = ch * 32 + bb * 16 + l15;
                bfh[bb] = *(const half8*)&Bs_h[r * TKP + dc];
                bfl[bb] = *(const half8*)&Bs_l[r * TKP + dc];
            }
            #pragma unroll
            for (int ab = 0; ab < 2; ++ab)
                #pragma unroll
                for (int bb = 0; bb < 2; ++bb) {
                    acc[ab][bb] = MFMA16(afh[ab], bfh[bb], acc[ab][bb]);
                    acc[ab][bb] = MFMA16(afh[ab], bfl[bb], acc[ab][bb]);
                    acc[ab][bb] = MFMA16(afl[ab], bfh[bb], acc[ab][bb]);
                }
        }
        __builtin_amdgcn_s_setprio(0);
        __syncthreads();
    }

    #pragma unroll
    for (int ab = 0; ab < 2; ++ab)
        #pragma unroll
        for (int bb = 0; bb < 2; ++bb) {
            const int c  = col0 + ch * 32 + bb * 16 + l15;
            const int r0 = row0 + rh * 32 + ab * 16 + h4 * 4;
            #pragma unroll
            for (int i = 0; i < 4; ++i) {
                const int r = r0 + i;
                float t = acc[ab][bb][i] + bias[c];
                if (MEPI == MEPI_WO) {
                    t += resid[(size_t)r * M + c];
                    u16 hh, ll;
                    split16(t, hh, ll);
                    outh[(size_t)r * M + c] = hh;
                    outl[(size_t)r * M + c] = ll;
                } else {
                    t = t > 0.f ? t : expm1f(t);
                    outf[(size_t)r * M + c] = t;
                }
            }
        }
    #undef TKP
}

// ---------------- MFMA flash attention (round-14: 8-wave, QB=128) ---------
// 512 threads: 8 waves, each owning 16 q-rows; all share one staged K/V
// tile (stage cost per q-row halved vs 4-wave). K/V LDS double-buffered,
// one barrier per tile. Per-wave math identical to round 13 -> bit-identical.
#define QB 128
#define KB 64
#define NSPLIT 4
#define NKT (NN / KB)
#define KP 72

__global__ __launch_bounds__(512, 2) void attn_kernel(
    const u16* __restrict__ qhi, const u16* __restrict__ qlo,
    const u16* __restrict__ khi, const u16* __restrict__ klo,
    const u16* __restrict__ vT,
    float* __restrict__ op0, float* __restrict__ op1,
    float* __restrict__ op2, float* __restrict__ op3,
    float* __restrict__ mpart, float* __restrict__ lpart)
{
    __shared__ u16 lds[37120];            // 74240 B -> 2 blocks/CU
    u16* Kh0 = lds;                       // buf0 [64][72] x3
    u16* Kl0 = lds + 4608;
    u16* Vt0 = lds + 9216;
    u16* Kh1 = lds + 13824;               // buf1
    u16* Kl1 = lds + 18432;
    u16* Vt1 = lds + 23040;
    u16* Pb  = lds + 27648;               // [128][72] P fp16 (wave-local rows)
    u16* Qh  = lds;                       // overlay buf0 (init): [128][72]
    u16* Ql  = lds + 13824;               // overlay buf1 (init)
    float* frow = (float*)(lds + 36864);  // [128]

    const int tid = threadIdx.x;
    const int h   = blockIdx.y;
    const int q0  = blockIdx.x * QB;
    const int sp  = blockIdx.z;
    const int kt0 = sp * (NKT / NSPLIT);  // 16 tiles/block (even)
    const int kt1 = kt0 + NKT / NSPLIT;

    const int w   = tid >> 6;             // wave 0..7 -> q rows w*16..+15
    const int l15 = tid & 15, h4 = (tid & 63) >> 4;
    const int lrow = tid & 63, lseg = tid >> 6;   // staging: 8 segs x 8 u16
    const int gq8 = h * DH + lseg * 8;

    {   // stage Q (once, into overlay region): 128 rows x 64 d
        const int qrow = tid >> 2, qseg = tid & 3;
        const u16* s0 = qhi + (size_t)(q0 + qrow) * DIM + h * DH + qseg * 16;
        const u16* s1 = qlo + (size_t)(q0 + qrow) * DIM + h * DH + qseg * 16;
        uint4 a = ((const uint4*)s0)[0], b = ((const uint4*)s0)[1];
        uint4 c = ((const uint4*)s1)[0], d = ((const uint4*)s1)[1];
        *(uint4*)&Qh[qrow * KP + qseg * 16]     = a;
        *(uint4*)&Qh[qrow * KP + qseg * 16 + 8] = b;
        *(uint4*)&Ql[qrow * KP + qseg * 16]     = c;
        *(uint4*)&Ql[qrow * KP + qseg * 16 + 8] = d;
    }

    uint4 rk, rl, rv;                     // staging registers (1 uint4 each)
    auto load_tile = [&](int kt_ld) {
        const int key0 = kt_ld * KB;
        rk = *(const uint4*)(khi + (size_t)(key0 + lrow) * DIM + gq8);
        rl = *(const uint4*)(klo + (size_t)(key0 + lrow) * DIM + gq8);
        rv = *(const uint4*)(vT + (size_t)(h * DH + lrow) * NN + key0 + lseg * 8);
    };
    load_tile(kt0);
    __syncthreads();                              // Q staged

    half8 qf[2][2];                               // [kc][hi/lo]
    #pragma unroll
    for (int kc = 0; kc < 2; ++kc) {
        const int r = w * 16 + l15;
        const int dc = kc * 32 + h4 * 8;
        qf[kc][0] = *(const half8*)&Qh[r * KP + dc];
        qf[kc][1] = *(const half8*)&Ql[r * KP + dc];
    }
    __syncthreads();                              // hoist done; overlay safe

    auto stage_to = [&](u16* Kh, u16* Kl, u16* Vt) {
        *(uint4*)&Kh[lrow * KP + lseg * 8] = rk;
        *(uint4*)&Kl[lrow * KP + lseg * 8] = rl;
        *(uint4*)&Vt[lrow * KP + lseg * 8] = rv;
    };

    stage_to(Kh0, Kl0, Vt0);                      // tile kt0 -> buf0
    load_tile(kt0 + 1);                           // tile kt0+1 -> regs
    __syncthreads();                              // buf0 ready

    const f32x4 z4 = {0.f, 0.f, 0.f, 0.f};
    f32x4 oacc[4] = {z4, z4, z4, z4};             // d-blocks 0..3 for own 16 q
    float m_run[4], l_run[4];
    #pragma unroll
    for (int i = 0; i < 4; ++i) { m_run[i] = -3.0e38f; l_run[i] = 0.f; }

    auto tile_body = [&](int t, u16* Kc, u16* Lc, u16* Vc,
                         u16* Kn, u16* Ln, u16* Vn) {
        if (t + 1 < kt1) stage_to(Kn, Ln, Vn);    // writes to the idle buffer
        if (t + 2 < kt1) load_tile(t + 2);        // early-issue global loads

        // ---- S = Q K^T (3-pass fp16 hi/lo): 16 q-rows x 64 k per wave ----
        f32x4 sc[4] = {z4, z4, z4, z4};
        __builtin_amdgcn_s_setprio(1);
        #pragma unroll
        for (int kc = 0; kc < 2; ++kc) {
            const int dc = kc * 32 + h4 * 8;
            half8 kfh[4], kfl[4];
            #pragma unroll
            for (int kcb = 0; kcb < 4; ++kcb) {
                const int r = kcb * 16 + l15;
                kfh[kcb] = *(const half8*)&Kc[r * KP + dc];
                kfl[kcb] = *(const half8*)&Lc[r * KP + dc];
            }
            #pragma unroll
            for (int kcb = 0; kcb < 4; ++kcb) {
                sc[kcb] = MFMA16(qf[kc][0], kfh[kcb], sc[kcb]);
                sc[kcb] = MFMA16(qf[kc][0], kfl[kcb], sc[kcb]);
                sc[kcb] = MFMA16(qf[kc][1], kfh[kcb], sc[kcb]);
            }
        }
        __builtin_amdgcn_s_setprio(0);
        // ---- wave-local softmax ----
        float p[4][4], fr[4];
        #pragma unroll
        for (int i = 0; i < 4; ++i) {
            float pm = fmaxf(fmaxf(sc[0][i], sc[1][i]), fmaxf(sc[2][i], sc[3][i]));
            #pragma unroll
            for (int off = 1; off < 16; off <<= 1)
                pm = fmaxf(pm, __shfl_xor(pm, off));
            const float mnew = fmaxf(m_run[i], pm);
            fr[i] = __expf(m_run[i] - mnew);
            m_run[i] = mnew;
            p[0][i] = __expf(sc[0][i] - mnew);
            p[1][i] = __expf(sc[1][i] - mnew);
            p[2][i] = __expf(sc[2][i] - mnew);
            p[3][i] = __expf(sc[3][i] - mnew);
            float ls = (p[0][i] + p[1][i]) + (p[2][i] + p[3][i]);
            #pragma unroll
            for (int off = 1; off < 16; off <<= 1) ls += __shfl_xor(ls, off);
            l_run[i] = l_run[i] * fr[i] + ls;
        }
        #pragma unroll
        for (int kcb = 0; kcb < 4; ++kcb) {
            const int kk = kcb * 16 + l15;
            #pragma unroll
            for (int i = 0; i < 4; ++i)
                Pb[(w * 16 + h4 * 4 + i) * KP + kk] = f2h(p[kcb][i]);
        }
        if (l15 == 0) {
            #pragma unroll
            for (int i = 0; i < 4; ++i)
                frow[w * 16 + h4 * 4 + i] = fr[i];
        }
        // wave-local: compiler waitcnt orders the reads below
        const float frq = frow[w * 16 + l15];
        #pragma unroll
        for (int db = 0; db < 4; ++db) oacc[db] *= frq;
        // ---- PV: wave-local ----
        __builtin_amdgcn_s_setprio(1);
        #pragma unroll
        for (int kc = 0; kc < 2; ++kc) {
            const half8 pf = *(const half8*)&Pb[(w * 16 + l15) * KP + kc * 32 + h4 * 8];
            #pragma unroll
            for (int db = 0; db < 4; ++db) {
                const half8 vf = *(const half8*)&Vc[(db * 16 + l15) * KP + kc * 32 + h4 * 8];
                oacc[db] = MFMA16(vf, pf, oacc[db]);
            }
        }
        __builtin_amdgcn_s_setprio(0);
        __syncthreads();   // single per-tile barrier: buf^1 staged + cur reads done
    };

    for (int t = kt0; t < kt1; t += 2) {
        tile_body(t,     Kh0, Kl0, Vt0, Kh1, Kl1, Vt1);
        tile_body(t + 1, Kh1, Kl1, Vt1, Kh0, Kl0, Vt0);
    }

    float* ob = (sp == 0) ? op0 : ((sp == 1) ? op1 : ((sp == 2) ? op2 : op3));
    #pragma unroll
    for (int db = 0; db < 4; ++db)
        *(f32x4*)&ob[(size_t)(q0 + w * 16 + l15) * DIM + h * DH + db * 16 + h4 * 4] = oacc[db];
    if (l15 == 0) {
        #pragma unroll
        for (int i = 0; i < 4; ++i) {
            const int r = w * 16 + h4 * 4 + i;
            mpart[((size_t)sp * NN + q0 + r) * NH + h] = m_run[i];
            lpart[((size_t)sp * NN + q0 + r) * NH + h] = l_run[i];
        }
    }
}

// merge the 4 partials -> fp16 hi/lo planes (feeds the MFMA Wo GEMM)
__global__ __launch_bounds__(256) void attn_combine(
    const float* __restrict__ o0, const float* __restrict__ o1,
    const float* __restrict__ o2, const float* __restrict__ o3,
    const float* __restrict__ mp, const float* __restrict__ lp,
    u16* __restrict__ ohi, u16* __restrict__ olo)
{
    const int gid = blockIdx.x * 256 + threadIdx.x;
    const int row = gid >> 6;
    const int c4  = (gid & 63) * 4;
    const int h   = c4 >> 6;
    float m[4], wgt[4];
    #pragma unroll
    for (int z = 0; z < 4; ++z) m[z] = mp[((size_t)z * NN + row) * NH + h];
    const float M = fmaxf(fmaxf(m[0], m[1]), fmaxf(m[2], m[3]));
    float den = 0.f;
    #pragma unroll
    for (int z = 0; z < 4; ++z) {
        wgt[z] = __expf(m[z] - M);
        den += lp[((size_t)z * NN + row) * NH + h] * wgt[z];
    }
    const float inv = 1.f / den;
    const float4 a = *(const float4*)&o0[(size_t)row * DIM + c4];
    const float4 b = *(const float4*)&o1[(size_t)row * DIM + c4];
    const float4 c = *(const float4*)&o2[(size_t)row * DIM + c4];
    const float4 d = *(const float4*)&o3[(size_t)row * DIM + c4];
    float r[4];
    r[0] = (a.x * wgt[0] + b.x * wgt[1] + c.x * wgt[2] + d.x * wgt[3]) * inv;
    r[1] = (a.y * wgt[0] + b.y * wgt[1] + c.y * wgt[2] + d.y * wgt[3]) * inv;
    r[2] = (a.z * wgt[0] + b.z * wgt[1] + c.z * wgt[2] + d.z * wgt[3]) * inv;
    r[3] = (a.w * wgt[0] + b.w * wgt[1] + c.w * wgt[2] + d.w * wgt[3]) * inv;
    u16 hh[4], ll[4];
    #pragma unroll
    for (int j = 0; j < 4; ++j) split16(r[j], hh[j], ll[j]);
    *(uint2*)&ohi[(size_t)row * DIM + c4] =
        make_uint2((u32)hh[0] | ((u32)hh[1] << 16), (u32)hh[2] | ((u32)hh[3] << 16));
    *(uint2*)&olo[(size_t)row * DIM + c4] =
        make_uint2((u32)ll[0] | ((u32)ll[1] << 16), (u32)ll[2] | ((u32)ll[3] << 16));
}

// ---------------- per-node group adapter ----------------
__global__ __launch_bounds__(64) void adapter_kernel(
    const float* __restrict__ feats, const int* __restrict__ grp,
    const float* __restrict__ AW1, const float* __restrict__ Ab1,
    const float* __restrict__ AW2, const float* __restrict__ Ab2,
    float* __restrict__ out)
{
    const int n = blockIdx.x;
    const int lane = threadIdx.x;
    __shared__ float f[F1D];
    f[lane]      = feats[(size_t)n * F1D + lane];
    f[lane + 64] = feats[(size_t)n * F1D + 64 + lane];
    __syncthreads();
    const int g = grp[n];
    const float* W1 = AW1 + (size_t)g * F1D * AD;
    const int a = lane & 31;
    const int half = lane >> 5;
    float hsum = 0.f;
    for (int d = 0; d < 64; ++d)
        hsum = fmaf(f[half * 64 + d], W1[(half * 64 + d) * AD + a], hsum);
    hsum += __shfl_xor(hsum, 32);
    hsum = fmaxf(hsum + Ab1[g * AD + a], 0.f);
    float p = hsum * AW2[g * AD + a];
    #pragma unroll
    for (int mm = 1; mm < 32; mm <<= 1) p += __shfl_xor(p, mm);
    if (lane == 0) out[n] = p + Ab2[g];
}

// ---------------- host-side orchestration ----------------
extern "C" void kernel_launch(void* const* d_in, const int* in_sizes, int n_in,
                              void* d_out, int out_size, void* d_ws, size_t ws_size,
                              hipStream_t stream)
{
    const float* x_in   = (const float*)d_in[0];
    const float* eattr  = (const float*)d_in[1];
    const float* Wself  = (const float*)d_in[2];
    const float* Wnbr   = (const float*)d_in[3];
    const float* convb  = (const float*)d_in[4];
    const float* gamma  = (const float*)d_in[5];
    const float* beta   = (const float*)d_in[6];
    const float* bnmean = (const float*)d_in[7];
    const float* bnvar  = (const float*)d_in[8];
    const float* Wqkv   = (const float*)d_in[9];
    const float* bqkv   = (const float*)d_in[10];
    const float* Wo     = (const float*)d_in[11];
    const float* bo     = (const float*)d_in[12];
    const float* fc1W   = (const float*)d_in[13];
    const float* fc1b   = (const float*)d_in[14];
    const float* AW1    = (const float*)d_in[15];
    const float* Ab1    = (const float*)d_in[16];
    const float* AW2    = (const float*)d_in[17];
    const float* Ab2    = (const float*)d_in[18];
    const int*   eidx   = (const int*)d_in[19];
    const int*   grp    = (const int*)d_in[20];
    const int* srcArr = eidx;
    const int* dstArr = eidx + NE;

    float* fws = (float*)d_ws;
    const size_t NM = (size_t)NN * DIM;
    float* bufA  = fws;                  // x L0 / x L2 (residual)
    float* bufB  = fws + NM;             // attn op0
    float* bufC  = fws + 2 * NM;         // x L1 / attn op1
    float* feats = fws + 3 * NM;         // NN x F1D
    float* mpart = fws + 3 * NM + NM / 2;         // [4][NN][NH]
    float* lpart = mpart + 4 * NN * NH;
    u16* up = (u16*)(lpart + 4 * NN * NH);
    u16* xpAh = up;             u16* xpAl = xpAh + NM;   // x planes ping
    u16* xpBh = xpAl + NM;      u16* xpBl = xpBh + NM;   // x planes pong
    u16* aggh = xpBl + NM;      u16* aggl = aggh + NM;   // agg planes
    u16* qh = aggl + NM;        u16* ql = qh + NM;       // Q planes / combine out
    u16* kh = ql + NM;          u16* kl = kh + NM;       // K planes / Wo out
    u16* vt = kl + NM;                                   // V^T fp16 [256][NN]
    u16* wcath = vt + NM;                                // [3][256][512]
    u16* wcatl = wcath + 3 * 131072;
    u16* wt4h  = wcatl + 3 * 131072;                     // [4][256][256] qkv+wo
    u16* wt4l  = wt4h + 4 * 65536;
    u16* fc1h  = wt4l + 4 * 65536;                       // [128][256]
    u16* fc1l  = fc1h + 32768;
    int*   esrc = (int*)(fc1l + 32768);                  // NE
    float* ewt  = (float*)(esrc + NE);                   // NE
    int* off    = (int*)(ewt + NE);                      // NN+1
    int* cur    = off + NN + 1;                          // NN
    float* outp = (float*)d_out;

    float* op2 = (float*)xpAh;           // attn partial overlays
    float* op3 = (float*)xpBh;

    // fused prep: all converts + zero(cur)
    prep_kernel<<<1700, 256, 0, stream>>>(
        x_in, Wself, Wnbr, Wqkv, Wo, fc1W,
        xpAh, xpAl, wcath, wcatl, wt4h, wt4l, fc1h, fc1l, cur);

    // CSR build (csr_scan zeroes cur for csr_fill)
    csr_count<<<NE / 256, 256, 0, stream>>>(dstArr, cur);
    csr_scan<<<1, 1024, 0, stream>>>(cur, off);
    csr_fill<<<NE / 256, 256, 0, stream>>>(dstArr, srcArr, eattr, off, cur, esrc, ewt);

    const dim3 gc(DIM / 64, NN / 32);    // 32-row conv tiles: 512 blocks
    const int rgrid = NN * DIM / 4 / 256;

    // conv layer 0: x_in -> bufA (fp32) + xpB planes
    agg_kernel<false><<<NN / 4, 256, 0, stream>>>(x_in, esrc, ewt, off, aggh, aggl);
    conv_mfma<EPI_BNELU><<<gc, 256, 0, stream>>>(
        xpAh, xpAl, aggh, aggl, wcath, wcatl, convb,
        gamma, beta, bnmean, bnvar, bufA, xpBh, xpBl);
    // conv layer 1: bufA -> bufC + xpA planes
    agg_kernel<false><<<NN / 4, 256, 0, stream>>>(bufA, esrc, ewt, off, aggh, aggl);
    conv_mfma<EPI_BNELU><<<gc, 256, 0, stream>>>(
        xpBh, xpBl, aggh, aggl, wcath + 131072, wcatl + 131072, convb + DIM,
        gamma + DIM, beta + DIM, bnmean + DIM, bnvar + DIM, bufC, xpAh, xpAl);
    // conv layer 2 (edge-weighted, bias only): bufC -> bufA + xpB planes
    agg_kernel<true><<<NN / 4, 256, 0, stream>>>(bufC, esrc, ewt, off, aggh, aggl);
    conv_mfma<EPI_BIAS><<<gc, 256, 0, stream>>>(
        xpAh, xpAl, aggh, aggl, wcath + 262144, wcatl + 262144, convb + 2 * DIM,
        nullptr, nullptr, nullptr, nullptr, bufA, xpBh, xpBl);

    // QKV (fp16 3-pass MFMA) -> Q/K planes (Q/8) + V^T
    qkv_mfma<<<dim3(12, NN / 64), 256, 0, stream>>>(
        xpBh, xpBl, wt4h, wt4l, bqkv, qh, ql, kh, kl, vt);

    // flash attention (8-wave QB=128, 4-way key split) -> partials -> combine
    attn_kernel<<<dim3(NN / QB, NH, NSPLIT), 512, 0, stream>>>(
        qh, ql, kh, kl, vt, bufB, bufC, op2, op3, mpart, lpart);
    attn_combine<<<rgrid, 256, 0, stream>>>(
        bufB, bufC, op2, op3, mpart, lpart, qh, ql);

    // Wo + residual (fp16 3-pass MFMA): kh/kl = planes(bufA + o@Wo + bo)
    mfma_gemm<MEPI_WO><<<dim3(DIM / 64, NN / 64), 256, 0, stream>>>(
        qh, ql, wt4h + 3 * 65536, wt4l + 3 * 65536, bo, bufA,
        nullptr, kh, kl, DIM, DIM);

    // fc1 + ELU (fp16 3-pass MFMA): feats = elu(x' @ fc1W + fc1b)
    mfma_gemm<MEPI_FC1><<<dim3(F1D / 64, NN / 64), 256, 0, stream>>>(
        kh, kl, fc1h, fc1l, fc1b, nullptr, feats, nullptr, nullptr, DIM, F1D);

    // adapter routing -> out
    adapter_kernel<<<NN, 64, 0, stream>>>(feats, grp, AW1, Ab1, AW2, Ab2, outp);
}